// Round 9
// baseline (348.687 us; speedup 1.0000x reference)
//
#include <hip/hip_runtime.h>
#include <hip/hip_bf16.h>
#include <math.h>

#define TID threadIdx.x

constexpr int Cc = 512, Tt = 1024, C3 = 1536;

typedef __attribute__((ext_vector_type(8))) __bf16 bf16x8;
typedef __attribute__((ext_vector_type(4))) float f32x4;

__device__ __forceinline__ void async16(const void* g, void* l) {
  __builtin_amdgcn_global_load_lds(
      (const __attribute__((address_space(1))) unsigned int*)g,
      (__attribute__((address_space(3))) unsigned int*)l, 16, 0, 0);
}

__device__ __forceinline__ unsigned int pack2bf(float a, float b) {
  __hip_bfloat162 h;
  h.x = __float2bfloat16(a);
  h.y = __float2bfloat16(b);
  return *reinterpret_cast<unsigned int*>(&h);
}

__device__ __forceinline__ float bf2f(unsigned short u) {
  unsigned int t = ((unsigned int)u) << 16;
  union { unsigned int i; float f; } c;
  c.i = t;
  return c.f;
}

__device__ __forceinline__ float mishf(float x) {
  float sp = (x > 20.f) ? x : log1pf(__expf(x));
  return x * tanhf(sp);
}

__device__ __forceinline__ void blockReduce2(float& s, float& ss) {
  #pragma unroll
  for (int off = 32; off > 0; off >>= 1) {
    s  += __shfl_xor(s,  off);
    ss += __shfl_xor(ss, off);
  }
  __shared__ float ls[4], lss[4];
  int w = TID >> 6;
  if ((TID & 63) == 0) { ls[w] = s; lss[w] = ss; }
  __syncthreads();
  s  = ls[0] + ls[1] + ls[2] + ls[3];
  ss = lss[0] + lss[1] + lss[2] + lss[3];
}

// ---------------- zero the raw-stat accumulators (256 floats) ----------------
__global__ void zero_stats(float* p) { p[TID] = 0.f; }

// ---------------- fused GN(32) + im2col(K=2, pad_lo=0) -> bf16 B1t[b][t][k=2ci+j] ----------------
__global__ __launch_bounds__(256) void gn1_im2col(const float* __restrict__ x,
    const float* __restrict__ w, const float* __restrict__ bv,
    __hip_bfloat16* __restrict__ B1t) {
  __shared__ float hs[16][262];
  int blk = blockIdx.x, bb = blk >> 5, g = blk & 31;
  size_t base = ((size_t)bb * Cc + g * 16) * Tt;
  const float* xp = x + base;
  float s = 0.f, ss = 0.f;
  for (int i = TID * 4; i < 16 * Tt; i += 1024) {
    float4 v = *reinterpret_cast<const float4*>(xp + i);
    s  += v.x + v.y + v.z + v.w;
    ss += v.x * v.x + v.y * v.y + v.z * v.z + v.w * v.w;
  }
  blockReduce2(s, ss);
  float mean = s * (1.f / 16384.f);
  float rstd = rsqrtf(ss * (1.f / 16384.f) - mean * mean + 1e-5f);

  char* ob = reinterpret_cast<char*>(B1t + (size_t)bb * Tt * 1024 + g * 32);
  for (int tc = 0; tc < 4; ++tc) {
    int tbase = tc * 256;
    __syncthreads();
    for (int task = TID; task < 1024; task += 256) {
      int row = task >> 6, c4 = task & 63;
      int ch = g * 16 + row;
      float sw = w[ch] * rstd;
      float sb = bv[ch] - mean * sw;
      float4 v = *reinterpret_cast<const float4*>(xp + (size_t)row * Tt + tbase + c4 * 4);
      hs[row][c4 * 4 + 0] = v.x * sw + sb;
      hs[row][c4 * 4 + 1] = v.y * sw + sb;
      hs[row][c4 * 4 + 2] = v.z * sw + sb;
      hs[row][c4 * 4 + 3] = v.w * sw + sb;
    }
    if (TID < 16) {
      int row = TID, t = tbase + 256;
      float val = 0.f;
      if (t < Tt) {
        int ch = g * 16 + row;
        float sw = w[ch] * rstd;
        float sb = bv[ch] - mean * sw;
        val = xp[(size_t)row * Tt + t] * sw + sb;
      }
      hs[row][256] = val;
    }
    __syncthreads();
    for (int task = TID; task < 1024; task += 256) {
      int t = task >> 2, cj = task & 3;
      int ci = cj * 4;
      uint4 u;
      u.x = pack2bf(hs[ci + 0][t], hs[ci + 0][t + 1]);
      u.y = pack2bf(hs[ci + 1][t], hs[ci + 1][t + 1]);
      u.z = pack2bf(hs[ci + 2][t], hs[ci + 2][t + 1]);
      u.w = pack2bf(hs[ci + 3][t], hs[ci + 3][t + 1]);
      *reinterpret_cast<uint4*>(ob + ((size_t)(tbase + t) * 1024 + cj * 8) * 2) = u;
    }
  }
}

// ---------------- im2col(K=4, pad_lo=1) on attn output -> bf16 B4t[b][t][k=4ci+j], coalesced ----------------
__global__ __launch_bounds__(256) void im2col_k4(const float* __restrict__ a,
    __hip_bfloat16* __restrict__ B4t) {
  __shared__ float hs[16][266];
  int bb = blockIdx.x >> 5, cg = blockIdx.x & 31;
  const float* ab = a + ((size_t)bb * Cc + cg * 16) * Tt;
  char* ob = reinterpret_cast<char*>(B4t + (size_t)bb * Tt * 2048 + cg * 64);
  for (int tc = 0; tc < 4; ++tc) {
    int tbase = tc * 256;
    __syncthreads();
    for (int task = TID; task < 1024; task += 256) {
      int row = task >> 6, c4 = task & 63;
      float4 v = *reinterpret_cast<const float4*>(ab + (size_t)row * Tt + tbase + c4 * 4);
      hs[row][c4 * 4 + 1] = v.x;
      hs[row][c4 * 4 + 2] = v.y;
      hs[row][c4 * 4 + 3] = v.z;
      hs[row][c4 * 4 + 4] = v.w;
    }
    if (TID < 48) {
      int row = TID / 3, e = TID % 3;
      int t = (e == 0) ? tbase - 1 : tbase + 256 + (e - 1);
      float v = (t >= 0 && t < Tt) ? ab[(size_t)row * Tt + t] : 0.f;
      int col = (e == 0) ? 0 : 257 + (e - 1);
      hs[row][col] = v;
    }
    __syncthreads();
    for (int task = TID; task < 2048; task += 256) {
      int t = task >> 3, cj = task & 7;
      int ci = cj * 2;
      uint4 u;
      u.x = pack2bf(hs[ci][t],     hs[ci][t + 1]);
      u.y = pack2bf(hs[ci][t + 2], hs[ci][t + 3]);
      u.z = pack2bf(hs[ci + 1][t],     hs[ci + 1][t + 1]);
      u.w = pack2bf(hs[ci + 1][t + 2], hs[ci + 1][t + 3]);
      *reinterpret_cast<uint4*>(ob + ((size_t)(tbase + t) * 2048 + cj * 8) * 2) = u;
    }
  }
}

// ---------------- f32 -> bf16 cast (weights) ----------------
__global__ __launch_bounds__(256) void cast_bf16(const float* __restrict__ in,
    __hip_bfloat16* __restrict__ out, int n) {
  int i = (blockIdx.x * 256 + TID) * 4;
  if (i >= n) return;
  float4 v = *reinterpret_cast<const float4*>(in + i);
  *reinterpret_cast<unsigned int*>(out + i)     = pack2bf(v.x, v.y);
  *reinterpret_cast<unsigned int*>(out + i + 2) = pack2bf(v.z, v.w);
}

// ---------------- bf16 MFMA GEMM v6: A direct global->VGPR (no LDS), B via LDS 2-buffer
//                  (stage(kt+1) before compute(kt), 1 barrier/step), fused GN raw stats ----------
// C[b][o][t] = sum_k A[o][k] * Bt[b][t][k] + bias[o]
template<int K, int MT, int GROWS, int NGRP, bool BF16OUT>
__global__ __launch_bounds__(256) void gemm_bt6(const __hip_bfloat16* __restrict__ A,
    const __hip_bfloat16* __restrict__ Bt, const float* __restrict__ bias,
    void* __restrict__ Cout, float* __restrict__ statraw, int M) {
  constexpr int NF  = (MT == 128) ? 4 : 2; // n-fragments per wave
  constexpr int NKT = K / 64;
  __shared__ __align__(16) char lds[2 * 16 * 1024];   // 2 x 16 B-chunks of 1KB
  int t0 = blockIdx.x * 128, o0 = blockIdx.y * MT, bz = blockIdx.z;
  int wave = TID >> 6, lane = TID & 63;
  int l4 = lane >> 4, r15 = lane & 15;
  const __hip_bfloat16* Bb = Bt + ((size_t)bz * 1024 + t0) * K;
  int mbase = (MT == 128) ? (wave >> 1) * 4 : 0;
  int nbase = (MT == 128) ? (wave & 1) * 4 : wave * 2;

  // per-lane A row pointers (direct global -> VGPR fragments)
  const __hip_bfloat16* Arow[4];
  #pragma unroll
  for (int m = 0; m < 4; ++m)
    Arow[m] = A + (size_t)(o0 + (mbase + m) * 16 + r15) * K + l4 * 8;

  f32x4 acc[4][NF];
  f32x4 zz = {0.f, 0.f, 0.f, 0.f};
  #pragma unroll
  for (int m = 0; m < 4; ++m)
    #pragma unroll
    for (int n = 0; n < NF; ++n) acc[m][n] = zz;

  auto stageB = [&](int kt) {
    char* dst = lds + (kt & 1) * 16384;
    #pragma unroll
    for (int c = 0; c < 4; ++c) {
      int ch = c * 4 + wave;
      int row = (ch >> 1) * 16 + r15;
      int kof = kt * 64 + (ch & 1) * 32 + l4 * 8;
      async16(Bb + (size_t)row * K + kof, dst + ch * 1024 + lane * 16);
    }
  };

  stageB(0);
  __syncthreads();
  for (int kt = 0; kt < NKT; ++kt) {
    if (kt + 1 < NKT) stageB(kt + 1);   // latency hides under this step's compute
    char* cur = lds + (kt & 1) * 16384;
    #pragma unroll
    for (int kk = 0; kk < 2; ++kk) {
      bf16x8 af[4], bfr[NF];
      #pragma unroll
      for (int m = 0; m < 4; ++m)
        af[m] = *reinterpret_cast<const bf16x8*>(Arow[m] + kt * 64 + kk * 32);
      #pragma unroll
      for (int n = 0; n < NF; ++n)
        bfr[n] = *reinterpret_cast<const bf16x8*>(cur + ((nbase + n) * 2 + kk) * 1024 + lane * 16);
      #pragma unroll
      for (int m = 0; m < 4; ++m)
        #pragma unroll
        for (int n = 0; n < NF; ++n)
          acc[m][n] = __builtin_amdgcn_mfma_f32_16x16x32_bf16(af[m], bfr[n], acc[m][n], 0, 0, 0);
    }
    __syncthreads();   // drains stage(kt+1); next step reads other buffer
  }

  // epilogue: store (+bias); per-(wave,m) lane-reduced stats into LDS, then <=2 groups -> atomics
  float* sred = reinterpret_cast<float*>(lds);  // 32 floats, buffer is dead
  #pragma unroll
  for (int m = 0; m < 4; ++m) {
    float s = 0.f, ss2 = 0.f;
    #pragma unroll
    for (int n = 0; n < NF; ++n) {
      int ocol = t0 + (nbase + n) * 16 + r15;
      #pragma unroll
      for (int r = 0; r < 4; ++r) {
        int orow = o0 + (mbase + m) * 16 + l4 * 4 + r;
        float v = acc[m][n][r] + bias[orow];
        if constexpr (BF16OUT)
          ((__hip_bfloat16*)Cout)[((size_t)bz * M + orow) * 1024 + ocol] = __float2bfloat16(v);
        else
          ((float*)Cout)[((size_t)bz * M + orow) * 1024 + ocol] = v;
        s += v;
        ss2 += v * v;
      }
    }
    #pragma unroll
    for (int off = 1; off < 64; off <<= 1) {
      s   += __shfl_xor(s, off);
      ss2 += __shfl_xor(ss2, off);
    }
    if (lane == 0) {
      sred[(wave * 4 + m) * 2]     = s;
      sred[(wave * 4 + m) * 2 + 1] = ss2;
    }
  }
  __syncthreads();
  if (TID < 2) {
    int g0 = o0 / GROWS;
    int gl = TID;
    float S = 0.f, SS = 0.f;
    int cnt = 0;
    #pragma unroll
    for (int slot = 0; slot < 16; ++slot) {
      int stripe = ((MT == 128) ? ((slot >> 3) << 2) : 0) + (slot & 3);
      int g = (o0 + stripe * 16) / GROWS;
      if (g == g0 + gl) {
        S  += sred[slot * 2];
        SS += sred[slot * 2 + 1];
        ++cnt;
      }
    }
    if (cnt) {
      atomicAdd(&statraw[2 * (bz * NGRP + g0 + gl)],     S);
      atomicAdd(&statraw[2 * (bz * NGRP + g0 + gl) + 1], SS);
    }
  }
}

// ---------------- fused GN(8)+Mish + build attn input images (bf16 qkv input, raw stats) ----------------
__global__ __launch_bounds__(256) void gn2_prep(const __hip_bfloat16* __restrict__ qkv,
    const float* __restrict__ straw, const float* __restrict__ w, const float* __restrict__ bv,
    char* __restrict__ qTp, char* __restrict__ kimg, char* __restrict__ vimg) {
  __shared__ unsigned short hbf[192 * 66];
  int tl = blockIdx.x & 15, hb = blockIdx.x >> 4;
  int b = hb >> 3, hd = hb & 7;
  float rs = straw[2 * (b * 8 + hd)], rq = straw[2 * (b * 8 + hd) + 1];
  float mean = rs * (1.f / 196608.f);
  float rstd = rsqrtf(fmaxf(rq * (1.f / 196608.f) - mean * mean, 0.f) + 1e-5f);
  for (int task = TID; task < 768; task += 256) {
    int row = task >> 2, seg = task & 3;
    int ch = hd * 192 + row;
    float sw = w[ch] * rstd;
    float sb = bv[ch] - mean * sw;
    const uint4* src = reinterpret_cast<const uint4*>(
        qkv + ((size_t)(b * C3 + ch)) * 1024 + tl * 64 + seg * 16);
    uint4 u0 = src[0], u1 = src[1];
    unsigned int uu[8] = {u0.x, u0.y, u0.z, u0.w, u1.x, u1.y, u1.z, u1.w};
    unsigned int* dst = reinterpret_cast<unsigned int*>(&hbf[row * 66 + seg * 16]);
    #pragma unroll
    for (int j = 0; j < 8; ++j) {
      float a = mishf(bf2f((unsigned short)(uu[j] & 0xffff)) * sw + sb);
      float c = mishf(bf2f((unsigned short)(uu[j] >> 16)) * sw + sb);
      dst[j] = pack2bf(a, c);
    }
  }
  __syncthreads();
  size_t tileof = ((size_t)hb * 16 + tl) * 8192;
  {
    int t = TID & 63, sel = TID >> 6;
    int img = sel >> 1, half = sel & 1;
    char* obase = (img == 0 ? qTp : kimg) + tileof + (size_t)t * 128;
    #pragma unroll
    for (int cc = 0; cc < 4; ++cc) {
      int chunk = half * 4 + cc;
      uint4 u;
      unsigned int* up = reinterpret_cast<unsigned int*>(&u);
      #pragma unroll
      for (int j = 0; j < 4; ++j) {
        int c = chunk * 8 + j * 2;
        unsigned int lo = hbf[(img * 64 + c) * 66 + t];
        unsigned int hi = hbf[(img * 64 + c + 1) * 66 + t];
        up[j] = lo | (hi << 16);
      }
      int cpos = (img == 0) ? chunk : (chunk ^ (t & 7));
      *reinterpret_cast<uint4*>(obase + cpos * 16) = u;
    }
  }
  {
    int c = TID & 63, qtr = TID >> 6;
    const unsigned int* vrow = reinterpret_cast<const unsigned int*>(&hbf[(128 + c) * 66]);
    char* obase = vimg + tileof + (size_t)c * 128;
    #pragma unroll
    for (int k = 0; k < 2; ++k) {
      int chunk = qtr * 2 + k;
      uint4 u;
      unsigned int* up = reinterpret_cast<unsigned int*>(&u);
      #pragma unroll
      for (int j = 0; j < 4; ++j) up[j] = vrow[chunk * 4 + j];
      *reinterpret_cast<uint4*>(obase + (chunk ^ (c & 7)) * 16) = u;
    }
  }
}

// ---------------- MFMA flash attention v2: async-staged images, double-buffered ----------------
__global__ __launch_bounds__(256) void attn_mfma2(const char* __restrict__ qTp,
    const char* __restrict__ kimg, const char* __restrict__ vimg,
    float* __restrict__ a) {
  __shared__ __align__(16) char smem[40960];
  char* kbuf0 = smem;
  char* kbuf1 = smem + 8192;
  char* vbuf0 = smem + 16384;
  char* vbuf1 = smem + 24576;
  char* pp    = smem + 32768;
  char* ov    = smem;

  int tl = blockIdx.x, hb = blockIdx.y;
  int b = hb >> 3, hd = hb & 7;
  int lane = TID & 63, wave = TID >> 6;
  int l4 = lane >> 4, r15 = lane & 15;
  size_t ibase = (size_t)hb * 16 * 8192;
  const char* ksrc = kimg + ibase;
  const char* vsrc = vimg + ibase;

  #pragma unroll
  for (int j = 0; j < 2; ++j) {
    int u = j * 256 + TID;
    async16(ksrc + u * 16, kbuf0 + u * 16);
    async16(vsrc + u * 16, vbuf0 + u * 16);
  }
  bf16x8 aq[2];
  int tg = wave * 16 + r15;
  const char* qrow = qTp + ibase + (size_t)tl * 8192 + (size_t)tg * 128;
  aq[0] = *reinterpret_cast<const bf16x8*>(qrow + l4 * 16);
  aq[1] = *reinterpret_cast<const bf16x8*>(qrow + 64 + l4 * 16);

  f32x4 osum[4];
  f32x4 zz = {0.f, 0.f, 0.f, 0.f};
  #pragma unroll
  for (int cf = 0; cf < 4; ++cf) osum[cf] = zz;
  float mrow[4] = {-1e30f, -1e30f, -1e30f, -1e30f};
  float lrow[4] = {0.f, 0.f, 0.f, 0.f};
  __syncthreads();

  for (int it = 0; it < 16; ++it) {
    char* kcur = (it & 1) ? kbuf1 : kbuf0;
    char* vcur = (it & 1) ? vbuf1 : vbuf0;
    if (it < 15) {
      char* knxt = (it & 1) ? kbuf0 : kbuf1;
      char* vnxt = (it & 1) ? vbuf0 : vbuf1;
      const char* kn = ksrc + (size_t)(it + 1) * 8192;
      const char* vn = vsrc + (size_t)(it + 1) * 8192;
      #pragma unroll
      for (int j = 0; j < 2; ++j) {
        int u = j * 256 + TID;
        async16(kn + u * 16, knxt + u * 16);
        async16(vn + u * 16, vnxt + u * 16);
      }
    }
    f32x4 sc[4];
    #pragma unroll
    for (int sf = 0; sf < 4; ++sf) sc[sf] = zz;
    #pragma unroll
    for (int sf = 0; sf < 4; ++sf) {
      int sr = sf * 16 + r15;
      #pragma unroll
      for (int kk = 0; kk < 2; ++kk) {
        bf16x8 bk = *reinterpret_cast<const bf16x8*>(kcur + sr * 128 + (((kk * 4 + l4) ^ (sr & 7)) << 4));
        sc[sf] = __builtin_amdgcn_mfma_f32_16x16x32_bf16(aq[kk], bk, sc[sf], 0, 0, 0);
      }
    }
    float tmax[4];
    #pragma unroll
    for (int r = 0; r < 4; ++r)
      tmax[r] = fmaxf(fmaxf(sc[0][r], sc[1][r]), fmaxf(sc[2][r], sc[3][r]));
    #pragma unroll
    for (int off = 1; off < 16; off <<= 1)
      #pragma unroll
      for (int r = 0; r < 4; ++r) tmax[r] = fmaxf(tmax[r], __shfl_xor(tmax[r], off));
    float alpha[4];
    #pragma unroll
    for (int r = 0; r < 4; ++r) {
      float mnew = fmaxf(mrow[r], tmax[r]);
      alpha[r] = __expf((mrow[r] - mnew) * 0.125f);
      mrow[r] = mnew;
      lrow[r] *= alpha[r];
    }
    #pragma unroll
    for (int cf = 0; cf < 4; ++cf)
      #pragma unroll
      for (int r = 0; r < 4; ++r) osum[cf][r] *= alpha[r];
    char* pw = pp + wave * 2048;
    float psum[4] = {0.f, 0.f, 0.f, 0.f};
    #pragma unroll
    for (int sf = 0; sf < 4; ++sf) {
      int s = sf * 16 + r15;
      #pragma unroll
      for (int r = 0; r < 4; ++r) {
        float p = __expf((sc[sf][r] - mrow[r]) * 0.125f);
        psum[r] += p;
        int tlc = l4 * 4 + r;
        *reinterpret_cast<__hip_bfloat16*>(pw + tlc * 128 + ((((s >> 3) ^ (tlc & 7)) << 4) | ((s & 7) * 2)))
            = __float2bfloat16(p);
      }
    }
    #pragma unroll
    for (int r = 0; r < 4; ++r) lrow[r] += psum[r];
    asm volatile("s_waitcnt lgkmcnt(0)" ::: "memory");
    __builtin_amdgcn_sched_barrier(0);

    bf16x8 pa[2];
    #pragma unroll
    for (int kk = 0; kk < 2; ++kk)
      pa[kk] = *reinterpret_cast<const bf16x8*>(pw + r15 * 128 + (((kk * 4 + l4) ^ (r15 & 7)) << 4));
    #pragma unroll
    for (int cf = 0; cf < 4; ++cf) {
      int cr = cf * 16 + r15;
      #pragma unroll
      for (int kk = 0; kk < 2; ++kk) {
        bf16x8 bv = *reinterpret_cast<const bf16x8*>(vcur + cr * 128 + (((kk * 4 + l4) ^ (cr & 7)) << 4));
        osum[cf] = __builtin_amdgcn_mfma_f32_16x16x32_bf16(pa[kk], bv, osum[cf], 0, 0, 0);
      }
    }
    __syncthreads();
  }

  #pragma unroll
  for (int off = 1; off < 16; off <<= 1)
    #pragma unroll
    for (int r = 0; r < 4; ++r) lrow[r] += __shfl_xor(lrow[r], off);
  float linv[4];
  #pragma unroll
  for (int r = 0; r < 4; ++r) linv[r] = 1.f / lrow[r];

  #pragma unroll
  for (int cf = 0; cf < 4; ++cf) {
    int c = cf * 16 + r15;
    #pragma unroll
    for (int r = 0; r < 4; ++r) {
      int t = wave * 16 + l4 * 4 + r;
      *reinterpret_cast<float*>(ov + c * 256 + ((((t >> 2) ^ (c & 7)) << 4) | ((t & 3) * 4)))
          = osum[cf][r] * linv[r];
    }
  }
  __syncthreads();
  float* ap = a + ((size_t)b * Cc + hd * 64) * Tt + tl * 64;
  for (int u = TID; u < 1024; u += 256) {
    int c = u >> 4, tq = u & 15;
    float4 o4 = *reinterpret_cast<const float4*>(ov + c * 256 + ((tq ^ (c & 7)) << 4));
    *reinterpret_cast<float4*>(ap + (size_t)c * Tt + tq * 4) = o4;
  }
}

// ---------------- final: out = x + mish(gn(y2)) in-place on d_out (raw stats) ----------------
__global__ __launch_bounds__(256) void final_kernel(const float* __restrict__ x,
    float* __restrict__ y, const float* __restrict__ straw,
    const float* __restrict__ w, const float* __restrict__ bv) {
  size_t i = ((size_t)blockIdx.x * 256 + TID) * 4;
  int ch = (int)((i >> 10) & (Cc - 1));
  int b = (int)(i >> 19);
  int g = b * 8 + (ch >> 6);
  float rs = straw[2 * g], rq = straw[2 * g + 1];
  float mean = rs * (1.f / 65536.f);
  float rstd = rsqrtf(fmaxf(rq * (1.f / 65536.f) - mean * mean, 0.f) + 1e-5f);
  float sw = w[ch] * rstd;
  float sb = bv[ch] - mean * sw;
  float4 v  = *reinterpret_cast<const float4*>(y + i);
  float4 xv = *reinterpret_cast<const float4*>(x + i);
  v.x = xv.x + mishf(v.x * sw + sb);
  v.y = xv.y + mishf(v.y * sw + sb);
  v.z = xv.z + mishf(v.z * sw + sb);
  v.w = xv.w + mishf(v.w * sw + sb);
  *reinterpret_cast<float4*>(y + i) = v;
}

extern "C" void kernel_launch(void* const* d_in, const int* in_sizes, int n_in,
                              void* d_out, int out_size, void* d_ws, size_t ws_size,
                              hipStream_t stream) {
  const float* x     = (const float*)d_in[0];
  const float* gn_w  = (const float*)d_in[1];
  const float* gn_b  = (const float*)d_in[2];
  const float* wqkv  = (const float*)d_in[3];
  const float* bqkv  = (const float*)d_in[4];
  const float* gnq_w = (const float*)d_in[5];
  const float* gnq_b = (const float*)d_in[6];
  const float* wproj = (const float*)d_in[7];
  const float* bproj = (const float*)d_in[8];
  const float* gnp_w = (const float*)d_in[9];
  const float* gnp_b = (const float*)d_in[10];
  float* out = (float*)d_out;

  char* ws = (char*)d_ws;
  const size_t MB = 1024 * 1024;
  // Time-multiplexed workspace (<= 64MB):
  __hip_bfloat16* qkvb = (__hip_bfloat16*)ws;            // [0,24MB)   step4 -> step5
  float* hbuf = (float*)ws;                              // [0,16MB)   step6 -> step7 (qkvb dead)
  __hip_bfloat16* B4t = (__hip_bfloat16*)(ws + 24 * MB); // [24,56MB)  step7 -> step9
  __hip_bfloat16* A1  = (__hip_bfloat16*)(ws + 56 * MB); // [56,59MB)  step2 -> step4
  char* vimg = ws + 56 * MB;                             // [56,64MB)  step5 -> step6 (A1 dead)
  __hip_bfloat16* A2  = (__hip_bfloat16*)(ws + 56 * MB); // [56,58MB)  step8 -> step9 (vimg dead)
  float* st2raw = (float*)(ws + 64 * MB);                // 128 floats
  float* st3raw = st2raw + 128;                          // 128 floats
  __hip_bfloat16* B1t = (__hip_bfloat16*)d_out;          // d_out as B1t  step3 -> step4
  char* qTp  = (char*)d_out;                             // d_out[0,8MB)  step5 -> step6
  char* kimg = (char*)d_out + 8 * MB;                    // d_out[8,16MB) step5 -> step6

  dim3 blk(256);
  zero_stats<<<1, blk, 0, stream>>>(st2raw);                                       // 1 (zeros both)
  cast_bf16<<<1536, blk, 0, stream>>>(wqkv, A1, C3 * 1024);                        // 2
  gn1_im2col<<<256, blk, 0, stream>>>(x, gn_w, gn_b, B1t);                         // 3
  gemm_bt6<1024, 128, 192, 8, true><<<dim3(8, 12, 8), blk, 0, stream>>>(
      A1, B1t, bqkv, qkvb, st2raw, C3);                                            // 4
  gn2_prep<<<1024, blk, 0, stream>>>(qkvb, st2raw, gnq_w, gnq_b, qTp, kimg, vimg); // 5
  attn_mfma2<<<dim3(16, 64), blk, 0, stream>>>(qTp, kimg, vimg, hbuf);             // 6
  im2col_k4<<<256, blk, 0, stream>>>(hbuf, B4t);                                   // 7
  cast_bf16<<<1024, blk, 0, stream>>>(wproj, A2, Cc * 2048);                       // 8
  gemm_bt6<2048, 64, 64, 8, false><<<dim3(8, 8, 8), blk, 0, stream>>>(
      A2, B4t, bproj, out, st3raw, Cc);                                            // 9
  final_kernel<<<4096, blk, 0, stream>>>(x, out, st3raw, gnp_w, gnp_b);            // 10
}

// Round 10
// 316.515 us; speedup vs baseline: 1.1016x; 1.1016x over previous
//
#include <hip/hip_runtime.h>
#include <hip/hip_bf16.h>
#include <math.h>

#define TID threadIdx.x

constexpr int Cc = 512, Tt = 1024, C3 = 1536;

typedef __attribute__((ext_vector_type(8))) __bf16 bf16x8;
typedef __attribute__((ext_vector_type(4))) float f32x4;

__device__ __forceinline__ void async16(const void* g, void* l) {
  __builtin_amdgcn_global_load_lds(
      (const __attribute__((address_space(1))) unsigned int*)g,
      (__attribute__((address_space(3))) unsigned int*)l, 16, 0, 0);
}

__device__ __forceinline__ unsigned int pack2bf(float a, float b) {
  __hip_bfloat162 h;
  h.x = __float2bfloat16(a);
  h.y = __float2bfloat16(b);
  return *reinterpret_cast<unsigned int*>(&h);
}

__device__ __forceinline__ float bf2f(unsigned short u) {
  unsigned int t = ((unsigned int)u) << 16;
  union { unsigned int i; float f; } c;
  c.i = t;
  return c.f;
}

__device__ __forceinline__ float mishf(float x) {
  float sp = (x > 20.f) ? x : log1pf(__expf(x));
  return x * tanhf(sp);
}

__device__ __forceinline__ void blockReduce2(float& s, float& ss) {
  #pragma unroll
  for (int off = 32; off > 0; off >>= 1) {
    s  += __shfl_xor(s,  off);
    ss += __shfl_xor(ss, off);
  }
  __shared__ float ls[4], lss[4];
  int w = TID >> 6;
  if ((TID & 63) == 0) { ls[w] = s; lss[w] = ss; }
  __syncthreads();
  s  = ls[0] + ls[1] + ls[2] + ls[3];
  ss = lss[0] + lss[1] + lss[2] + lss[3];
}

// ---------------- zero the raw-stat accumulators (256 floats) ----------------
__global__ void zero_stats(float* p) { p[TID] = 0.f; }

// ---------------- fused GN(32) + im2col(K=2, pad_lo=0) -> bf16 B1t[b][t][k=2ci+j] ----------------
__global__ __launch_bounds__(256) void gn1_im2col(const float* __restrict__ x,
    const float* __restrict__ w, const float* __restrict__ bv,
    __hip_bfloat16* __restrict__ B1t) {
  __shared__ float hs[16][262];
  int blk = blockIdx.x, bb = blk >> 5, g = blk & 31;
  size_t base = ((size_t)bb * Cc + g * 16) * Tt;
  const float* xp = x + base;
  float s = 0.f, ss = 0.f;
  for (int i = TID * 4; i < 16 * Tt; i += 1024) {
    float4 v = *reinterpret_cast<const float4*>(xp + i);
    s  += v.x + v.y + v.z + v.w;
    ss += v.x * v.x + v.y * v.y + v.z * v.z + v.w * v.w;
  }
  blockReduce2(s, ss);
  float mean = s * (1.f / 16384.f);
  float rstd = rsqrtf(ss * (1.f / 16384.f) - mean * mean + 1e-5f);

  char* ob = reinterpret_cast<char*>(B1t + (size_t)bb * Tt * 1024 + g * 32);
  for (int tc = 0; tc < 4; ++tc) {
    int tbase = tc * 256;
    __syncthreads();
    for (int task = TID; task < 1024; task += 256) {
      int row = task >> 6, c4 = task & 63;
      int ch = g * 16 + row;
      float sw = w[ch] * rstd;
      float sb = bv[ch] - mean * sw;
      float4 v = *reinterpret_cast<const float4*>(xp + (size_t)row * Tt + tbase + c4 * 4);
      hs[row][c4 * 4 + 0] = v.x * sw + sb;
      hs[row][c4 * 4 + 1] = v.y * sw + sb;
      hs[row][c4 * 4 + 2] = v.z * sw + sb;
      hs[row][c4 * 4 + 3] = v.w * sw + sb;
    }
    if (TID < 16) {
      int row = TID, t = tbase + 256;
      float val = 0.f;
      if (t < Tt) {
        int ch = g * 16 + row;
        float sw = w[ch] * rstd;
        float sb = bv[ch] - mean * sw;
        val = xp[(size_t)row * Tt + t] * sw + sb;
      }
      hs[row][256] = val;
    }
    __syncthreads();
    for (int task = TID; task < 1024; task += 256) {
      int t = task >> 2, cj = task & 3;
      int ci = cj * 4;
      uint4 u;
      u.x = pack2bf(hs[ci + 0][t], hs[ci + 0][t + 1]);
      u.y = pack2bf(hs[ci + 1][t], hs[ci + 1][t + 1]);
      u.z = pack2bf(hs[ci + 2][t], hs[ci + 2][t + 1]);
      u.w = pack2bf(hs[ci + 3][t], hs[ci + 3][t + 1]);
      *reinterpret_cast<uint4*>(ob + ((size_t)(tbase + t) * 1024 + cj * 8) * 2) = u;
    }
  }
}

// ---------------- im2col(K=4, pad_lo=1) on attn output -> bf16 B4t[b][t][k=4ci+j], coalesced ----------------
__global__ __launch_bounds__(256) void im2col_k4(const float* __restrict__ a,
    __hip_bfloat16* __restrict__ B4t) {
  __shared__ float hs[16][266];
  int bb = blockIdx.x >> 5, cg = blockIdx.x & 31;
  const float* ab = a + ((size_t)bb * Cc + cg * 16) * Tt;
  char* ob = reinterpret_cast<char*>(B4t + (size_t)bb * Tt * 2048 + cg * 64);
  for (int tc = 0; tc < 4; ++tc) {
    int tbase = tc * 256;
    __syncthreads();
    for (int task = TID; task < 1024; task += 256) {
      int row = task >> 6, c4 = task & 63;
      float4 v = *reinterpret_cast<const float4*>(ab + (size_t)row * Tt + tbase + c4 * 4);
      hs[row][c4 * 4 + 1] = v.x;
      hs[row][c4 * 4 + 2] = v.y;
      hs[row][c4 * 4 + 3] = v.z;
      hs[row][c4 * 4 + 4] = v.w;
    }
    if (TID < 48) {
      int row = TID / 3, e = TID % 3;
      int t = (e == 0) ? tbase - 1 : tbase + 256 + (e - 1);
      float v = (t >= 0 && t < Tt) ? ab[(size_t)row * Tt + t] : 0.f;
      int col = (e == 0) ? 0 : 257 + (e - 1);
      hs[row][col] = v;
    }
    __syncthreads();
    for (int task = TID; task < 2048; task += 256) {
      int t = task >> 3, cj = task & 7;
      int ci = cj * 2;
      uint4 u;
      u.x = pack2bf(hs[ci][t],     hs[ci][t + 1]);
      u.y = pack2bf(hs[ci][t + 2], hs[ci][t + 3]);
      u.z = pack2bf(hs[ci + 1][t],     hs[ci + 1][t + 1]);
      u.w = pack2bf(hs[ci + 1][t + 2], hs[ci + 1][t + 3]);
      *reinterpret_cast<uint4*>(ob + ((size_t)(tbase + t) * 2048 + cj * 8) * 2) = u;
    }
  }
}

// ---------------- f32 -> bf16 cast (weights) ----------------
__global__ __launch_bounds__(256) void cast_bf16(const float* __restrict__ in,
    __hip_bfloat16* __restrict__ out, int n) {
  int i = (blockIdx.x * 256 + TID) * 4;
  if (i >= n) return;
  float4 v = *reinterpret_cast<const float4*>(in + i);
  *reinterpret_cast<unsigned int*>(out + i)     = pack2bf(v.x, v.y);
  *reinterpret_cast<unsigned int*>(out + i + 2) = pack2bf(v.z, v.w);
}

// ---------------- bf16 MFMA GEMM v7: R8 staging core + DUAL t-tile (NT=256, shared A stage),
//                  fused GN raw-stats (LDS-prereduced) + optional bf16 output -------------------
// C[b][o][t] = sum_k A[o][k] * Bt[b][t][k] + bias[o]
// MT=128: waves 2x2, NPT=4 (acc 4x8).  MT=64: waves 1x4, NPT=2 (acc 4x4).
template<int K, int MT, int NPT, int GROWS, int NGRP, bool BF16OUT>
__global__ __launch_bounds__(256) void gemm_bt7(const __hip_bfloat16* __restrict__ A,
    const __hip_bfloat16* __restrict__ Bt, const float* __restrict__ bias,
    void* __restrict__ Cout, float* __restrict__ statraw, int M) {
  constexpr int ACH = (MT / 16) * 2;       // A chunks of 1KB
  constexpr int NCH = ACH + 32;            // + B chunks for two 128-col tiles
  constexpr int NFW = 2 * NPT;             // n-fragments per wave (both tiles)
  constexpr int NKT = K / 64;
  __shared__ __align__(16) char lds[NCH * 1024];
  int t0 = blockIdx.x * 256, o0 = blockIdx.y * MT, bz = blockIdx.z;
  int wave = TID >> 6, lane = TID & 63;
  int l4 = lane >> 4, r15 = lane & 15;
  const __hip_bfloat16* Ab = A + (size_t)o0 * K;
  const __hip_bfloat16* Bb = Bt + ((size_t)bz * 1024 + t0) * K;
  int mbase = (MT == 128) ? (wave >> 1) * 4 : 0;
  int wn    = (MT == 128) ? (wave & 1) : wave;
  int nb    = wn * NPT;

  f32x4 acc[4][NFW];
  f32x4 zz = {0.f, 0.f, 0.f, 0.f};
  #pragma unroll
  for (int m = 0; m < 4; ++m)
    #pragma unroll
    for (int n = 0; n < NFW; ++n) acc[m][n] = zz;

  for (int kt = 0; kt < NKT; ++kt) {
    #pragma unroll
    for (int c = 0; c < NCH / 4; ++c) {
      int ch = c * 4 + wave;
      const __hip_bfloat16* src;
      int kof = kt * 64 + (((ch < ACH) ? (ch & 1) : (ch & 1))) * 32 + l4 * 8;
      if (ch < ACH) {
        int row = (ch >> 1) * 16 + r15;
        src = Ab + (size_t)row * K + kof;
      } else {
        int cb = ch - ACH;
        int j = cb >> 4, cl = cb & 15;
        int row = j * 128 + (cl >> 1) * 16 + r15;
        kof = kt * 64 + (cl & 1) * 32 + l4 * 8;
        src = Bb + (size_t)row * K + kof;
      }
      async16(src, lds + ch * 1024 + lane * 16);
    }
    __syncthreads();
    #pragma unroll
    for (int kk = 0; kk < 2; ++kk) {
      bf16x8 af[4], bfr[NFW];
      #pragma unroll
      for (int m = 0; m < 4; ++m)
        af[m] = *reinterpret_cast<const bf16x8*>(lds + ((mbase + m) * 2 + kk) * 1024 + lane * 16);
      #pragma unroll
      for (int j = 0; j < 2; ++j)
        #pragma unroll
        for (int l = 0; l < NPT; ++l)
          bfr[j * NPT + l] = *reinterpret_cast<const bf16x8*>(
              lds + (ACH + j * 16 + (nb + l) * 2 + kk) * 1024 + lane * 16);
      #pragma unroll
      for (int m = 0; m < 4; ++m)
        #pragma unroll
        for (int n = 0; n < NFW; ++n)
          acc[m][n] = __builtin_amdgcn_mfma_f32_16x16x32_bf16(af[m], bfr[n], acc[m][n], 0, 0, 0);
    }
    __syncthreads();
  }

  // epilogue: store (+bias); per-(wave,m) lane-reduced stats into LDS, then <=2 groups -> atomics
  float* sred = reinterpret_cast<float*>(lds);  // 32 floats, buffer is dead
  #pragma unroll
  for (int m = 0; m < 4; ++m) {
    float s = 0.f, ss2 = 0.f;
    #pragma unroll
    for (int n = 0; n < NFW; ++n) {
      int j = n / NPT, l = n % NPT;
      int ocol = t0 + j * 128 + (nb + l) * 16 + r15;
      #pragma unroll
      for (int r = 0; r < 4; ++r) {
        int orow = o0 + (mbase + m) * 16 + l4 * 4 + r;
        float v = acc[m][n][r] + bias[orow];
        if constexpr (BF16OUT)
          ((__hip_bfloat16*)Cout)[((size_t)bz * M + orow) * 1024 + ocol] = __float2bfloat16(v);
        else
          ((float*)Cout)[((size_t)bz * M + orow) * 1024 + ocol] = v;
        s += v;
        ss2 += v * v;
      }
    }
    #pragma unroll
    for (int off = 1; off < 64; off <<= 1) {
      s   += __shfl_xor(s, off);
      ss2 += __shfl_xor(ss2, off);
    }
    if (lane == 0) {
      sred[(wave * 4 + m) * 2]     = s;
      sred[(wave * 4 + m) * 2 + 1] = ss2;
    }
  }
  __syncthreads();
  if (TID < 2) {
    int g0 = o0 / GROWS;
    int gl = TID;
    float S = 0.f, SS = 0.f;
    int cnt = 0;
    #pragma unroll
    for (int slot = 0; slot < 16; ++slot) {
      int stripe = ((MT == 128) ? ((slot >> 3) << 2) : 0) + (slot & 3);
      int g = (o0 + stripe * 16) / GROWS;
      if (g == g0 + gl) {
        S  += sred[slot * 2];
        SS += sred[slot * 2 + 1];
        ++cnt;
      }
    }
    if (cnt) {
      atomicAdd(&statraw[2 * (bz * NGRP + g0 + gl)],     S);
      atomicAdd(&statraw[2 * (bz * NGRP + g0 + gl) + 1], SS);
    }
  }
}

// ---------------- fused GN(8)+Mish + build attn input images (bf16 qkv input, raw stats) ----------------
__global__ __launch_bounds__(256) void gn2_prep(const __hip_bfloat16* __restrict__ qkv,
    const float* __restrict__ straw, const float* __restrict__ w, const float* __restrict__ bv,
    char* __restrict__ qTp, char* __restrict__ kimg, char* __restrict__ vimg) {
  __shared__ unsigned short hbf[192 * 66];
  int tl = blockIdx.x & 15, hb = blockIdx.x >> 4;
  int b = hb >> 3, hd = hb & 7;
  float rs = straw[2 * (b * 8 + hd)], rq = straw[2 * (b * 8 + hd) + 1];
  float mean = rs * (1.f / 196608.f);
  float rstd = rsqrtf(fmaxf(rq * (1.f / 196608.f) - mean * mean, 0.f) + 1e-5f);
  for (int task = TID; task < 768; task += 256) {
    int row = task >> 2, seg = task & 3;
    int ch = hd * 192 + row;
    float sw = w[ch] * rstd;
    float sb = bv[ch] - mean * sw;
    const uint4* src = reinterpret_cast<const uint4*>(
        qkv + ((size_t)(b * C3 + ch)) * 1024 + tl * 64 + seg * 16);
    uint4 u0 = src[0], u1 = src[1];
    unsigned int uu[8] = {u0.x, u0.y, u0.z, u0.w, u1.x, u1.y, u1.z, u1.w};
    unsigned int* dst = reinterpret_cast<unsigned int*>(&hbf[row * 66 + seg * 16]);
    #pragma unroll
    for (int j = 0; j < 8; ++j) {
      float a = mishf(bf2f((unsigned short)(uu[j] & 0xffff)) * sw + sb);
      float c = mishf(bf2f((unsigned short)(uu[j] >> 16)) * sw + sb);
      dst[j] = pack2bf(a, c);
    }
  }
  __syncthreads();
  size_t tileof = ((size_t)hb * 16 + tl) * 8192;
  {
    int t = TID & 63, sel = TID >> 6;
    int img = sel >> 1, half = sel & 1;
    char* obase = (img == 0 ? qTp : kimg) + tileof + (size_t)t * 128;
    #pragma unroll
    for (int cc = 0; cc < 4; ++cc) {
      int chunk = half * 4 + cc;
      uint4 u;
      unsigned int* up = reinterpret_cast<unsigned int*>(&u);
      #pragma unroll
      for (int j = 0; j < 4; ++j) {
        int c = chunk * 8 + j * 2;
        unsigned int lo = hbf[(img * 64 + c) * 66 + t];
        unsigned int hi = hbf[(img * 64 + c + 1) * 66 + t];
        up[j] = lo | (hi << 16);
      }
      int cpos = (img == 0) ? chunk : (chunk ^ (t & 7));
      *reinterpret_cast<uint4*>(obase + cpos * 16) = u;
    }
  }
  {
    int c = TID & 63, qtr = TID >> 6;
    const unsigned int* vrow = reinterpret_cast<const unsigned int*>(&hbf[(128 + c) * 66]);
    char* obase = vimg + tileof + (size_t)c * 128;
    #pragma unroll
    for (int k = 0; k < 2; ++k) {
      int chunk = qtr * 2 + k;
      uint4 u;
      unsigned int* up = reinterpret_cast<unsigned int*>(&u);
      #pragma unroll
      for (int j = 0; j < 4; ++j) up[j] = vrow[chunk * 4 + j];
      *reinterpret_cast<uint4*>(obase + (chunk ^ (c & 7)) * 16) = u;
    }
  }
}

// ---------------- MFMA flash attention v2: async-staged images, double-buffered ----------------
__global__ __launch_bounds__(256) void attn_mfma2(const char* __restrict__ qTp,
    const char* __restrict__ kimg, const char* __restrict__ vimg,
    float* __restrict__ a) {
  __shared__ __align__(16) char smem[40960];
  char* kbuf0 = smem;
  char* kbuf1 = smem + 8192;
  char* vbuf0 = smem + 16384;
  char* vbuf1 = smem + 24576;
  char* pp    = smem + 32768;
  char* ov    = smem;

  int tl = blockIdx.x, hb = blockIdx.y;
  int b = hb >> 3, hd = hb & 7;
  int lane = TID & 63, wave = TID >> 6;
  int l4 = lane >> 4, r15 = lane & 15;
  size_t ibase = (size_t)hb * 16 * 8192;
  const char* ksrc = kimg + ibase;
  const char* vsrc = vimg + ibase;

  #pragma unroll
  for (int j = 0; j < 2; ++j) {
    int u = j * 256 + TID;
    async16(ksrc + u * 16, kbuf0 + u * 16);
    async16(vsrc + u * 16, vbuf0 + u * 16);
  }
  bf16x8 aq[2];
  int tg = wave * 16 + r15;
  const char* qrow = qTp + ibase + (size_t)tl * 8192 + (size_t)tg * 128;
  aq[0] = *reinterpret_cast<const bf16x8*>(qrow + l4 * 16);
  aq[1] = *reinterpret_cast<const bf16x8*>(qrow + 64 + l4 * 16);

  f32x4 osum[4];
  f32x4 zz = {0.f, 0.f, 0.f, 0.f};
  #pragma unroll
  for (int cf = 0; cf < 4; ++cf) osum[cf] = zz;
  float mrow[4] = {-1e30f, -1e30f, -1e30f, -1e30f};
  float lrow[4] = {0.f, 0.f, 0.f, 0.f};
  __syncthreads();

  for (int it = 0; it < 16; ++it) {
    char* kcur = (it & 1) ? kbuf1 : kbuf0;
    char* vcur = (it & 1) ? vbuf1 : vbuf0;
    if (it < 15) {
      char* knxt = (it & 1) ? kbuf0 : kbuf1;
      char* vnxt = (it & 1) ? vbuf0 : vbuf1;
      const char* kn = ksrc + (size_t)(it + 1) * 8192;
      const char* vn = vsrc + (size_t)(it + 1) * 8192;
      #pragma unroll
      for (int j = 0; j < 2; ++j) {
        int u = j * 256 + TID;
        async16(kn + u * 16, knxt + u * 16);
        async16(vn + u * 16, vnxt + u * 16);
      }
    }
    f32x4 sc[4];
    #pragma unroll
    for (int sf = 0; sf < 4; ++sf) sc[sf] = zz;
    #pragma unroll
    for (int sf = 0; sf < 4; ++sf) {
      int sr = sf * 16 + r15;
      #pragma unroll
      for (int kk = 0; kk < 2; ++kk) {
        bf16x8 bk = *reinterpret_cast<const bf16x8*>(kcur + sr * 128 + (((kk * 4 + l4) ^ (sr & 7)) << 4));
        sc[sf] = __builtin_amdgcn_mfma_f32_16x16x32_bf16(aq[kk], bk, sc[sf], 0, 0, 0);
      }
    }
    float tmax[4];
    #pragma unroll
    for (int r = 0; r < 4; ++r)
      tmax[r] = fmaxf(fmaxf(sc[0][r], sc[1][r]), fmaxf(sc[2][r], sc[3][r]));
    #pragma unroll
    for (int off = 1; off < 16; off <<= 1)
      #pragma unroll
      for (int r = 0; r < 4; ++r) tmax[r] = fmaxf(tmax[r], __shfl_xor(tmax[r], off));
    float alpha[4];
    #pragma unroll
    for (int r = 0; r < 4; ++r) {
      float mnew = fmaxf(mrow[r], tmax[r]);
      alpha[r] = __expf((mrow[r] - mnew) * 0.125f);
      mrow[r] = mnew;
      lrow[r] *= alpha[r];
    }
    #pragma unroll
    for (int cf = 0; cf < 4; ++cf)
      #pragma unroll
      for (int r = 0; r < 4; ++r) osum[cf][r] *= alpha[r];
    char* pw = pp + wave * 2048;
    float psum[4] = {0.f, 0.f, 0.f, 0.f};
    #pragma unroll
    for (int sf = 0; sf < 4; ++sf) {
      int s = sf * 16 + r15;
      #pragma unroll
      for (int r = 0; r < 4; ++r) {
        float p = __expf((sc[sf][r] - mrow[r]) * 0.125f);
        psum[r] += p;
        int tlc = l4 * 4 + r;
        *reinterpret_cast<__hip_bfloat16*>(pw + tlc * 128 + ((((s >> 3) ^ (tlc & 7)) << 4) | ((s & 7) * 2)))
            = __float2bfloat16(p);
      }
    }
    #pragma unroll
    for (int r = 0; r < 4; ++r) lrow[r] += psum[r];
    asm volatile("s_waitcnt lgkmcnt(0)" ::: "memory");
    __builtin_amdgcn_sched_barrier(0);

    bf16x8 pa[2];
    #pragma unroll
    for (int kk = 0; kk < 2; ++kk)
      pa[kk] = *reinterpret_cast<const bf16x8*>(pw + r15 * 128 + (((kk * 4 + l4) ^ (r15 & 7)) << 4));
    #pragma unroll
    for (int cf = 0; cf < 4; ++cf) {
      int cr = cf * 16 + r15;
      #pragma unroll
      for (int kk = 0; kk < 2; ++kk) {
        bf16x8 bv = *reinterpret_cast<const bf16x8*>(vcur + cr * 128 + (((kk * 4 + l4) ^ (cr & 7)) << 4));
        osum[cf] = __builtin_amdgcn_mfma_f32_16x16x32_bf16(pa[kk], bv, osum[cf], 0, 0, 0);
      }
    }
    __syncthreads();
  }

  #pragma unroll
  for (int off = 1; off < 16; off <<= 1)
    #pragma unroll
    for (int r = 0; r < 4; ++r) lrow[r] += __shfl_xor(lrow[r], off);
  float linv[4];
  #pragma unroll
  for (int r = 0; r < 4; ++r) linv[r] = 1.f / lrow[r];

  #pragma unroll
  for (int cf = 0; cf < 4; ++cf) {
    int c = cf * 16 + r15;
    #pragma unroll
    for (int r = 0; r < 4; ++r) {
      int t = wave * 16 + l4 * 4 + r;
      *reinterpret_cast<float*>(ov + c * 256 + ((((t >> 2) ^ (c & 7)) << 4) | ((t & 3) * 4)))
          = osum[cf][r] * linv[r];
    }
  }
  __syncthreads();
  float* ap = a + ((size_t)b * Cc + hd * 64) * Tt + tl * 64;
  for (int u = TID; u < 1024; u += 256) {
    int c = u >> 4, tq = u & 15;
    float4 o4 = *reinterpret_cast<const float4*>(ov + c * 256 + ((tq ^ (c & 7)) << 4));
    *reinterpret_cast<float4*>(ap + (size_t)c * Tt + tq * 4) = o4;
  }
}

// ---------------- final: out = x + mish(gn(y2)) in-place on d_out (raw stats) ----------------
__global__ __launch_bounds__(256) void final_kernel(const float* __restrict__ x,
    float* __restrict__ y, const float* __restrict__ straw,
    const float* __restrict__ w, const float* __restrict__ bv) {
  size_t i = ((size_t)blockIdx.x * 256 + TID) * 4;
  int ch = (int)((i >> 10) & (Cc - 1));
  int b = (int)(i >> 19);
  int g = b * 8 + (ch >> 6);
  float rs = straw[2 * g], rq = straw[2 * g + 1];
  float mean = rs * (1.f / 65536.f);
  float rstd = rsqrtf(fmaxf(rq * (1.f / 65536.f) - mean * mean, 0.f) + 1e-5f);
  float sw = w[ch] * rstd;
  float sb = bv[ch] - mean * sw;
  float4 v  = *reinterpret_cast<const float4*>(y + i);
  float4 xv = *reinterpret_cast<const float4*>(x + i);
  v.x = xv.x + mishf(v.x * sw + sb);
  v.y = xv.y + mishf(v.y * sw + sb);
  v.z = xv.z + mishf(v.z * sw + sb);
  v.w = xv.w + mishf(v.w * sw + sb);
  *reinterpret_cast<float4*>(y + i) = v;
}

extern "C" void kernel_launch(void* const* d_in, const int* in_sizes, int n_in,
                              void* d_out, int out_size, void* d_ws, size_t ws_size,
                              hipStream_t stream) {
  const float* x     = (const float*)d_in[0];
  const float* gn_w  = (const float*)d_in[1];
  const float* gn_b  = (const float*)d_in[2];
  const float* wqkv  = (const float*)d_in[3];
  const float* bqkv  = (const float*)d_in[4];
  const float* gnq_w = (const float*)d_in[5];
  const float* gnq_b = (const float*)d_in[6];
  const float* wproj = (const float*)d_in[7];
  const float* bproj = (const float*)d_in[8];
  const float* gnp_w = (const float*)d_in[9];
  const float* gnp_b = (const float*)d_in[10];
  float* out = (float*)d_out;

  char* ws = (char*)d_ws;
  const size_t MB = 1024 * 1024;
  // Time-multiplexed workspace (<= 64MB):
  __hip_bfloat16* qkvb = (__hip_bfloat16*)ws;            // [0,24MB)   step4 -> step5
  float* hbuf = (float*)ws;                              // [0,16MB)   step6 -> step7 (qkvb dead)
  __hip_bfloat16* B4t = (__hip_bfloat16*)(ws + 24 * MB); // [24,56MB)  step7 -> step9
  __hip_bfloat16* A1  = (__hip_bfloat16*)(ws + 56 * MB); // [56,59MB)  step2 -> step4
  char* vimg = ws + 56 * MB;                             // [56,64MB)  step5 -> step6 (A1 dead)
  __hip_bfloat16* A2  = (__hip_bfloat16*)(ws + 56 * MB); // [56,58MB)  step8 -> step9 (vimg dead)
  float* st2raw = (float*)(ws + 64 * MB);                // 128 floats
  float* st3raw = st2raw + 128;                          // 128 floats
  __hip_bfloat16* B1t = (__hip_bfloat16*)d_out;          // d_out as B1t  step3 -> step4
  char* qTp  = (char*)d_out;                             // d_out[0,8MB)  step5 -> step6
  char* kimg = (char*)d_out + 8 * MB;                    // d_out[8,16MB) step5 -> step6

  dim3 blk(256);
  zero_stats<<<1, blk, 0, stream>>>(st2raw);                                       // 1 (zeros both)
  cast_bf16<<<1536, blk, 0, stream>>>(wqkv, A1, C3 * 1024);                        // 2
  gn1_im2col<<<256, blk, 0, stream>>>(x, gn_w, gn_b, B1t);                         // 3
  gemm_bt7<1024, 128, 4, 192, 8, true><<<dim3(4, 12, 8), blk, 0, stream>>>(
      A1, B1t, bqkv, qkvb, st2raw, C3);                                            // 4
  gn2_prep<<<1024, blk, 0, stream>>>(qkvb, st2raw, gnq_w, gnq_b, qTp, kimg, vimg); // 5
  attn_mfma2<<<dim3(16, 64), blk, 0, stream>>>(qTp, kimg, vimg, hbuf);             // 6
  im2col_k4<<<256, blk, 0, stream>>>(hbuf, B4t);                                   // 7
  cast_bf16<<<1024, blk, 0, stream>>>(wproj, A2, Cc * 2048);                       // 8
  gemm_bt7<2048, 64, 2, 64, 8, false><<<dim3(4, 8, 8), blk, 0, stream>>>(
      A2, B4t, bproj, out, st3raw, Cc);                                            // 9
  final_kernel<<<4096, blk, 0, stream>>>(x, out, st3raw, gnp_w, gnp_b);            // 10
}

// Round 11
// 259.667 us; speedup vs baseline: 1.3428x; 1.2189x over previous
//
#include <hip/hip_runtime.h>
#include <hip/hip_bf16.h>
#include <math.h>

#define TID threadIdx.x

constexpr int Cc = 512, Tt = 1024, C3 = 1536;

typedef __attribute__((ext_vector_type(8))) __bf16 bf16x8;
typedef __attribute__((ext_vector_type(4))) float f32x4;

__device__ __forceinline__ void async16(const void* g, void* l) {
  __builtin_amdgcn_global_load_lds(
      (const __attribute__((address_space(1))) unsigned int*)g,
      (__attribute__((address_space(3))) unsigned int*)l, 16, 0, 0);
}

__device__ __forceinline__ unsigned int pack2bf(float a, float b) {
  __hip_bfloat162 h;
  h.x = __float2bfloat16(a);
  h.y = __float2bfloat16(b);
  return *reinterpret_cast<unsigned int*>(&h);
}

__device__ __forceinline__ float bf2f(unsigned short u) {
  unsigned int t = ((unsigned int)u) << 16;
  union { unsigned int i; float f; } c;
  c.i = t;
  return c.f;
}

__device__ __forceinline__ float mishf(float x) {
  float sp = (x > 20.f) ? x : log1pf(__expf(x));
  return x * tanhf(sp);
}

__device__ __forceinline__ void blockReduce2(float& s, float& ss) {
  #pragma unroll
  for (int off = 32; off > 0; off >>= 1) {
    s  += __shfl_xor(s,  off);
    ss += __shfl_xor(ss, off);
  }
  __shared__ float ls[4], lss[4];
  int w = TID >> 6;
  if ((TID & 63) == 0) { ls[w] = s; lss[w] = ss; }
  __syncthreads();
  s  = ls[0] + ls[1] + ls[2] + ls[3];
  ss = lss[0] + lss[1] + lss[2] + lss[3];
}

// ---------------- zero the raw-stat accumulators (256 floats) ----------------
__global__ void zero_stats(float* p) { p[TID] = 0.f; }

// ---------------- fused GN(32) + im2col(K=2, pad_lo=0) -> bf16 B1t[b][t][k=2ci+j] ----------------
__global__ __launch_bounds__(256) void gn1_im2col(const float* __restrict__ x,
    const float* __restrict__ w, const float* __restrict__ bv,
    __hip_bfloat16* __restrict__ B1t) {
  __shared__ float hs[16][262];
  int blk = blockIdx.x, bb = blk >> 5, g = blk & 31;
  size_t base = ((size_t)bb * Cc + g * 16) * Tt;
  const float* xp = x + base;
  float s = 0.f, ss = 0.f;
  for (int i = TID * 4; i < 16 * Tt; i += 1024) {
    float4 v = *reinterpret_cast<const float4*>(xp + i);
    s  += v.x + v.y + v.z + v.w;
    ss += v.x * v.x + v.y * v.y + v.z * v.z + v.w * v.w;
  }
  blockReduce2(s, ss);
  float mean = s * (1.f / 16384.f);
  float rstd = rsqrtf(ss * (1.f / 16384.f) - mean * mean + 1e-5f);

  char* ob = reinterpret_cast<char*>(B1t + (size_t)bb * Tt * 1024 + g * 32);
  for (int tc = 0; tc < 4; ++tc) {
    int tbase = tc * 256;
    __syncthreads();
    for (int task = TID; task < 1024; task += 256) {
      int row = task >> 6, c4 = task & 63;
      int ch = g * 16 + row;
      float sw = w[ch] * rstd;
      float sb = bv[ch] - mean * sw;
      float4 v = *reinterpret_cast<const float4*>(xp + (size_t)row * Tt + tbase + c4 * 4);
      hs[row][c4 * 4 + 0] = v.x * sw + sb;
      hs[row][c4 * 4 + 1] = v.y * sw + sb;
      hs[row][c4 * 4 + 2] = v.z * sw + sb;
      hs[row][c4 * 4 + 3] = v.w * sw + sb;
    }
    if (TID < 16) {
      int row = TID, t = tbase + 256;
      float val = 0.f;
      if (t < Tt) {
        int ch = g * 16 + row;
        float sw = w[ch] * rstd;
        float sb = bv[ch] - mean * sw;
        val = xp[(size_t)row * Tt + t] * sw + sb;
      }
      hs[row][256] = val;
    }
    __syncthreads();
    for (int task = TID; task < 1024; task += 256) {
      int t = task >> 2, cj = task & 3;
      int ci = cj * 4;
      uint4 u;
      u.x = pack2bf(hs[ci + 0][t], hs[ci + 0][t + 1]);
      u.y = pack2bf(hs[ci + 1][t], hs[ci + 1][t + 1]);
      u.z = pack2bf(hs[ci + 2][t], hs[ci + 2][t + 1]);
      u.w = pack2bf(hs[ci + 3][t], hs[ci + 3][t + 1]);
      *reinterpret_cast<uint4*>(ob + ((size_t)(tbase + t) * 1024 + cj * 8) * 2) = u;
    }
  }
}

// ---------------- im2col(K=4, pad_lo=1) on attn output -> bf16 B4t[b][t][k=4ci+j], coalesced ----------------
__global__ __launch_bounds__(256) void im2col_k4(const float* __restrict__ a,
    __hip_bfloat16* __restrict__ B4t) {
  __shared__ float hs[16][266];
  int bb = blockIdx.x >> 5, cg = blockIdx.x & 31;
  const float* ab = a + ((size_t)bb * Cc + cg * 16) * Tt;
  char* ob = reinterpret_cast<char*>(B4t + (size_t)bb * Tt * 2048 + cg * 64);
  for (int tc = 0; tc < 4; ++tc) {
    int tbase = tc * 256;
    __syncthreads();
    for (int task = TID; task < 1024; task += 256) {
      int row = task >> 6, c4 = task & 63;
      float4 v = *reinterpret_cast<const float4*>(ab + (size_t)row * Tt + tbase + c4 * 4);
      hs[row][c4 * 4 + 1] = v.x;
      hs[row][c4 * 4 + 2] = v.y;
      hs[row][c4 * 4 + 3] = v.z;
      hs[row][c4 * 4 + 4] = v.w;
    }
    if (TID < 48) {
      int row = TID / 3, e = TID % 3;
      int t = (e == 0) ? tbase - 1 : tbase + 256 + (e - 1);
      float v = (t >= 0 && t < Tt) ? ab[(size_t)row * Tt + t] : 0.f;
      int col = (e == 0) ? 0 : 257 + (e - 1);
      hs[row][col] = v;
    }
    __syncthreads();
    for (int task = TID; task < 2048; task += 256) {
      int t = task >> 3, cj = task & 7;
      int ci = cj * 2;
      uint4 u;
      u.x = pack2bf(hs[ci][t],     hs[ci][t + 1]);
      u.y = pack2bf(hs[ci][t + 2], hs[ci][t + 3]);
      u.z = pack2bf(hs[ci + 1][t],     hs[ci + 1][t + 1]);
      u.w = pack2bf(hs[ci + 1][t + 2], hs[ci + 1][t + 3]);
      *reinterpret_cast<uint4*>(ob + ((size_t)(tbase + t) * 2048 + cj * 8) * 2) = u;
    }
  }
}

// ---------------- f32 -> bf16 cast (weights) ----------------
__global__ __launch_bounds__(256) void cast_bf16(const float* __restrict__ in,
    __hip_bfloat16* __restrict__ out, int n) {
  int i = (blockIdx.x * 256 + TID) * 4;
  if (i >= n) return;
  float4 v = *reinterpret_cast<const float4*>(in + i);
  *reinterpret_cast<unsigned int*>(out + i)     = pack2bf(v.x, v.y);
  *reinterpret_cast<unsigned int*>(out + i + 2) = pack2bf(v.z, v.w);
}

// ---------------- bf16 MFMA GEMM v8: 512 threads, BM=256 x BN=128, bt5-style single buffer,
//                  fragment-ordered chunks, fused GN raw stats + bf16 out --------------------
template<int K, int GROWS, int NGRP, bool BF16OUT>
__global__ __launch_bounds__(512, 4) void gemm_bt8(const __hip_bfloat16* __restrict__ A,
    const __hip_bfloat16* __restrict__ Bt, const float* __restrict__ bias,
    void* __restrict__ Cout, float* __restrict__ statraw, int M) {
  constexpr int NKT = K / 64;
  __shared__ __align__(16) char lds[48 * 1024];   // 32 A-chunks + 16 B-chunks of 1KB
  int t0 = blockIdx.x * 128, o0 = blockIdx.y * 256, bz = blockIdx.z;
  int wave = TID >> 6, lane = TID & 63;
  int l4 = lane >> 4, r15 = lane & 15;
  int wm = wave >> 1, wn = wave & 1;              // 4 M-waves x 2 N-waves
  const __hip_bfloat16* Ab = A + (size_t)o0 * K;
  const __hip_bfloat16* Bb = Bt + ((size_t)bz * 1024 + t0) * K;

  f32x4 acc[4][4];
  f32x4 zz = {0.f, 0.f, 0.f, 0.f};
  #pragma unroll
  for (int m = 0; m < 4; ++m)
    #pragma unroll
    for (int n = 0; n < 4; ++n) acc[m][n] = zz;

  for (int kt = 0; kt < NKT; ++kt) {
    #pragma unroll
    for (int c = 0; c < 6; ++c) {
      int ch = c * 8 + wave;
      int kof = kt * 64 + (ch & 1) * 32 + l4 * 8;
      const __hip_bfloat16* src;
      if (ch < 32) {
        int row = (ch >> 1) * 16 + r15;
        src = Ab + (size_t)row * K + kof;
      } else {
        int row = ((ch - 32) >> 1) * 16 + r15;
        src = Bb + (size_t)row * K + kof;
      }
      async16(src, lds + ch * 1024 + lane * 16);
    }
    __syncthreads();
    #pragma unroll
    for (int kk = 0; kk < 2; ++kk) {
      bf16x8 af[4], bfr[4];
      #pragma unroll
      for (int m = 0; m < 4; ++m)
        af[m] = *reinterpret_cast<const bf16x8*>(lds + ((wm * 4 + m) * 2 + kk) * 1024 + lane * 16);
      #pragma unroll
      for (int n = 0; n < 4; ++n)
        bfr[n] = *reinterpret_cast<const bf16x8*>(lds + (32 + (wn * 4 + n) * 2 + kk) * 1024 + lane * 16);
      #pragma unroll
      for (int m = 0; m < 4; ++m)
        #pragma unroll
        for (int n = 0; n < 4; ++n)
          acc[m][n] = __builtin_amdgcn_mfma_f32_16x16x32_bf16(af[m], bfr[n], acc[m][n], 0, 0, 0);
    }
    __syncthreads();
  }

  // epilogue: store (+bias), per-(wave,m) lane-reduced stats -> LDS -> <=2 group atomics
  float* sred = reinterpret_cast<float*>(lds);  // 64 floats, buffer dead
  #pragma unroll
  for (int m = 0; m < 4; ++m) {
    float s = 0.f, ss2 = 0.f;
    #pragma unroll
    for (int n = 0; n < 4; ++n) {
      int ocol = t0 + (wn * 4 + n) * 16 + r15;
      #pragma unroll
      for (int r = 0; r < 4; ++r) {
        int orow = o0 + (wm * 4 + m) * 16 + l4 * 4 + r;
        float v = acc[m][n][r] + bias[orow];
        if constexpr (BF16OUT)
          ((__hip_bfloat16*)Cout)[((size_t)bz * M + orow) * 1024 + ocol] = __float2bfloat16(v);
        else
          ((float*)Cout)[((size_t)bz * M + orow) * 1024 + ocol] = v;
        s += v;
        ss2 += v * v;
      }
    }
    #pragma unroll
    for (int off = 1; off < 64; off <<= 1) {
      s   += __shfl_xor(s, off);
      ss2 += __shfl_xor(ss2, off);
    }
    if (lane == 0) {
      sred[(wave * 4 + m) * 2]     = s;
      sred[(wave * 4 + m) * 2 + 1] = ss2;
    }
  }
  __syncthreads();
  if (TID < 2) {
    int g0 = o0 / GROWS;
    float S = 0.f, SS = 0.f;
    int cnt = 0;
    #pragma unroll
    for (int slot = 0; slot < 32; ++slot) {
      int w = slot >> 2, m = slot & 3;
      int rc = (w >> 1) * 4 + m;
      int g = (o0 + rc * 16) / GROWS;
      if (g == g0 + (int)TID && g < NGRP) {
        S  += sred[slot * 2];
        SS += sred[slot * 2 + 1];
        ++cnt;
      }
    }
    if (cnt) {
      atomicAdd(&statraw[2 * (bz * NGRP + g0 + TID)],     S);
      atomicAdd(&statraw[2 * (bz * NGRP + g0 + TID) + 1], SS);
    }
  }
}

// ---------------- bf16 MFMA GEMM v5 (R8-proven): MT x 128, single buffer, fused stats ----------
template<int K, int MT, int GROWS, int NGRP, bool BF16OUT>
__global__ __launch_bounds__(256) void gemm_bt5(const __hip_bfloat16* __restrict__ A,
    const __hip_bfloat16* __restrict__ Bt, const float* __restrict__ bias,
    void* __restrict__ Cout, float* __restrict__ statraw, int M) {
  constexpr int ACH = (MT / 16) * 2;
  constexpr int NCH = ACH + 16;
  constexpr int NF  = (MT == 128) ? 4 : 2;
  __shared__ __align__(16) char lds[NCH * 1024];
  int t0 = blockIdx.x * 128, o0 = blockIdx.y * MT, bz = blockIdx.z;
  int wave = TID >> 6, lane = TID & 63;
  int l4 = lane >> 4, r15 = lane & 15;
  const __hip_bfloat16* Ab = A + (size_t)o0 * K;
  const __hip_bfloat16* Bb = Bt + ((size_t)bz * 1024 + t0) * K;
  int mbase = (MT == 128) ? (wave >> 1) * 4 : 0;
  int nbase = (MT == 128) ? (wave & 1) * 4 : wave * 2;

  f32x4 acc[4][NF];
  f32x4 zz = {0.f, 0.f, 0.f, 0.f};
  #pragma unroll
  for (int m = 0; m < 4; ++m)
    #pragma unroll
    for (int n = 0; n < NF; ++n) acc[m][n] = zz;

  for (int kt = 0; kt < K / 64; ++kt) {
    #pragma unroll
    for (int c = 0; c < NCH / 4; ++c) {
      int ch = c * 4 + wave;
      int cl = (ch < ACH) ? ch : ch - ACH;
      int row = (cl >> 1) * 16 + r15;
      int kof = kt * 64 + (cl & 1) * 32 + l4 * 8;
      const __hip_bfloat16* src = (ch < ACH) ? (Ab + (size_t)row * K + kof)
                                             : (Bb + (size_t)row * K + kof);
      async16(src, lds + ch * 1024 + lane * 16);
    }
    __syncthreads();
    #pragma unroll
    for (int kk = 0; kk < 2; ++kk) {
      bf16x8 af[4], bfr[NF];
      #pragma unroll
      for (int m = 0; m < 4; ++m)
        af[m] = *reinterpret_cast<const bf16x8*>(lds + ((mbase + m) * 2 + kk) * 1024 + lane * 16);
      #pragma unroll
      for (int n = 0; n < NF; ++n)
        bfr[n] = *reinterpret_cast<const bf16x8*>(lds + (ACH + (nbase + n) * 2 + kk) * 1024 + lane * 16);
      #pragma unroll
      for (int m = 0; m < 4; ++m)
        #pragma unroll
        for (int n = 0; n < NF; ++n)
          acc[m][n] = __builtin_amdgcn_mfma_f32_16x16x32_bf16(af[m], bfr[n], acc[m][n], 0, 0, 0);
    }
    __syncthreads();
  }

  float* sred = reinterpret_cast<float*>(lds);
  #pragma unroll
  for (int m = 0; m < 4; ++m) {
    float s = 0.f, ss2 = 0.f;
    #pragma unroll
    for (int n = 0; n < NF; ++n) {
      int ocol = t0 + (nbase + n) * 16 + r15;
      #pragma unroll
      for (int r = 0; r < 4; ++r) {
        int orow = o0 + (mbase + m) * 16 + l4 * 4 + r;
        float v = acc[m][n][r] + bias[orow];
        if constexpr (BF16OUT)
          ((__hip_bfloat16*)Cout)[((size_t)bz * M + orow) * 1024 + ocol] = __float2bfloat16(v);
        else
          ((float*)Cout)[((size_t)bz * M + orow) * 1024 + ocol] = v;
        s += v;
        ss2 += v * v;
      }
    }
    #pragma unroll
    for (int off = 1; off < 64; off <<= 1) {
      s   += __shfl_xor(s, off);
      ss2 += __shfl_xor(ss2, off);
    }
    if (lane == 0) {
      sred[(wave * 4 + m) * 2]     = s;
      sred[(wave * 4 + m) * 2 + 1] = ss2;
    }
  }
  __syncthreads();
  if (TID < 2) {
    int g0 = o0 / GROWS;
    int gl = TID;
    float S = 0.f, SS = 0.f;
    int cnt = 0;
    #pragma unroll
    for (int slot = 0; slot < 16; ++slot) {
      int stripe = ((MT == 128) ? ((slot >> 3) << 2) : 0) + (slot & 3);
      int g = (o0 + stripe * 16) / GROWS;
      if (g == g0 + gl && g < NGRP) {
        S  += sred[slot * 2];
        SS += sred[slot * 2 + 1];
        ++cnt;
      }
    }
    if (cnt) {
      atomicAdd(&statraw[2 * (bz * NGRP + g0 + gl)],     S);
      atomicAdd(&statraw[2 * (bz * NGRP + g0 + gl) + 1], SS);
    }
  }
}

// ---------------- fused GN(8)+Mish + build attn input images (bf16 qkv input, raw stats) ----------------
__global__ __launch_bounds__(256) void gn2_prep(const __hip_bfloat16* __restrict__ qkv,
    const float* __restrict__ straw, const float* __restrict__ w, const float* __restrict__ bv,
    char* __restrict__ qTp, char* __restrict__ kimg, char* __restrict__ vimg) {
  __shared__ unsigned short hbf[192 * 66];
  int tl = blockIdx.x & 15, hb = blockIdx.x >> 4;
  int b = hb >> 3, hd = hb & 7;
  float rs = straw[2 * (b * 8 + hd)], rq = straw[2 * (b * 8 + hd) + 1];
  float mean = rs * (1.f / 196608.f);
  float rstd = rsqrtf(fmaxf(rq * (1.f / 196608.f) - mean * mean, 0.f) + 1e-5f);
  for (int task = TID; task < 768; task += 256) {
    int row = task >> 2, seg = task & 3;
    int ch = hd * 192 + row;
    float sw = w[ch] * rstd;
    float sb = bv[ch] - mean * sw;
    const uint4* src = reinterpret_cast<const uint4*>(
        qkv + ((size_t)(b * C3 + ch)) * 1024 + tl * 64 + seg * 16);
    uint4 u0 = src[0], u1 = src[1];
    unsigned int uu[8] = {u0.x, u0.y, u0.z, u0.w, u1.x, u1.y, u1.z, u1.w};
    unsigned int* dst = reinterpret_cast<unsigned int*>(&hbf[row * 66 + seg * 16]);
    #pragma unroll
    for (int j = 0; j < 8; ++j) {
      float a = mishf(bf2f((unsigned short)(uu[j] & 0xffff)) * sw + sb);
      float c = mishf(bf2f((unsigned short)(uu[j] >> 16)) * sw + sb);
      dst[j] = pack2bf(a, c);
    }
  }
  __syncthreads();
  size_t tileof = ((size_t)hb * 16 + tl) * 8192;
  {
    int t = TID & 63, sel = TID >> 6;
    int img = sel >> 1, half = sel & 1;
    char* obase = (img == 0 ? qTp : kimg) + tileof + (size_t)t * 128;
    #pragma unroll
    for (int cc = 0; cc < 4; ++cc) {
      int chunk = half * 4 + cc;
      uint4 u;
      unsigned int* up = reinterpret_cast<unsigned int*>(&u);
      #pragma unroll
      for (int j = 0; j < 4; ++j) {
        int c = chunk * 8 + j * 2;
        unsigned int lo = hbf[(img * 64 + c) * 66 + t];
        unsigned int hi = hbf[(img * 64 + c + 1) * 66 + t];
        up[j] = lo | (hi << 16);
      }
      int cpos = (img == 0) ? chunk : (chunk ^ (t & 7));
      *reinterpret_cast<uint4*>(obase + cpos * 16) = u;
    }
  }
  {
    int c = TID & 63, qtr = TID >> 6;
    const unsigned int* vrow = reinterpret_cast<const unsigned int*>(&hbf[(128 + c) * 66]);
    char* obase = vimg + tileof + (size_t)c * 128;
    #pragma unroll
    for (int k = 0; k < 2; ++k) {
      int chunk = qtr * 2 + k;
      uint4 u;
      unsigned int* up = reinterpret_cast<unsigned int*>(&u);
      #pragma unroll
      for (int j = 0; j < 4; ++j) up[j] = vrow[chunk * 4 + j];
      *reinterpret_cast<uint4*>(obase + (chunk ^ (c & 7)) * 16) = u;
    }
  }
}

// ---------------- MFMA flash attention v3: 512 threads, 2 q-tiles/block (halved K/V re-reads) ----------------
__global__ __launch_bounds__(512) void attn_mfma3(const char* __restrict__ qTp,
    const char* __restrict__ kimg, const char* __restrict__ vimg,
    float* __restrict__ a) {
  __shared__ __align__(16) char smem[49152];
  char* kbuf0 = smem;
  char* kbuf1 = smem + 8192;
  char* vbuf0 = smem + 16384;
  char* vbuf1 = smem + 24576;
  char* pp    = smem + 32768;  // 8 waves x 2KB
  char* ov    = smem;          // 32KB alias over K/V buffers

  int hb = blockIdx.y;
  int b = hb >> 3, hd = hb & 7;
  int lane = TID & 63, wave = TID >> 6;
  int qt = wave >> 2, qw = wave & 3;   // q-tile pair member, quarter within tile
  int l4 = lane >> 4, r15 = lane & 15;
  size_t ibase = (size_t)hb * 16 * 8192;
  const char* ksrc = kimg + ibase;
  const char* vsrc = vimg + ibase;

  async16(ksrc + (size_t)TID * 16, kbuf0 + (size_t)TID * 16);
  async16(vsrc + (size_t)TID * 16, vbuf0 + (size_t)TID * 16);

  bf16x8 aq[2];
  int tg = qw * 16 + r15;
  const char* qrow = qTp + ibase + (size_t)(blockIdx.x * 2 + qt) * 8192 + (size_t)tg * 128;
  aq[0] = *reinterpret_cast<const bf16x8*>(qrow + l4 * 16);
  aq[1] = *reinterpret_cast<const bf16x8*>(qrow + 64 + l4 * 16);

  f32x4 osum[4];
  f32x4 zz = {0.f, 0.f, 0.f, 0.f};
  #pragma unroll
  for (int cf = 0; cf < 4; ++cf) osum[cf] = zz;
  float mrow[4] = {-1e30f, -1e30f, -1e30f, -1e30f};
  float lrow[4] = {0.f, 0.f, 0.f, 0.f};
  __syncthreads();

  for (int it = 0; it < 16; ++it) {
    char* kcur = (it & 1) ? kbuf1 : kbuf0;
    char* vcur = (it & 1) ? vbuf1 : vbuf0;
    if (it < 15) {
      char* knxt = (it & 1) ? kbuf0 : kbuf1;
      char* vnxt = (it & 1) ? vbuf0 : vbuf1;
      const char* kn = ksrc + (size_t)(it + 1) * 8192;
      const char* vn = vsrc + (size_t)(it + 1) * 8192;
      async16(kn + (size_t)TID * 16, knxt + (size_t)TID * 16);
      async16(vn + (size_t)TID * 16, vnxt + (size_t)TID * 16);
    }
    f32x4 sc[4];
    #pragma unroll
    for (int sf = 0; sf < 4; ++sf) sc[sf] = zz;
    #pragma unroll
    for (int sf = 0; sf < 4; ++sf) {
      int sr = sf * 16 + r15;
      #pragma unroll
      for (int kk = 0; kk < 2; ++kk) {
        bf16x8 bk = *reinterpret_cast<const bf16x8*>(kcur + sr * 128 + (((kk * 4 + l4) ^ (sr & 7)) << 4));
        sc[sf] = __builtin_amdgcn_mfma_f32_16x16x32_bf16(aq[kk], bk, sc[sf], 0, 0, 0);
      }
    }
    float tmax[4];
    #pragma unroll
    for (int r = 0; r < 4; ++r)
      tmax[r] = fmaxf(fmaxf(sc[0][r], sc[1][r]), fmaxf(sc[2][r], sc[3][r]));
    #pragma unroll
    for (int off = 1; off < 16; off <<= 1)
      #pragma unroll
      for (int r = 0; r < 4; ++r) tmax[r] = fmaxf(tmax[r], __shfl_xor(tmax[r], off));
    float alpha[4];
    #pragma unroll
    for (int r = 0; r < 4; ++r) {
      float mnew = fmaxf(mrow[r], tmax[r]);
      alpha[r] = __expf((mrow[r] - mnew) * 0.125f);
      mrow[r] = mnew;
      lrow[r] *= alpha[r];
    }
    #pragma unroll
    for (int cf = 0; cf < 4; ++cf)
      #pragma unroll
      for (int r = 0; r < 4; ++r) osum[cf][r] *= alpha[r];
    char* pw = pp + wave * 2048;
    float psum[4] = {0.f, 0.f, 0.f, 0.f};
    #pragma unroll
    for (int sf = 0; sf < 4; ++sf) {
      int s = sf * 16 + r15;
      #pragma unroll
      for (int r = 0; r < 4; ++r) {
        float p = __expf((sc[sf][r] - mrow[r]) * 0.125f);
        psum[r] += p;
        int tlc = l4 * 4 + r;
        *reinterpret_cast<__hip_bfloat16*>(pw + tlc * 128 + ((((s >> 3) ^ (tlc & 7)) << 4) | ((s & 7) * 2)))
            = __float2bfloat16(p);
      }
    }
    #pragma unroll
    for (int r = 0; r < 4; ++r) lrow[r] += psum[r];
    asm volatile("s_waitcnt lgkmcnt(0)" ::: "memory");
    __builtin_amdgcn_sched_barrier(0);

    bf16x8 pa[2];
    #pragma unroll
    for (int kk = 0; kk < 2; ++kk)
      pa[kk] = *reinterpret_cast<const bf16x8*>(pw + r15 * 128 + (((kk * 4 + l4) ^ (r15 & 7)) << 4));
    #pragma unroll
    for (int cf = 0; cf < 4; ++cf) {
      int cr = cf * 16 + r15;
      #pragma unroll
      for (int kk = 0; kk < 2; ++kk) {
        bf16x8 bv = *reinterpret_cast<const bf16x8*>(vcur + cr * 128 + (((kk * 4 + l4) ^ (cr & 7)) << 4));
        osum[cf] = __builtin_amdgcn_mfma_f32_16x16x32_bf16(pa[kk], bv, osum[cf], 0, 0, 0);
      }
    }
    __syncthreads();
  }

  #pragma unroll
  for (int off = 1; off < 16; off <<= 1)
    #pragma unroll
    for (int r = 0; r < 4; ++r) lrow[r] += __shfl_xor(lrow[r], off);
  float linv[4];
  #pragma unroll
  for (int r = 0; r < 4; ++r) linv[r] = 1.f / lrow[r];

  // ov[c][t] f32, c in [0,64), t in [0,128), chunk-swizzled
  #pragma unroll
  for (int cf = 0; cf < 4; ++cf) {
    int c = cf * 16 + r15;
    #pragma unroll
    for (int r = 0; r < 4; ++r) {
      int t = qt * 64 + qw * 16 + l4 * 4 + r;
      *reinterpret_cast<float*>(ov + c * 512 + ((((t >> 2) ^ (c & 7)) << 4) | ((t & 3) * 4)))
          = osum[cf][r] * linv[r];
    }
  }
  __syncthreads();
  float* ap = a + ((size_t)b * Cc + hd * 64) * Tt + blockIdx.x * 128;
  for (int u = TID; u < 2048; u += 512) {
    int c = u >> 5, tq = u & 31;
    float4 o4 = *reinterpret_cast<const float4*>(ov + c * 512 + ((tq ^ (c & 7)) << 4));
    *reinterpret_cast<float4*>(ap + (size_t)c * Tt + tq * 4) = o4;
  }
}

// ---------------- final: out = x + mish(gn(y2)) in-place on d_out (raw stats) ----------------
__global__ __launch_bounds__(256) void final_kernel(const float* __restrict__ x,
    float* __restrict__ y, const float* __restrict__ straw,
    const float* __restrict__ w, const float* __restrict__ bv) {
  size_t i = ((size_t)blockIdx.x * 256 + TID) * 4;
  int ch = (int)((i >> 10) & (Cc - 1));
  int b = (int)(i >> 19);
  int g = b * 8 + (ch >> 6);
  float rs = straw[2 * g], rq = straw[2 * g + 1];
  float mean = rs * (1.f / 65536.f);
  float rstd = rsqrtf(fmaxf(rq * (1.f / 65536.f) - mean * mean, 0.f) + 1e-5f);
  float sw = w[ch] * rstd;
  float sb = bv[ch] - mean * sw;
  float4 v  = *reinterpret_cast<const float4*>(y + i);
  float4 xv = *reinterpret_cast<const float4*>(x + i);
  v.x = xv.x + mishf(v.x * sw + sb);
  v.y = xv.y + mishf(v.y * sw + sb);
  v.z = xv.z + mishf(v.z * sw + sb);
  v.w = xv.w + mishf(v.w * sw + sb);
  *reinterpret_cast<float4*>(y + i) = v;
}

extern "C" void kernel_launch(void* const* d_in, const int* in_sizes, int n_in,
                              void* d_out, int out_size, void* d_ws, size_t ws_size,
                              hipStream_t stream) {
  const float* x     = (const float*)d_in[0];
  const float* gn_w  = (const float*)d_in[1];
  const float* gn_b  = (const float*)d_in[2];
  const float* wqkv  = (const float*)d_in[3];
  const float* bqkv  = (const float*)d_in[4];
  const float* gnq_w = (const float*)d_in[5];
  const float* gnq_b = (const float*)d_in[6];
  const float* wproj = (const float*)d_in[7];
  const float* bproj = (const float*)d_in[8];
  const float* gnp_w = (const float*)d_in[9];
  const float* gnp_b = (const float*)d_in[10];
  float* out = (float*)d_out;

  char* ws = (char*)d_ws;
  const size_t MB = 1024 * 1024;
  // Time-multiplexed workspace (<= 64MB):
  __hip_bfloat16* qkvb = (__hip_bfloat16*)ws;            // [0,24MB)   step4 -> step5
  float* hbuf = (float*)ws;                              // [0,16MB)   step6 -> step7 (qkvb dead)
  __hip_bfloat16* B4t = (__hip_bfloat16*)(ws + 24 * MB); // [24,56MB)  step7 -> step9
  __hip_bfloat16* A1  = (__hip_bfloat16*)(ws + 56 * MB); // [56,59MB)  step2 -> step4
  char* vimg = ws + 56 * MB;                             // [56,64MB)  step5 -> step6 (A1 dead)
  __hip_bfloat16* A2  = (__hip_bfloat16*)(ws + 56 * MB); // [56,58MB)  step8 -> step9 (vimg dead)
  float* st2raw = (float*)(ws + 64 * MB);                // 128 floats
  float* st3raw = st2raw + 128;                          // 128 floats
  __hip_bfloat16* B1t = (__hip_bfloat16*)d_out;          // d_out as B1t  step3 -> step4
  char* qTp  = (char*)d_out;                             // d_out[0,8MB)  step5 -> step6
  char* kimg = (char*)d_out + 8 * MB;                    // d_out[8,16MB) step5 -> step6

  dim3 blk(256);
  zero_stats<<<1, blk, 0, stream>>>(st2raw);                                       // 1 (zeros both)
  cast_bf16<<<1536, blk, 0, stream>>>(wqkv, A1, C3 * 1024);                        // 2
  gn1_im2col<<<256, blk, 0, stream>>>(x, gn_w, gn_b, B1t);                         // 3
  gemm_bt8<1024, 192, 8, true><<<dim3(8, 6, 8), dim3(512), 0, stream>>>(
      A1, B1t, bqkv, qkvb, st2raw, C3);                                            // 4
  gn2_prep<<<1024, blk, 0, stream>>>(qkvb, st2raw, gnq_w, gnq_b, qTp, kimg, vimg); // 5
  attn_mfma3<<<dim3(8, 64), dim3(512), 0, stream>>>(qTp, kimg, vimg, hbuf);        // 6
  im2col_k4<<<256, blk, 0, stream>>>(hbuf, B4t);                                   // 7
  cast_bf16<<<1024, blk, 0, stream>>>(wproj, A2, Cc * 2048);                       // 8
  gemm_bt5<2048, 64, 64, 8, false><<<dim3(8, 8, 8), blk, 0, stream>>>(
      A2, B4t, bproj, out, st3raw, Cc);                                            // 9
  final_kernel<<<4096, blk, 0, stream>>>(x, out, st3raw, gnp_w, gnp_b);            // 10
}

// Round 12
// 214.386 us; speedup vs baseline: 1.6264x; 1.2112x over previous
//
#include <hip/hip_runtime.h>
#include <hip/hip_bf16.h>
#include <math.h>

#define TID threadIdx.x

constexpr int Cc = 512, Tt = 1024, C3 = 1536;

typedef __attribute__((ext_vector_type(8))) __bf16 bf16x8;
typedef __attribute__((ext_vector_type(4))) float f32x4;

__device__ __forceinline__ void async16(const void* g, void* l) {
  __builtin_amdgcn_global_load_lds(
      (const __attribute__((address_space(1))) unsigned int*)g,
      (__attribute__((address_space(3))) unsigned int*)l, 16, 0, 0);
}

__device__ __forceinline__ unsigned int pack2bf(float a, float b) {
  __hip_bfloat162 h;
  h.x = __float2bfloat16(a);
  h.y = __float2bfloat16(b);
  return *reinterpret_cast<unsigned int*>(&h);
}

__device__ __forceinline__ float bf2f(unsigned short u) {
  unsigned int t = ((unsigned int)u) << 16;
  union { unsigned int i; float f; } c;
  c.i = t;
  return c.f;
}

// mish(x) = x*tanh(softplus(x)) = x * n/(n+2) with n = u*(u+2), u = e^x.
// One hw exp + one rcp instead of log1pf+tanhf libcalls (~8 VALU ops vs ~150).
__device__ __forceinline__ float mishf(float x) {
  float u = __expf(x);
  float n = u * (u + 2.f);
  float r = x * n * __builtin_amdgcn_rcpf(n + 2.f);
  return (x > 20.f) ? x : r;
}

__device__ __forceinline__ void blockReduce2(float& s, float& ss) {
  #pragma unroll
  for (int off = 32; off > 0; off >>= 1) {
    s  += __shfl_xor(s,  off);
    ss += __shfl_xor(ss, off);
  }
  __shared__ float ls[4], lss[4];
  int w = TID >> 6;
  if ((TID & 63) == 0) { ls[w] = s; lss[w] = ss; }
  __syncthreads();
  s  = ls[0] + ls[1] + ls[2] + ls[3];
  ss = lss[0] + lss[1] + lss[2] + lss[3];
}

// ---------------- zero the raw-stat accumulators (256 floats) ----------------
__global__ void zero_stats(float* p) { p[TID] = 0.f; }

// ---------------- fused GN(32) + im2col(K=2, pad_lo=0) -> bf16 B1t[b][t][k=2ci+j] ----------------
__global__ __launch_bounds__(256) void gn1_im2col(const float* __restrict__ x,
    const float* __restrict__ w, const float* __restrict__ bv,
    __hip_bfloat16* __restrict__ B1t) {
  __shared__ float hs[16][262];
  int blk = blockIdx.x, bb = blk >> 5, g = blk & 31;
  size_t base = ((size_t)bb * Cc + g * 16) * Tt;
  const float* xp = x + base;
  float s = 0.f, ss = 0.f;
  for (int i = TID * 4; i < 16 * Tt; i += 1024) {
    float4 v = *reinterpret_cast<const float4*>(xp + i);
    s  += v.x + v.y + v.z + v.w;
    ss += v.x * v.x + v.y * v.y + v.z * v.z + v.w * v.w;
  }
  blockReduce2(s, ss);
  float mean = s * (1.f / 16384.f);
  float rstd = rsqrtf(ss * (1.f / 16384.f) - mean * mean + 1e-5f);

  char* ob = reinterpret_cast<char*>(B1t + (size_t)bb * Tt * 1024 + g * 32);
  for (int tc = 0; tc < 4; ++tc) {
    int tbase = tc * 256;
    __syncthreads();
    for (int task = TID; task < 1024; task += 256) {
      int row = task >> 6, c4 = task & 63;
      int ch = g * 16 + row;
      float sw = w[ch] * rstd;
      float sb = bv[ch] - mean * sw;
      float4 v = *reinterpret_cast<const float4*>(xp + (size_t)row * Tt + tbase + c4 * 4);
      hs[row][c4 * 4 + 0] = v.x * sw + sb;
      hs[row][c4 * 4 + 1] = v.y * sw + sb;
      hs[row][c4 * 4 + 2] = v.z * sw + sb;
      hs[row][c4 * 4 + 3] = v.w * sw + sb;
    }
    if (TID < 16) {
      int row = TID, t = tbase + 256;
      float val = 0.f;
      if (t < Tt) {
        int ch = g * 16 + row;
        float sw = w[ch] * rstd;
        float sb = bv[ch] - mean * sw;
        val = xp[(size_t)row * Tt + t] * sw + sb;
      }
      hs[row][256] = val;
    }
    __syncthreads();
    for (int task = TID; task < 1024; task += 256) {
      int t = task >> 2, cj = task & 3;
      int ci = cj * 4;
      uint4 u;
      u.x = pack2bf(hs[ci + 0][t], hs[ci + 0][t + 1]);
      u.y = pack2bf(hs[ci + 1][t], hs[ci + 1][t + 1]);
      u.z = pack2bf(hs[ci + 2][t], hs[ci + 2][t + 1]);
      u.w = pack2bf(hs[ci + 3][t], hs[ci + 3][t + 1]);
      *reinterpret_cast<uint4*>(ob + ((size_t)(tbase + t) * 1024 + cj * 8) * 2) = u;
    }
  }
}

// ---------------- im2col(K=4, pad_lo=1) on attn output -> bf16 B4t[b][t][k=4ci+j], coalesced ----------------
__global__ __launch_bounds__(256) void im2col_k4(const float* __restrict__ a,
    __hip_bfloat16* __restrict__ B4t) {
  __shared__ float hs[16][266];
  int bb = blockIdx.x >> 5, cg = blockIdx.x & 31;
  const float* ab = a + ((size_t)bb * Cc + cg * 16) * Tt;
  char* ob = reinterpret_cast<char*>(B4t + (size_t)bb * Tt * 2048 + cg * 64);
  for (int tc = 0; tc < 4; ++tc) {
    int tbase = tc * 256;
    __syncthreads();
    for (int task = TID; task < 1024; task += 256) {
      int row = task >> 6, c4 = task & 63;
      float4 v = *reinterpret_cast<const float4*>(ab + (size_t)row * Tt + tbase + c4 * 4);
      hs[row][c4 * 4 + 1] = v.x;
      hs[row][c4 * 4 + 2] = v.y;
      hs[row][c4 * 4 + 3] = v.z;
      hs[row][c4 * 4 + 4] = v.w;
    }
    if (TID < 48) {
      int row = TID / 3, e = TID % 3;
      int t = (e == 0) ? tbase - 1 : tbase + 256 + (e - 1);
      float v = (t >= 0 && t < Tt) ? ab[(size_t)row * Tt + t] : 0.f;
      int col = (e == 0) ? 0 : 257 + (e - 1);
      hs[row][col] = v;
    }
    __syncthreads();
    for (int task = TID; task < 2048; task += 256) {
      int t = task >> 3, cj = task & 7;
      int ci = cj * 2;
      uint4 u;
      u.x = pack2bf(hs[ci][t],     hs[ci][t + 1]);
      u.y = pack2bf(hs[ci][t + 2], hs[ci][t + 3]);
      u.z = pack2bf(hs[ci + 1][t],     hs[ci + 1][t + 1]);
      u.w = pack2bf(hs[ci + 1][t + 2], hs[ci + 1][t + 3]);
      *reinterpret_cast<uint4*>(ob + ((size_t)(tbase + t) * 2048 + cj * 8) * 2) = u;
    }
  }
}

// ---------------- f32 -> bf16 cast (weights) ----------------
__global__ __launch_bounds__(256) void cast_bf16(const float* __restrict__ in,
    __hip_bfloat16* __restrict__ out, int n) {
  int i = (blockIdx.x * 256 + TID) * 4;
  if (i >= n) return;
  float4 v = *reinterpret_cast<const float4*>(in + i);
  *reinterpret_cast<unsigned int*>(out + i)     = pack2bf(v.x, v.y);
  *reinterpret_cast<unsigned int*>(out + i + 2) = pack2bf(v.z, v.w);
}

// ---------------- bf16 MFMA GEMM v8: 512 threads, BM=256 x BN=128, bt5-style single buffer,
//                  fragment-ordered chunks, fused GN raw stats + bf16 out --------------------
template<int K, int GROWS, int NGRP, bool BF16OUT>
__global__ __launch_bounds__(512, 4) void gemm_bt8(const __hip_bfloat16* __restrict__ A,
    const __hip_bfloat16* __restrict__ Bt, const float* __restrict__ bias,
    void* __restrict__ Cout, float* __restrict__ statraw, int M) {
  constexpr int NKT = K / 64;
  __shared__ __align__(16) char lds[48 * 1024];   // 32 A-chunks + 16 B-chunks of 1KB
  int t0 = blockIdx.x * 128, o0 = blockIdx.y * 256, bz = blockIdx.z;
  int wave = TID >> 6, lane = TID & 63;
  int l4 = lane >> 4, r15 = lane & 15;
  int wm = wave >> 1, wn = wave & 1;              // 4 M-waves x 2 N-waves
  const __hip_bfloat16* Ab = A + (size_t)o0 * K;
  const __hip_bfloat16* Bb = Bt + ((size_t)bz * 1024 + t0) * K;

  f32x4 acc[4][4];
  f32x4 zz = {0.f, 0.f, 0.f, 0.f};
  #pragma unroll
  for (int m = 0; m < 4; ++m)
    #pragma unroll
    for (int n = 0; n < 4; ++n) acc[m][n] = zz;

  for (int kt = 0; kt < NKT; ++kt) {
    #pragma unroll
    for (int c = 0; c < 6; ++c) {
      int ch = c * 8 + wave;
      int kof = kt * 64 + (ch & 1) * 32 + l4 * 8;
      const __hip_bfloat16* src;
      if (ch < 32) {
        int row = (ch >> 1) * 16 + r15;
        src = Ab + (size_t)row * K + kof;
      } else {
        int row = ((ch - 32) >> 1) * 16 + r15;
        src = Bb + (size_t)row * K + kof;
      }
      async16(src, lds + ch * 1024 + lane * 16);
    }
    __syncthreads();
    #pragma unroll
    for (int kk = 0; kk < 2; ++kk) {
      bf16x8 af[4], bfr[4];
      #pragma unroll
      for (int m = 0; m < 4; ++m)
        af[m] = *reinterpret_cast<const bf16x8*>(lds + ((wm * 4 + m) * 2 + kk) * 1024 + lane * 16);
      #pragma unroll
      for (int n = 0; n < 4; ++n)
        bfr[n] = *reinterpret_cast<const bf16x8*>(lds + (32 + (wn * 4 + n) * 2 + kk) * 1024 + lane * 16);
      #pragma unroll
      for (int m = 0; m < 4; ++m)
        #pragma unroll
        for (int n = 0; n < 4; ++n)
          acc[m][n] = __builtin_amdgcn_mfma_f32_16x16x32_bf16(af[m], bfr[n], acc[m][n], 0, 0, 0);
    }
    __syncthreads();
  }

  // epilogue: store (+bias), per-(wave,m) lane-reduced stats -> LDS -> <=2 group atomics
  float* sred = reinterpret_cast<float*>(lds);  // 64 floats, buffer dead
  #pragma unroll
  for (int m = 0; m < 4; ++m) {
    float s = 0.f, ss2 = 0.f;
    #pragma unroll
    for (int n = 0; n < 4; ++n) {
      int ocol = t0 + (wn * 4 + n) * 16 + r15;
      #pragma unroll
      for (int r = 0; r < 4; ++r) {
        int orow = o0 + (wm * 4 + m) * 16 + l4 * 4 + r;
        float v = acc[m][n][r] + bias[orow];
        if constexpr (BF16OUT)
          ((__hip_bfloat16*)Cout)[((size_t)bz * M + orow) * 1024 + ocol] = __float2bfloat16(v);
        else
          ((float*)Cout)[((size_t)bz * M + orow) * 1024 + ocol] = v;
        s += v;
        ss2 += v * v;
      }
    }
    #pragma unroll
    for (int off = 1; off < 64; off <<= 1) {
      s   += __shfl_xor(s, off);
      ss2 += __shfl_xor(ss2, off);
    }
    if (lane == 0) {
      sred[(wave * 4 + m) * 2]     = s;
      sred[(wave * 4 + m) * 2 + 1] = ss2;
    }
  }
  __syncthreads();
  if (TID < 2) {
    int g0 = o0 / GROWS;
    float S = 0.f, SS = 0.f;
    int cnt = 0;
    #pragma unroll
    for (int slot = 0; slot < 32; ++slot) {
      int w = slot >> 2, m = slot & 3;
      int rc = (w >> 1) * 4 + m;
      int g = (o0 + rc * 16) / GROWS;
      if (g == g0 + (int)TID && g < NGRP) {
        S  += sred[slot * 2];
        SS += sred[slot * 2 + 1];
        ++cnt;
      }
    }
    if (cnt) {
      atomicAdd(&statraw[2 * (bz * NGRP + g0 + TID)],     S);
      atomicAdd(&statraw[2 * (bz * NGRP + g0 + TID) + 1], SS);
    }
  }
}

// ---------------- bf16 MFMA GEMM v5 (R8-proven): MT x 128, single buffer, fused stats ----------
template<int K, int MT, int GROWS, int NGRP, bool BF16OUT>
__global__ __launch_bounds__(256) void gemm_bt5(const __hip_bfloat16* __restrict__ A,
    const __hip_bfloat16* __restrict__ Bt, const float* __restrict__ bias,
    void* __restrict__ Cout, float* __restrict__ statraw, int M) {
  constexpr int ACH = (MT / 16) * 2;
  constexpr int NCH = ACH + 16;
  constexpr int NF  = (MT == 128) ? 4 : 2;
  __shared__ __align__(16) char lds[NCH * 1024];
  int t0 = blockIdx.x * 128, o0 = blockIdx.y * MT, bz = blockIdx.z;
  int wave = TID >> 6, lane = TID & 63;
  int l4 = lane >> 4, r15 = lane & 15;
  const __hip_bfloat16* Ab = A + (size_t)o0 * K;
  const __hip_bfloat16* Bb = Bt + ((size_t)bz * 1024 + t0) * K;
  int mbase = (MT == 128) ? (wave >> 1) * 4 : 0;
  int nbase = (MT == 128) ? (wave & 1) * 4 : wave * 2;

  f32x4 acc[4][NF];
  f32x4 zz = {0.f, 0.f, 0.f, 0.f};
  #pragma unroll
  for (int m = 0; m < 4; ++m)
    #pragma unroll
    for (int n = 0; n < NF; ++n) acc[m][n] = zz;

  for (int kt = 0; kt < K / 64; ++kt) {
    #pragma unroll
    for (int c = 0; c < NCH / 4; ++c) {
      int ch = c * 4 + wave;
      int cl = (ch < ACH) ? ch : ch - ACH;
      int row = (cl >> 1) * 16 + r15;
      int kof = kt * 64 + (cl & 1) * 32 + l4 * 8;
      const __hip_bfloat16* src = (ch < ACH) ? (Ab + (size_t)row * K + kof)
                                             : (Bb + (size_t)row * K + kof);
      async16(src, lds + ch * 1024 + lane * 16);
    }
    __syncthreads();
    #pragma unroll
    for (int kk = 0; kk < 2; ++kk) {
      bf16x8 af[4], bfr[NF];
      #pragma unroll
      for (int m = 0; m < 4; ++m)
        af[m] = *reinterpret_cast<const bf16x8*>(lds + ((mbase + m) * 2 + kk) * 1024 + lane * 16);
      #pragma unroll
      for (int n = 0; n < NF; ++n)
        bfr[n] = *reinterpret_cast<const bf16x8*>(lds + (ACH + (nbase + n) * 2 + kk) * 1024 + lane * 16);
      #pragma unroll
      for (int m = 0; m < 4; ++m)
        #pragma unroll
        for (int n = 0; n < NF; ++n)
          acc[m][n] = __builtin_amdgcn_mfma_f32_16x16x32_bf16(af[m], bfr[n], acc[m][n], 0, 0, 0);
    }
    __syncthreads();
  }

  float* sred = reinterpret_cast<float*>(lds);
  #pragma unroll
  for (int m = 0; m < 4; ++m) {
    float s = 0.f, ss2 = 0.f;
    #pragma unroll
    for (int n = 0; n < NF; ++n) {
      int ocol = t0 + (nbase + n) * 16 + r15;
      #pragma unroll
      for (int r = 0; r < 4; ++r) {
        int orow = o0 + (mbase + m) * 16 + l4 * 4 + r;
        float v = acc[m][n][r] + bias[orow];
        if constexpr (BF16OUT)
          ((__hip_bfloat16*)Cout)[((size_t)bz * M + orow) * 1024 + ocol] = __float2bfloat16(v);
        else
          ((float*)Cout)[((size_t)bz * M + orow) * 1024 + ocol] = v;
        s += v;
        ss2 += v * v;
      }
    }
    #pragma unroll
    for (int off = 1; off < 64; off <<= 1) {
      s   += __shfl_xor(s, off);
      ss2 += __shfl_xor(ss2, off);
    }
    if (lane == 0) {
      sred[(wave * 4 + m) * 2]     = s;
      sred[(wave * 4 + m) * 2 + 1] = ss2;
    }
  }
  __syncthreads();
  if (TID < 2) {
    int g0 = o0 / GROWS;
    int gl = TID;
    float S = 0.f, SS = 0.f;
    int cnt = 0;
    #pragma unroll
    for (int slot = 0; slot < 16; ++slot) {
      int stripe = ((MT == 128) ? ((slot >> 3) << 2) : 0) + (slot & 3);
      int g = (o0 + stripe * 16) / GROWS;
      if (g == g0 + gl && g < NGRP) {
        S  += sred[slot * 2];
        SS += sred[slot * 2 + 1];
        ++cnt;
      }
    }
    if (cnt) {
      atomicAdd(&statraw[2 * (bz * NGRP + g0 + gl)],     S);
      atomicAdd(&statraw[2 * (bz * NGRP + g0 + gl) + 1], SS);
    }
  }
}

// ---------------- fused GN(8)+Mish + build attn input images (bf16 qkv input, raw stats) ----------------
__global__ __launch_bounds__(256) void gn2_prep(const __hip_bfloat16* __restrict__ qkv,
    const float* __restrict__ straw, const float* __restrict__ w, const float* __restrict__ bv,
    char* __restrict__ qTp, char* __restrict__ kimg, char* __restrict__ vimg) {
  __shared__ unsigned short hbf[192 * 66];
  int tl = blockIdx.x & 15, hb = blockIdx.x >> 4;
  int b = hb >> 3, hd = hb & 7;
  float rs = straw[2 * (b * 8 + hd)], rq = straw[2 * (b * 8 + hd) + 1];
  float mean = rs * (1.f / 196608.f);
  float rstd = rsqrtf(fmaxf(rq * (1.f / 196608.f) - mean * mean, 0.f) + 1e-5f);
  for (int task = TID; task < 768; task += 256) {
    int row = task >> 2, seg = task & 3;
    int ch = hd * 192 + row;
    float sw = w[ch] * rstd;
    float sb = bv[ch] - mean * sw;
    const uint4* src = reinterpret_cast<const uint4*>(
        qkv + ((size_t)(b * C3 + ch)) * 1024 + tl * 64 + seg * 16);
    uint4 u0 = src[0], u1 = src[1];
    unsigned int uu[8] = {u0.x, u0.y, u0.z, u0.w, u1.x, u1.y, u1.z, u1.w};
    unsigned int* dst = reinterpret_cast<unsigned int*>(&hbf[row * 66 + seg * 16]);
    #pragma unroll
    for (int j = 0; j < 8; ++j) {
      float a = mishf(bf2f((unsigned short)(uu[j] & 0xffff)) * sw + sb);
      float c = mishf(bf2f((unsigned short)(uu[j] >> 16)) * sw + sb);
      dst[j] = pack2bf(a, c);
    }
  }
  __syncthreads();
  size_t tileof = ((size_t)hb * 16 + tl) * 8192;
  {
    int t = TID & 63, sel = TID >> 6;
    int img = sel >> 1, half = sel & 1;
    char* obase = (img == 0 ? qTp : kimg) + tileof + (size_t)t * 128;
    #pragma unroll
    for (int cc = 0; cc < 4; ++cc) {
      int chunk = half * 4 + cc;
      uint4 u;
      unsigned int* up = reinterpret_cast<unsigned int*>(&u);
      #pragma unroll
      for (int j = 0; j < 4; ++j) {
        int c = chunk * 8 + j * 2;
        unsigned int lo = hbf[(img * 64 + c) * 66 + t];
        unsigned int hi = hbf[(img * 64 + c + 1) * 66 + t];
        up[j] = lo | (hi << 16);
      }
      int cpos = (img == 0) ? chunk : (chunk ^ (t & 7));
      *reinterpret_cast<uint4*>(obase + cpos * 16) = u;
    }
  }
  {
    int c = TID & 63, qtr = TID >> 6;
    const unsigned int* vrow = reinterpret_cast<const unsigned int*>(&hbf[(128 + c) * 66]);
    char* obase = vimg + tileof + (size_t)c * 128;
    #pragma unroll
    for (int k = 0; k < 2; ++k) {
      int chunk = qtr * 2 + k;
      uint4 u;
      unsigned int* up = reinterpret_cast<unsigned int*>(&u);
      #pragma unroll
      for (int j = 0; j < 4; ++j) up[j] = vrow[chunk * 4 + j];
      *reinterpret_cast<uint4*>(obase + (chunk ^ (c & 7)) * 16) = u;
    }
  }
}

// ---------------- MFMA flash attention v3: 512 threads, 2 q-tiles/block (halved K/V re-reads) ----------------
__global__ __launch_bounds__(512) void attn_mfma3(const char* __restrict__ qTp,
    const char* __restrict__ kimg, const char* __restrict__ vimg,
    float* __restrict__ a) {
  __shared__ __align__(16) char smem[49152];
  char* kbuf0 = smem;
  char* kbuf1 = smem + 8192;
  char* vbuf0 = smem + 16384;
  char* vbuf1 = smem + 24576;
  char* pp    = smem + 32768;  // 8 waves x 2KB
  char* ov    = smem;          // 32KB alias over K/V buffers

  int hb = blockIdx.y;
  int b = hb >> 3, hd = hb & 7;
  int lane = TID & 63, wave = TID >> 6;
  int qt = wave >> 2, qw = wave & 3;   // q-tile pair member, quarter within tile
  int l4 = lane >> 4, r15 = lane & 15;
  size_t ibase = (size_t)hb * 16 * 8192;
  const char* ksrc = kimg + ibase;
  const char* vsrc = vimg + ibase;

  async16(ksrc + (size_t)TID * 16, kbuf0 + (size_t)TID * 16);
  async16(vsrc + (size_t)TID * 16, vbuf0 + (size_t)TID * 16);

  bf16x8 aq[2];
  int tg = qw * 16 + r15;
  const char* qrow = qTp + ibase + (size_t)(blockIdx.x * 2 + qt) * 8192 + (size_t)tg * 128;
  aq[0] = *reinterpret_cast<const bf16x8*>(qrow + l4 * 16);
  aq[1] = *reinterpret_cast<const bf16x8*>(qrow + 64 + l4 * 16);

  f32x4 osum[4];
  f32x4 zz = {0.f, 0.f, 0.f, 0.f};
  #pragma unroll
  for (int cf = 0; cf < 4; ++cf) osum[cf] = zz;
  float mrow[4] = {-1e30f, -1e30f, -1e30f, -1e30f};
  float lrow[4] = {0.f, 0.f, 0.f, 0.f};
  __syncthreads();

  for (int it = 0; it < 16; ++it) {
    char* kcur = (it & 1) ? kbuf1 : kbuf0;
    char* vcur = (it & 1) ? vbuf1 : vbuf0;
    if (it < 15) {
      char* knxt = (it & 1) ? kbuf0 : kbuf1;
      char* vnxt = (it & 1) ? vbuf0 : vbuf1;
      const char* kn = ksrc + (size_t)(it + 1) * 8192;
      const char* vn = vsrc + (size_t)(it + 1) * 8192;
      async16(kn + (size_t)TID * 16, knxt + (size_t)TID * 16);
      async16(vn + (size_t)TID * 16, vnxt + (size_t)TID * 16);
    }
    f32x4 sc[4];
    #pragma unroll
    for (int sf = 0; sf < 4; ++sf) sc[sf] = zz;
    #pragma unroll
    for (int sf = 0; sf < 4; ++sf) {
      int sr = sf * 16 + r15;
      #pragma unroll
      for (int kk = 0; kk < 2; ++kk) {
        bf16x8 bk = *reinterpret_cast<const bf16x8*>(kcur + sr * 128 + (((kk * 4 + l4) ^ (sr & 7)) << 4));
        sc[sf] = __builtin_amdgcn_mfma_f32_16x16x32_bf16(aq[kk], bk, sc[sf], 0, 0, 0);
      }
    }
    float tmax[4];
    #pragma unroll
    for (int r = 0; r < 4; ++r)
      tmax[r] = fmaxf(fmaxf(sc[0][r], sc[1][r]), fmaxf(sc[2][r], sc[3][r]));
    #pragma unroll
    for (int off = 1; off < 16; off <<= 1)
      #pragma unroll
      for (int r = 0; r < 4; ++r) tmax[r] = fmaxf(tmax[r], __shfl_xor(tmax[r], off));
    float alpha[4];
    #pragma unroll
    for (int r = 0; r < 4; ++r) {
      float mnew = fmaxf(mrow[r], tmax[r]);
      alpha[r] = __expf((mrow[r] - mnew) * 0.125f);
      mrow[r] = mnew;
      lrow[r] *= alpha[r];
    }
    #pragma unroll
    for (int cf = 0; cf < 4; ++cf)
      #pragma unroll
      for (int r = 0; r < 4; ++r) osum[cf][r] *= alpha[r];
    char* pw = pp + wave * 2048;
    float psum[4] = {0.f, 0.f, 0.f, 0.f};
    #pragma unroll
    for (int sf = 0; sf < 4; ++sf) {
      int s = sf * 16 + r15;
      #pragma unroll
      for (int r = 0; r < 4; ++r) {
        float p = __expf((sc[sf][r] - mrow[r]) * 0.125f);
        psum[r] += p;
        int tlc = l4 * 4 + r;
        *reinterpret_cast<__hip_bfloat16*>(pw + tlc * 128 + ((((s >> 3) ^ (tlc & 7)) << 4) | ((s & 7) * 2)))
            = __float2bfloat16(p);
      }
    }
    #pragma unroll
    for (int r = 0; r < 4; ++r) lrow[r] += psum[r];
    asm volatile("s_waitcnt lgkmcnt(0)" ::: "memory");
    __builtin_amdgcn_sched_barrier(0);

    bf16x8 pa[2];
    #pragma unroll
    for (int kk = 0; kk < 2; ++kk)
      pa[kk] = *reinterpret_cast<const bf16x8*>(pw + r15 * 128 + (((kk * 4 + l4) ^ (r15 & 7)) << 4));
    #pragma unroll
    for (int cf = 0; cf < 4; ++cf) {
      int cr = cf * 16 + r15;
      #pragma unroll
      for (int kk = 0; kk < 2; ++kk) {
        bf16x8 bv = *reinterpret_cast<const bf16x8*>(vcur + cr * 128 + (((kk * 4 + l4) ^ (cr & 7)) << 4));
        osum[cf] = __builtin_amdgcn_mfma_f32_16x16x32_bf16(pa[kk], bv, osum[cf], 0, 0, 0);
      }
    }
    __syncthreads();
  }

  #pragma unroll
  for (int off = 1; off < 16; off <<= 1)
    #pragma unroll
    for (int r = 0; r < 4; ++r) lrow[r] += __shfl_xor(lrow[r], off);
  float linv[4];
  #pragma unroll
  for (int r = 0; r < 4; ++r) linv[r] = 1.f / lrow[r];

  // ov[c][t] f32, c in [0,64), t in [0,128), chunk-swizzled
  #pragma unroll
  for (int cf = 0; cf < 4; ++cf) {
    int c = cf * 16 + r15;
    #pragma unroll
    for (int r = 0; r < 4; ++r) {
      int t = qt * 64 + qw * 16 + l4 * 4 + r;
      *reinterpret_cast<float*>(ov + c * 512 + ((((t >> 2) ^ (c & 7)) << 4) | ((t & 3) * 4)))
          = osum[cf][r] * linv[r];
    }
  }
  __syncthreads();
  float* ap = a + ((size_t)b * Cc + hd * 64) * Tt + blockIdx.x * 128;
  for (int u = TID; u < 2048; u += 512) {
    int c = u >> 5, tq = u & 31;
    float4 o4 = *reinterpret_cast<const float4*>(ov + c * 512 + ((tq ^ (c & 7)) << 4));
    *reinterpret_cast<float4*>(ap + (size_t)c * Tt + tq * 4) = o4;
  }
}

// ---------------- final: out = x + mish(gn(y2)) in-place on d_out (raw stats) ----------------
__global__ __launch_bounds__(256) void final_kernel(const float* __restrict__ x,
    float* __restrict__ y, const float* __restrict__ straw,
    const float* __restrict__ w, const float* __restrict__ bv) {
  size_t i = ((size_t)blockIdx.x * 256 + TID) * 4;
  int ch = (int)((i >> 10) & (Cc - 1));
  int b = (int)(i >> 19);
  int g = b * 8 + (ch >> 6);
  float rs = straw[2 * g], rq = straw[2 * g + 1];
  float mean = rs * (1.f / 65536.f);
  float rstd = rsqrtf(fmaxf(rq * (1.f / 65536.f) - mean * mean, 0.f) + 1e-5f);
  float sw = w[ch] * rstd;
  float sb = bv[ch] - mean * sw;
  float4 v  = *reinterpret_cast<const float4*>(y + i);
  float4 xv = *reinterpret_cast<const float4*>(x + i);
  v.x = xv.x + mishf(v.x * sw + sb);
  v.y = xv.y + mishf(v.y * sw + sb);
  v.z = xv.z + mishf(v.z * sw + sb);
  v.w = xv.w + mishf(v.w * sw + sb);
  *reinterpret_cast<float4*>(y + i) = v;
}

extern "C" void kernel_launch(void* const* d_in, const int* in_sizes, int n_in,
                              void* d_out, int out_size, void* d_ws, size_t ws_size,
                              hipStream_t stream) {
  const float* x     = (const float*)d_in[0];
  const float* gn_w  = (const float*)d_in[1];
  const float* gn_b  = (const float*)d_in[2];
  const float* wqkv  = (const float*)d_in[3];
  const float* bqkv  = (const float*)d_in[4];
  const float* gnq_w = (const float*)d_in[5];
  const float* gnq_b = (const float*)d_in[6];
  const float* wproj = (const float*)d_in[7];
  const float* bproj = (const float*)d_in[8];
  const float* gnp_w = (const float*)d_in[9];
  const float* gnp_b = (const float*)d_in[10];
  float* out = (float*)d_out;

  char* ws = (char*)d_ws;
  const size_t MB = 1024 * 1024;
  // Time-multiplexed workspace (<= 64MB):
  __hip_bfloat16* qkvb = (__hip_bfloat16*)ws;            // [0,24MB)   step4 -> step5
  float* hbuf = (float*)ws;                              // [0,16MB)   step6 -> step7 (qkvb dead)
  __hip_bfloat16* B4t = (__hip_bfloat16*)(ws + 24 * MB); // [24,56MB)  step7 -> step9
  __hip_bfloat16* A1  = (__hip_bfloat16*)(ws + 56 * MB); // [56,59MB)  step2 -> step4
  char* vimg = ws + 56 * MB;                             // [56,64MB)  step5 -> step6 (A1 dead)
  __hip_bfloat16* A2  = (__hip_bfloat16*)(ws + 56 * MB); // [56,58MB)  step8 -> step9 (vimg dead)
  float* st2raw = (float*)(ws + 64 * MB);                // 128 floats
  float* st3raw = st2raw + 128;                          // 128 floats
  __hip_bfloat16* B1t = (__hip_bfloat16*)d_out;          // d_out as B1t  step3 -> step4
  char* qTp  = (char*)d_out;                             // d_out[0,8MB)  step5 -> step6
  char* kimg = (char*)d_out + 8 * MB;                    // d_out[8,16MB) step5 -> step6

  dim3 blk(256);
  zero_stats<<<1, blk, 0, stream>>>(st2raw);                                       // 1 (zeros both)
  cast_bf16<<<1536, blk, 0, stream>>>(wqkv, A1, C3 * 1024);                        // 2
  gn1_im2col<<<256, blk, 0, stream>>>(x, gn_w, gn_b, B1t);                         // 3
  gemm_bt8<1024, 192, 8, true><<<dim3(8, 6, 8), dim3(512), 0, stream>>>(
      A1, B1t, bqkv, qkvb, st2raw, C3);                                            // 4
  gn2_prep<<<1024, blk, 0, stream>>>(qkvb, st2raw, gnq_w, gnq_b, qTp, kimg, vimg); // 5
  attn_mfma3<<<dim3(8, 64), dim3(512), 0, stream>>>(qTp, kimg, vimg, hbuf);        // 6
  im2col_k4<<<256, blk, 0, stream>>>(hbuf, B4t);                                   // 7
  cast_bf16<<<1024, blk, 0, stream>>>(wproj, A2, Cc * 2048);                       // 8
  gemm_bt5<2048, 64, 64, 8, false><<<dim3(8, 8, 8), blk, 0, stream>>>(
      A2, B4t, bproj, out, st3raw, Cc);                                            // 9
  final_kernel<<<4096, blk, 0, stream>>>(x, out, st3raw, gnp_w, gnp_b);            // 10
}

// Round 13
// 191.675 us; speedup vs baseline: 1.8192x; 1.1185x over previous
//
#include <hip/hip_runtime.h>
#include <hip/hip_bf16.h>
#include <math.h>

#define TID threadIdx.x

constexpr int Cc = 512, Tt = 1024, C3 = 1536;

typedef __attribute__((ext_vector_type(8))) __bf16 bf16x8;
typedef __attribute__((ext_vector_type(4))) float f32x4;

__device__ __forceinline__ void async16(const void* g, void* l) {
  __builtin_amdgcn_global_load_lds(
      (const __attribute__((address_space(1))) unsigned int*)g,
      (__attribute__((address_space(3))) unsigned int*)l, 16, 0, 0);
}

__device__ __forceinline__ unsigned int pack2bf(float a, float b) {
  __hip_bfloat162 h;
  h.x = __float2bfloat16(a);
  h.y = __float2bfloat16(b);
  return *reinterpret_cast<unsigned int*>(&h);
}

__device__ __forceinline__ float bf2f(unsigned short u) {
  unsigned int t = ((unsigned int)u) << 16;
  union { unsigned int i; float f; } c;
  c.i = t;
  return c.f;
}

// mish(x) = x * n/(n+2), n = u*(u+2), u = e^x  (one hw exp + one rcp)
__device__ __forceinline__ float mishf(float x) {
  float u = __expf(x);
  float n = u * (u + 2.f);
  float r = x * n * __builtin_amdgcn_rcpf(n + 2.f);
  return (x > 20.f) ? x : r;
}

__device__ __forceinline__ void blockReduce2(float& s, float& ss) {
  #pragma unroll
  for (int off = 32; off > 0; off >>= 1) {
    s  += __shfl_xor(s,  off);
    ss += __shfl_xor(ss, off);
  }
  __shared__ float ls[4], lss[4];
  int w = TID >> 6;
  if ((TID & 63) == 0) { ls[w] = s; lss[w] = ss; }
  __syncthreads();
  s  = ls[0] + ls[1] + ls[2] + ls[3];
  ss = lss[0] + lss[1] + lss[2] + lss[3];
}

// ---------------- zero the raw-stat accumulators (256 floats) ----------------
__global__ void zero_stats(float* p) { p[TID] = 0.f; }

// ---------------- zero the 16-row halo pads of aT[8][1056][512] ----------------
__global__ __launch_bounds__(256) void zero_pads(__hip_bfloat16* __restrict__ aT) {
  int idx = blockIdx.x * 256 + TID;         // 16384 tasks x 8 bf16
  int bb = idx >> 11;
  int task = idx & 2047;
  int prow = task >> 6;                     // 32 pad rows per batch
  int col = (task & 63) * 8;
  int P = (prow < 16) ? prow : (1024 + prow);
  uint4 z = {0u, 0u, 0u, 0u};
  *reinterpret_cast<uint4*>(aT + ((size_t)bb * 1056 + P) * 512 + col) = z;
}

// ---------------- fused GN(32) + im2col(K=2, pad_lo=0) -> bf16 B1t[b][t][k=2ci+j] ----------------
__global__ __launch_bounds__(256) void gn1_im2col(const float* __restrict__ x,
    const float* __restrict__ w, const float* __restrict__ bv,
    __hip_bfloat16* __restrict__ B1t) {
  __shared__ float hs[16][262];
  int blk = blockIdx.x, bb = blk >> 5, g = blk & 31;
  size_t base = ((size_t)bb * Cc + g * 16) * Tt;
  const float* xp = x + base;
  float s = 0.f, ss = 0.f;
  for (int i = TID * 4; i < 16 * Tt; i += 1024) {
    float4 v = *reinterpret_cast<const float4*>(xp + i);
    s  += v.x + v.y + v.z + v.w;
    ss += v.x * v.x + v.y * v.y + v.z * v.z + v.w * v.w;
  }
  blockReduce2(s, ss);
  float mean = s * (1.f / 16384.f);
  float rstd = rsqrtf(ss * (1.f / 16384.f) - mean * mean + 1e-5f);

  char* ob = reinterpret_cast<char*>(B1t + (size_t)bb * Tt * 1024 + g * 32);
  for (int tc = 0; tc < 4; ++tc) {
    int tbase = tc * 256;
    __syncthreads();
    for (int task = TID; task < 1024; task += 256) {
      int row = task >> 6, c4 = task & 63;
      int ch = g * 16 + row;
      float sw = w[ch] * rstd;
      float sb = bv[ch] - mean * sw;
      float4 v = *reinterpret_cast<const float4*>(xp + (size_t)row * Tt + tbase + c4 * 4);
      hs[row][c4 * 4 + 0] = v.x * sw + sb;
      hs[row][c4 * 4 + 1] = v.y * sw + sb;
      hs[row][c4 * 4 + 2] = v.z * sw + sb;
      hs[row][c4 * 4 + 3] = v.w * sw + sb;
    }
    if (TID < 16) {
      int row = TID, t = tbase + 256;
      float val = 0.f;
      if (t < Tt) {
        int ch = g * 16 + row;
        float sw = w[ch] * rstd;
        float sb = bv[ch] - mean * sw;
        val = xp[(size_t)row * Tt + t] * sw + sb;
      }
      hs[row][256] = val;
    }
    __syncthreads();
    for (int task = TID; task < 1024; task += 256) {
      int t = task >> 2, cj = task & 3;
      int ci = cj * 4;
      uint4 u;
      u.x = pack2bf(hs[ci + 0][t], hs[ci + 0][t + 1]);
      u.y = pack2bf(hs[ci + 1][t], hs[ci + 1][t + 1]);
      u.z = pack2bf(hs[ci + 2][t], hs[ci + 2][t + 1]);
      u.w = pack2bf(hs[ci + 3][t], hs[ci + 3][t + 1]);
      *reinterpret_cast<uint4*>(ob + ((size_t)(tbase + t) * 1024 + cj * 8) * 2) = u;
    }
  }
}

// ---------------- f32 -> bf16 cast (weights) ----------------
__global__ __launch_bounds__(256) void cast_bf16(const float* __restrict__ in,
    __hip_bfloat16* __restrict__ out, int n) {
  int i = (blockIdx.x * 256 + TID) * 4;
  if (i >= n) return;
  float4 v = *reinterpret_cast<const float4*>(in + i);
  *reinterpret_cast<unsigned int*>(out + i)     = pack2bf(v.x, v.y);
  *reinterpret_cast<unsigned int*>(out + i + 2) = pack2bf(v.z, v.w);
}

// ---------------- wproj [o][ci][4] f32 -> A2[j][o][ci] bf16 (4 planes of 512x512) ----------------
__global__ __launch_bounds__(256) void cast_wproj(const float* __restrict__ wp,
    __hip_bfloat16* __restrict__ A2) {
  int o = blockIdx.x;
  int ci = TID * 2;
  float4 v0 = *reinterpret_cast<const float4*>(wp + ((size_t)o * 512 + ci) * 4);
  float4 v1 = *reinterpret_cast<const float4*>(wp + ((size_t)o * 512 + ci + 1) * 4);
  const float* a0 = &v0.x;
  const float* a1 = &v1.x;
  #pragma unroll
  for (int j = 0; j < 4; ++j) {
    unsigned int u = pack2bf(a0[j], a1[j]);
    *reinterpret_cast<unsigned int*>(A2 + ((size_t)j * 512 + o) * 512 + ci) = u;
  }
}

// ---------------- bf16 MFMA GEMM v8: 512 threads, BM=256 x BN=128 (R12-proven) ----------------
template<int K, int GROWS, int NGRP, bool BF16OUT>
__global__ __launch_bounds__(512, 4) void gemm_bt8(const __hip_bfloat16* __restrict__ A,
    const __hip_bfloat16* __restrict__ Bt, const float* __restrict__ bias,
    void* __restrict__ Cout, float* __restrict__ statraw, int M) {
  constexpr int NKT = K / 64;
  __shared__ __align__(16) char lds[48 * 1024];
  int t0 = blockIdx.x * 128, o0 = blockIdx.y * 256, bz = blockIdx.z;
  int wave = TID >> 6, lane = TID & 63;
  int l4 = lane >> 4, r15 = lane & 15;
  int wm = wave >> 1, wn = wave & 1;
  const __hip_bfloat16* Ab = A + (size_t)o0 * K;
  const __hip_bfloat16* Bb = Bt + ((size_t)bz * 1024 + t0) * K;

  f32x4 acc[4][4];
  f32x4 zz = {0.f, 0.f, 0.f, 0.f};
  #pragma unroll
  for (int m = 0; m < 4; ++m)
    #pragma unroll
    for (int n = 0; n < 4; ++n) acc[m][n] = zz;

  for (int kt = 0; kt < NKT; ++kt) {
    #pragma unroll
    for (int c = 0; c < 6; ++c) {
      int ch = c * 8 + wave;
      int kof = kt * 64 + (ch & 1) * 32 + l4 * 8;
      const __hip_bfloat16* src;
      if (ch < 32) {
        int row = (ch >> 1) * 16 + r15;
        src = Ab + (size_t)row * K + kof;
      } else {
        int row = ((ch - 32) >> 1) * 16 + r15;
        src = Bb + (size_t)row * K + kof;
      }
      async16(src, lds + ch * 1024 + lane * 16);
    }
    __syncthreads();
    #pragma unroll
    for (int kk = 0; kk < 2; ++kk) {
      bf16x8 af[4], bfr[4];
      #pragma unroll
      for (int m = 0; m < 4; ++m)
        af[m] = *reinterpret_cast<const bf16x8*>(lds + ((wm * 4 + m) * 2 + kk) * 1024 + lane * 16);
      #pragma unroll
      for (int n = 0; n < 4; ++n)
        bfr[n] = *reinterpret_cast<const bf16x8*>(lds + (32 + (wn * 4 + n) * 2 + kk) * 1024 + lane * 16);
      #pragma unroll
      for (int m = 0; m < 4; ++m)
        #pragma unroll
        for (int n = 0; n < 4; ++n)
          acc[m][n] = __builtin_amdgcn_mfma_f32_16x16x32_bf16(af[m], bfr[n], acc[m][n], 0, 0, 0);
    }
    __syncthreads();
  }

  float* sred = reinterpret_cast<float*>(lds);
  #pragma unroll
  for (int m = 0; m < 4; ++m) {
    float s = 0.f, ss2 = 0.f;
    #pragma unroll
    for (int n = 0; n < 4; ++n) {
      int ocol = t0 + (wn * 4 + n) * 16 + r15;
      #pragma unroll
      for (int r = 0; r < 4; ++r) {
        int orow = o0 + (wm * 4 + m) * 16 + l4 * 4 + r;
        float v = acc[m][n][r] + bias[orow];
        if constexpr (BF16OUT)
          ((__hip_bfloat16*)Cout)[((size_t)bz * M + orow) * 1024 + ocol] = __float2bfloat16(v);
        else
          ((float*)Cout)[((size_t)bz * M + orow) * 1024 + ocol] = v;
        s += v;
        ss2 += v * v;
      }
    }
    #pragma unroll
    for (int off = 1; off < 64; off <<= 1) {
      s   += __shfl_xor(s, off);
      ss2 += __shfl_xor(ss2, off);
    }
    if (lane == 0) {
      sred[(wave * 4 + m) * 2]     = s;
      sred[(wave * 4 + m) * 2 + 1] = ss2;
    }
  }
  __syncthreads();
  if (TID < 2) {
    int g0 = o0 / GROWS;
    float S = 0.f, SS = 0.f;
    int cnt = 0;
    #pragma unroll
    for (int slot = 0; slot < 32; ++slot) {
      int w = slot >> 2, m = slot & 3;
      int rc = (w >> 1) * 4 + m;
      int g = (o0 + rc * 16) / GROWS;
      if (g == g0 + (int)TID && g < NGRP) {
        S  += sred[slot * 2];
        SS += sred[slot * 2 + 1];
        ++cnt;
      }
    }
    if (cnt) {
      atomicAdd(&statraw[2 * (bz * NGRP + g0 + TID)],     S);
      atomicAdd(&statraw[2 * (bz * NGRP + g0 + TID) + 1], SS);
    }
  }
}

// ---------------- shift-conv GEMM (conv K=4, no im2col duplication) ----------------
// y[b][o][t] = sum_j sum_ci A2[j][o][ci] * aT[b][16+t+j-1][ci] + bias[o]
// BM=128, BN=128, BK=32, 256 thr. LDS: 32 A-chunks (4 planes x 8 rowgrp) + 10 B-chunks (160 rows).
__global__ __launch_bounds__(256) void gemm_c4(const __hip_bfloat16* __restrict__ A2,
    const __hip_bfloat16* __restrict__ aT, const float* __restrict__ bias,
    float* __restrict__ Cout, float* __restrict__ statraw) {
  __shared__ __align__(16) char lds[42 * 1024];
  int t0 = blockIdx.x * 128, o0 = blockIdx.y * 128, bz = blockIdx.z;
  int wave = TID >> 6, lane = TID & 63;
  int l4 = lane >> 4, r15 = lane & 15;
  int wm = wave >> 1, wn = wave & 1;
  const __hip_bfloat16* aTb = aT + (size_t)bz * 1056 * 512;

  f32x4 acc[4][4];
  f32x4 zz = {0.f, 0.f, 0.f, 0.f};
  #pragma unroll
  for (int m = 0; m < 4; ++m)
    #pragma unroll
    for (int n = 0; n < 4; ++n) acc[m][n] = zz;

  for (int kt = 0; kt < 16; ++kt) {
    #pragma unroll
    for (int c = 0; c < 11; ++c) {
      int ch = c * 4 + wave;
      if (ch < 42) {
        const __hip_bfloat16* src;
        if (ch < 32) {
          int j = ch >> 3, rg = ch & 7;
          src = A2 + ((size_t)j * 512 + o0 + rg * 16 + r15) * 512 + kt * 32 + l4 * 8;
        } else {
          int rg = ch - 32;   // window rows P = t0 .. t0+159
          src = aTb + (size_t)(t0 + rg * 16 + r15) * 512 + kt * 32 + l4 * 8;
        }
        async16(src, lds + ch * 1024 + lane * 16);
      }
    }
    __syncthreads();
    #pragma unroll
    for (int j = 0; j < 4; ++j) {
      bf16x8 af[4], bfr[4];
      #pragma unroll
      for (int m = 0; m < 4; ++m)
        af[m] = *reinterpret_cast<const bf16x8*>(lds + (j * 8 + wm * 4 + m) * 1024 + lane * 16);
      #pragma unroll
      for (int n = 0; n < 4; ++n) {
        int q = (wn * 4 + n) * 16 + r15 + j + 15;  // P - t0 for row t_local + j - 1 (+16 pad)
        bfr[n] = *reinterpret_cast<const bf16x8*>(lds + 32 * 1024 + (q >> 4) * 1024 + l4 * 256 + (q & 15) * 16);
      }
      #pragma unroll
      for (int m = 0; m < 4; ++m)
        #pragma unroll
        for (int n = 0; n < 4; ++n)
          acc[m][n] = __builtin_amdgcn_mfma_f32_16x16x32_bf16(af[m], bfr[n], acc[m][n], 0, 0, 0);
    }
    __syncthreads();
  }

  // epilogue: store f32 + bias, fused GN raw stats (GROWS=64, NGRP=8)
  float* sred = reinterpret_cast<float*>(lds);
  #pragma unroll
  for (int m = 0; m < 4; ++m) {
    float s = 0.f, ss2 = 0.f;
    #pragma unroll
    for (int n = 0; n < 4; ++n) {
      int ocol = t0 + (wn * 4 + n) * 16 + r15;
      #pragma unroll
      for (int r = 0; r < 4; ++r) {
        int orow = o0 + (wm * 4 + m) * 16 + l4 * 4 + r;
        float v = acc[m][n][r] + bias[orow];
        Cout[((size_t)bz * Cc + orow) * 1024 + ocol] = v;
        s += v;
        ss2 += v * v;
      }
    }
    #pragma unroll
    for (int off = 1; off < 64; off <<= 1) {
      s   += __shfl_xor(s, off);
      ss2 += __shfl_xor(ss2, off);
    }
    if (lane == 0) {
      sred[(wave * 4 + m) * 2]     = s;
      sred[(wave * 4 + m) * 2 + 1] = ss2;
    }
  }
  __syncthreads();
  if (TID < 2) {
    int g0 = o0 >> 6;
    float S = 0.f, SS = 0.f;
    int cnt = 0;
    #pragma unroll
    for (int slot = 0; slot < 16; ++slot) {
      int rc = ((slot >> 3) << 2) + (slot & 3);
      int g = (o0 + rc * 16) >> 6;
      if (g == g0 + (int)TID) {
        S  += sred[slot * 2];
        SS += sred[slot * 2 + 1];
        ++cnt;
      }
    }
    if (cnt) {
      atomicAdd(&statraw[2 * (bz * 8 + g0 + TID)],     S);
      atomicAdd(&statraw[2 * (bz * 8 + g0 + TID) + 1], SS);
    }
  }
}

// ---------------- fused GN(8)+Mish + build attn input images (bf16 qkv input, raw stats) ----------------
__global__ __launch_bounds__(256) void gn2_prep(const __hip_bfloat16* __restrict__ qkv,
    const float* __restrict__ straw, const float* __restrict__ w, const float* __restrict__ bv,
    char* __restrict__ qTp, char* __restrict__ kimg, char* __restrict__ vimg) {
  __shared__ unsigned short hbf[192 * 66];
  int tl = blockIdx.x & 15, hb = blockIdx.x >> 4;
  int b = hb >> 3, hd = hb & 7;
  float rs = straw[2 * (b * 8 + hd)], rq = straw[2 * (b * 8 + hd) + 1];
  float mean = rs * (1.f / 196608.f);
  float rstd = rsqrtf(fmaxf(rq * (1.f / 196608.f) - mean * mean, 0.f) + 1e-5f);
  for (int task = TID; task < 768; task += 256) {
    int row = task >> 2, seg = task & 3;
    int ch = hd * 192 + row;
    float sw = w[ch] * rstd;
    float sb = bv[ch] - mean * sw;
    const uint4* src = reinterpret_cast<const uint4*>(
        qkv + ((size_t)(b * C3 + ch)) * 1024 + tl * 64 + seg * 16);
    uint4 u0 = src[0], u1 = src[1];
    unsigned int uu[8] = {u0.x, u0.y, u0.z, u0.w, u1.x, u1.y, u1.z, u1.w};
    unsigned int* dst = reinterpret_cast<unsigned int*>(&hbf[row * 66 + seg * 16]);
    #pragma unroll
    for (int j = 0; j < 8; ++j) {
      float a = mishf(bf2f((unsigned short)(uu[j] & 0xffff)) * sw + sb);
      float c = mishf(bf2f((unsigned short)(uu[j] >> 16)) * sw + sb);
      dst[j] = pack2bf(a, c);
    }
  }
  __syncthreads();
  size_t tileof = ((size_t)hb * 16 + tl) * 8192;
  {
    int t = TID & 63, sel = TID >> 6;
    int img = sel >> 1, half = sel & 1;
    char* obase = (img == 0 ? qTp : kimg) + tileof + (size_t)t * 128;
    #pragma unroll
    for (int cc = 0; cc < 4; ++cc) {
      int chunk = half * 4 + cc;
      uint4 u;
      unsigned int* up = reinterpret_cast<unsigned int*>(&u);
      #pragma unroll
      for (int j = 0; j < 4; ++j) {
        int c = chunk * 8 + j * 2;
        unsigned int lo = hbf[(img * 64 + c) * 66 + t];
        unsigned int hi = hbf[(img * 64 + c + 1) * 66 + t];
        up[j] = lo | (hi << 16);
      }
      int cpos = (img == 0) ? chunk : (chunk ^ (t & 7));
      *reinterpret_cast<uint4*>(obase + cpos * 16) = u;
    }
  }
  {
    int c = TID & 63, qtr = TID >> 6;
    const unsigned int* vrow = reinterpret_cast<const unsigned int*>(&hbf[(128 + c) * 66]);
    char* obase = vimg + tileof + (size_t)c * 128;
    #pragma unroll
    for (int k = 0; k < 2; ++k) {
      int chunk = qtr * 2 + k;
      uint4 u;
      unsigned int* up = reinterpret_cast<unsigned int*>(&u);
      #pragma unroll
      for (int j = 0; j < 4; ++j) up[j] = vrow[chunk * 4 + j];
      *reinterpret_cast<uint4*>(obase + (chunk ^ (c & 7)) * 16) = u;
    }
  }
}

// ---------------- MFMA flash attention v3: 512 threads, 2 q-tiles/block; writes bf16 aT ----------------
__global__ __launch_bounds__(512) void attn_mfma3(const char* __restrict__ qTp,
    const char* __restrict__ kimg, const char* __restrict__ vimg,
    __hip_bfloat16* __restrict__ aT) {
  __shared__ __align__(16) char smem[49152];
  char* kbuf0 = smem;
  char* kbuf1 = smem + 8192;
  char* vbuf0 = smem + 16384;
  char* vbuf1 = smem + 24576;
  char* pp    = smem + 32768;  // 8 waves x 2KB
  char* ov    = smem;          // 16KB alias (dead K/V buffers)

  int hb = blockIdx.y;
  int b = hb >> 3, hd = hb & 7;
  int lane = TID & 63, wave = TID >> 6;
  int qt = wave >> 2, qw = wave & 3;
  int l4 = lane >> 4, r15 = lane & 15;
  size_t ibase = (size_t)hb * 16 * 8192;
  const char* ksrc = kimg + ibase;
  const char* vsrc = vimg + ibase;

  async16(ksrc + (size_t)TID * 16, kbuf0 + (size_t)TID * 16);
  async16(vsrc + (size_t)TID * 16, vbuf0 + (size_t)TID * 16);

  bf16x8 aq[2];
  int tg = qw * 16 + r15;
  const char* qrow = qTp + ibase + (size_t)(blockIdx.x * 2 + qt) * 8192 + (size_t)tg * 128;
  aq[0] = *reinterpret_cast<const bf16x8*>(qrow + l4 * 16);
  aq[1] = *reinterpret_cast<const bf16x8*>(qrow + 64 + l4 * 16);

  f32x4 osum[4];
  f32x4 zz = {0.f, 0.f, 0.f, 0.f};
  #pragma unroll
  for (int cf = 0; cf < 4; ++cf) osum[cf] = zz;
  float mrow[4] = {-1e30f, -1e30f, -1e30f, -1e30f};
  float lrow[4] = {0.f, 0.f, 0.f, 0.f};
  __syncthreads();

  for (int it = 0; it < 16; ++it) {
    char* kcur = (it & 1) ? kbuf1 : kbuf0;
    char* vcur = (it & 1) ? vbuf1 : vbuf0;
    if (it < 15) {
      char* knxt = (it & 1) ? kbuf0 : kbuf1;
      char* vnxt = (it & 1) ? vbuf0 : vbuf1;
      const char* kn = ksrc + (size_t)(it + 1) * 8192;
      const char* vn = vsrc + (size_t)(it + 1) * 8192;
      async16(kn + (size_t)TID * 16, knxt + (size_t)TID * 16);
      async16(vn + (size_t)TID * 16, vnxt + (size_t)TID * 16);
    }
    f32x4 sc[4];
    #pragma unroll
    for (int sf = 0; sf < 4; ++sf) sc[sf] = zz;
    #pragma unroll
    for (int sf = 0; sf < 4; ++sf) {
      int sr = sf * 16 + r15;
      #pragma unroll
      for (int kk = 0; kk < 2; ++kk) {
        bf16x8 bk = *reinterpret_cast<const bf16x8*>(kcur + sr * 128 + (((kk * 4 + l4) ^ (sr & 7)) << 4));
        sc[sf] = __builtin_amdgcn_mfma_f32_16x16x32_bf16(aq[kk], bk, sc[sf], 0, 0, 0);
      }
    }
    float tmax[4];
    #pragma unroll
    for (int r = 0; r < 4; ++r)
      tmax[r] = fmaxf(fmaxf(sc[0][r], sc[1][r]), fmaxf(sc[2][r], sc[3][r]));
    #pragma unroll
    for (int off = 1; off < 16; off <<= 1)
      #pragma unroll
      for (int r = 0; r < 4; ++r) tmax[r] = fmaxf(tmax[r], __shfl_xor(tmax[r], off));
    float alpha[4];
    #pragma unroll
    for (int r = 0; r < 4; ++r) {
      float mnew = fmaxf(mrow[r], tmax[r]);
      alpha[r] = __expf((mrow[r] - mnew) * 0.125f);
      mrow[r] = mnew;
      lrow[r] *= alpha[r];
    }
    #pragma unroll
    for (int cf = 0; cf < 4; ++cf)
      #pragma unroll
      for (int r = 0; r < 4; ++r) osum[cf][r] *= alpha[r];
    char* pw = pp + wave * 2048;
    float psum[4] = {0.f, 0.f, 0.f, 0.f};
    #pragma unroll
    for (int sf = 0; sf < 4; ++sf) {
      int s = sf * 16 + r15;
      #pragma unroll
      for (int r = 0; r < 4; ++r) {
        float p = __expf((sc[sf][r] - mrow[r]) * 0.125f);
        psum[r] += p;
        int tlc = l4 * 4 + r;
        *reinterpret_cast<__hip_bfloat16*>(pw + tlc * 128 + ((((s >> 3) ^ (tlc & 7)) << 4) | ((s & 7) * 2)))
            = __float2bfloat16(p);
      }
    }
    #pragma unroll
    for (int r = 0; r < 4; ++r) lrow[r] += psum[r];
    asm volatile("s_waitcnt lgkmcnt(0)" ::: "memory");
    __builtin_amdgcn_sched_barrier(0);

    bf16x8 pa[2];
    #pragma unroll
    for (int kk = 0; kk < 2; ++kk)
      pa[kk] = *reinterpret_cast<const bf16x8*>(pw + r15 * 128 + (((kk * 4 + l4) ^ (r15 & 7)) << 4));
    #pragma unroll
    for (int cf = 0; cf < 4; ++cf) {
      int cr = cf * 16 + r15;
      #pragma unroll
      for (int kk = 0; kk < 2; ++kk) {
        bf16x8 bv = *reinterpret_cast<const bf16x8*>(vcur + cr * 128 + (((kk * 4 + l4) ^ (cr & 7)) << 4));
        osum[cf] = __builtin_amdgcn_mfma_f32_16x16x32_bf16(pa[kk], bv, osum[cf], 0, 0, 0);
      }
    }
    __syncthreads();
  }

  #pragma unroll
  for (int off = 1; off < 16; off <<= 1)
    #pragma unroll
    for (int r = 0; r < 4; ++r) lrow[r] += __shfl_xor(lrow[r], off);
  float linv[4];
  #pragma unroll
  for (int r = 0; r < 4; ++r) linv[r] = 1.f / lrow[r];

  // ov[t][c] bf16 (chunk-swizzled rows of 128B), then coalesced aT store
  #pragma unroll
  for (int cf = 0; cf < 4; ++cf) {
    int c = cf * 16 + r15;
    #pragma unroll
    for (int r = 0; r < 4; ++r) {
      int t = qt * 64 + qw * 16 + l4 * 4 + r;
      *reinterpret_cast<__hip_bfloat16*>(ov + t * 128 + ((((c >> 3) ^ (t & 7)) << 4) | ((c & 7) * 2)))
          = __float2bfloat16(osum[cf][r] * linv[r]);
    }
  }
  __syncthreads();
  __hip_bfloat16* ap = aT + ((size_t)b * 1056 + 16 + blockIdx.x * 128) * 512 + hd * 64;
  for (int u = TID; u < 1024; u += 512) {
    int t = u >> 3, cj = u & 7;
    uint4 o4 = *reinterpret_cast<const uint4*>(ov + t * 128 + ((cj ^ (t & 7)) << 4));
    *reinterpret_cast<uint4*>(ap + (size_t)t * 512 + cj * 8) = o4;
  }
}

// ---------------- final: out = x + mish(gn(y2)) in-place on d_out (raw stats) ----------------
__global__ __launch_bounds__(256) void final_kernel(const float* __restrict__ x,
    float* __restrict__ y, const float* __restrict__ straw,
    const float* __restrict__ w, const float* __restrict__ bv) {
  size_t i = ((size_t)blockIdx.x * 256 + TID) * 4;
  int ch = (int)((i >> 10) & (Cc - 1));
  int b = (int)(i >> 19);
  int g = b * 8 + (ch >> 6);
  float rs = straw[2 * g], rq = straw[2 * g + 1];
  float mean = rs * (1.f / 65536.f);
  float rstd = rsqrtf(fmaxf(rq * (1.f / 65536.f) - mean * mean, 0.f) + 1e-5f);
  float sw = w[ch] * rstd;
  float sb = bv[ch] - mean * sw;
  float4 v  = *reinterpret_cast<const float4*>(y + i);
  float4 xv = *reinterpret_cast<const float4*>(x + i);
  v.x = xv.x + mishf(v.x * sw + sb);
  v.y = xv.y + mishf(v.y * sw + sb);
  v.z = xv.z + mishf(v.z * sw + sb);
  v.w = xv.w + mishf(v.w * sw + sb);
  *reinterpret_cast<float4*>(y + i) = v;
}

extern "C" void kernel_launch(void* const* d_in, const int* in_sizes, int n_in,
                              void* d_out, int out_size, void* d_ws, size_t ws_size,
                              hipStream_t stream) {
  const float* x     = (const float*)d_in[0];
  const float* gn_w  = (const float*)d_in[1];
  const float* gn_b  = (const float*)d_in[2];
  const float* wqkv  = (const float*)d_in[3];
  const float* bqkv  = (const float*)d_in[4];
  const float* gnq_w = (const float*)d_in[5];
  const float* gnq_b = (const float*)d_in[6];
  const float* wproj = (const float*)d_in[7];
  const float* bproj = (const float*)d_in[8];
  const float* gnp_w = (const float*)d_in[9];
  const float* gnp_b = (const float*)d_in[10];
  float* out = (float*)d_out;

  char* ws = (char*)d_ws;
  const size_t MB = 1024 * 1024;
  // Time-multiplexed workspace (<= 64MB):
  __hip_bfloat16* qkvb = (__hip_bfloat16*)ws;            // [0,24MB)   step5 -> step6
  __hip_bfloat16* aT   = (__hip_bfloat16*)(ws + 24 * MB);// [24,33MB)  step2/7 -> step9 (padded 8x1056x512)
  __hip_bfloat16* A1   = (__hip_bfloat16*)(ws + 56 * MB);// [56,59MB)  step3 -> step5
  char* vimg = ws + 56 * MB;                             // [56,64MB)  step6 -> step7 (A1 dead)
  __hip_bfloat16* A2   = (__hip_bfloat16*)(ws + 56 * MB);// [56,58MB)  step8 -> step9 (vimg dead)
  float* st2raw = (float*)(ws + 64 * MB);                // 128 floats
  float* st3raw = st2raw + 128;                          // 128 floats
  __hip_bfloat16* B1t = (__hip_bfloat16*)d_out;          // d_out as B1t  step4 -> step5
  char* qTp  = (char*)d_out;                             // d_out[0,8MB)  step6 -> step7
  char* kimg = (char*)d_out + 8 * MB;                    // d_out[8,16MB) step6 -> step7

  dim3 blk(256);
  zero_stats<<<1, blk, 0, stream>>>(st2raw);                                       // 1
  zero_pads<<<64, blk, 0, stream>>>(aT);                                           // 2
  cast_bf16<<<1536, blk, 0, stream>>>(wqkv, A1, C3 * 1024);                        // 3
  gn1_im2col<<<256, blk, 0, stream>>>(x, gn_w, gn_b, B1t);                         // 4
  gemm_bt8<1024, 192, 8, true><<<dim3(8, 6, 8), dim3(512), 0, stream>>>(
      A1, B1t, bqkv, qkvb, st2raw, C3);                                            // 5
  gn2_prep<<<1024, blk, 0, stream>>>(qkvb, st2raw, gnq_w, gnq_b, qTp, kimg, vimg); // 6
  attn_mfma3<<<dim3(8, 64), dim3(512), 0, stream>>>(qTp, kimg, vimg, aT);          // 7
  cast_wproj<<<512, blk, 0, stream>>>(wproj, A2);                                  // 8
  gemm_c4<<<dim3(8, 4, 8), blk, 0, stream>>>(A2, aT, bproj, out, st3raw);          // 9
  final_kernel<<<4096, blk, 0, stream>>>(x, out, st3raw, gnp_w, gnp_b);            // 10
}

// Round 14
// 186.489 us; speedup vs baseline: 1.8697x; 1.0278x over previous
//
#include <hip/hip_runtime.h>
#include <hip/hip_bf16.h>
#include <math.h>

#define TID threadIdx.x

constexpr int Cc = 512, Tt = 1024, C3 = 1536;

typedef __attribute__((ext_vector_type(8))) __bf16 bf16x8;
typedef __attribute__((ext_vector_type(4))) float f32x4;

__device__ __forceinline__ void async16(const void* g, void* l) {
  __builtin_amdgcn_global_load_lds(
      (const __attribute__((address_space(1))) unsigned int*)g,
      (__attribute__((address_space(3))) unsigned int*)l, 16, 0, 0);
}

__device__ __forceinline__ unsigned int pack2bf(float a, float b) {
  __hip_bfloat162 h;
  h.x = __float2bfloat16(a);
  h.y = __float2bfloat16(b);
  return *reinterpret_cast<unsigned int*>(&h);
}

__device__ __forceinline__ float bf2f(unsigned short u) {
  unsigned int t = ((unsigned int)u) << 16;
  union { unsigned int i; float f; } c;
  c.i = t;
  return c.f;
}

// mish(x) = x * n/(n+2), n = u*(u+2), u = e^x  (one hw exp + one rcp)
__device__ __forceinline__ float mishf(float x) {
  float u = __expf(x);
  float n = u * (u + 2.f);
  float r = x * n * __builtin_amdgcn_rcpf(n + 2.f);
  return (x > 20.f) ? x : r;
}

__device__ __forceinline__ void blockReduce2(float& s, float& ss) {
  #pragma unroll
  for (int off = 32; off > 0; off >>= 1) {
    s  += __shfl_xor(s,  off);
    ss += __shfl_xor(ss, off);
  }
  __shared__ float ls[4], lss[4];
  int w = TID >> 6;
  if ((TID & 63) == 0) { ls[w] = s; lss[w] = ss; }
  __syncthreads();
  s  = ls[0] + ls[1] + ls[2] + ls[3];
  ss = lss[0] + lss[1] + lss[2] + lss[3];
}

// ---------------- zero the raw-stat accumulators (256 floats) ----------------
__global__ void zero_stats(float* p) { p[TID] = 0.f; }

// ---------------- zero the 16-row halo pads of aT[8][1056][512] ----------------
__global__ __launch_bounds__(256) void zero_pads(__hip_bfloat16* __restrict__ aT) {
  int idx = blockIdx.x * 256 + TID;
  int bb = idx >> 11;
  int task = idx & 2047;
  int prow = task >> 6;
  int col = (task & 63) * 8;
  int P = (prow < 16) ? prow : (1024 + prow);
  uint4 z = {0u, 0u, 0u, 0u};
  *reinterpret_cast<uint4*>(aT + ((size_t)bb * 1056 + P) * 512 + col) = z;
}

// ---------------- fused GN(32) + im2col(K=2, pad_lo=0) -> bf16 B1t[b][t][k=2ci+j] ----------------
__global__ __launch_bounds__(256) void gn1_im2col(const float* __restrict__ x,
    const float* __restrict__ w, const float* __restrict__ bv,
    __hip_bfloat16* __restrict__ B1t) {
  __shared__ float hs[16][262];
  int blk = blockIdx.x, bb = blk >> 5, g = blk & 31;
  size_t base = ((size_t)bb * Cc + g * 16) * Tt;
  const float* xp = x + base;
  float s = 0.f, ss = 0.f;
  for (int i = TID * 4; i < 16 * Tt; i += 1024) {
    float4 v = *reinterpret_cast<const float4*>(xp + i);
    s  += v.x + v.y + v.z + v.w;
    ss += v.x * v.x + v.y * v.y + v.z * v.z + v.w * v.w;
  }
  blockReduce2(s, ss);
  float mean = s * (1.f / 16384.f);
  float rstd = rsqrtf(ss * (1.f / 16384.f) - mean * mean + 1e-5f);

  char* ob = reinterpret_cast<char*>(B1t + (size_t)bb * Tt * 1024 + g * 32);
  for (int tc = 0; tc < 4; ++tc) {
    int tbase = tc * 256;
    __syncthreads();
    for (int task = TID; task < 1024; task += 256) {
      int row = task >> 6, c4 = task & 63;
      int ch = g * 16 + row;
      float sw = w[ch] * rstd;
      float sb = bv[ch] - mean * sw;
      float4 v = *reinterpret_cast<const float4*>(xp + (size_t)row * Tt + tbase + c4 * 4);
      hs[row][c4 * 4 + 0] = v.x * sw + sb;
      hs[row][c4 * 4 + 1] = v.y * sw + sb;
      hs[row][c4 * 4 + 2] = v.z * sw + sb;
      hs[row][c4 * 4 + 3] = v.w * sw + sb;
    }
    if (TID < 16) {
      int row = TID, t = tbase + 256;
      float val = 0.f;
      if (t < Tt) {
        int ch = g * 16 + row;
        float sw = w[ch] * rstd;
        float sb = bv[ch] - mean * sw;
        val = xp[(size_t)row * Tt + t] * sw + sb;
      }
      hs[row][256] = val;
    }
    __syncthreads();
    for (int task = TID; task < 1024; task += 256) {
      int t = task >> 2, cj = task & 3;
      int ci = cj * 4;
      uint4 u;
      u.x = pack2bf(hs[ci + 0][t], hs[ci + 0][t + 1]);
      u.y = pack2bf(hs[ci + 1][t], hs[ci + 1][t + 1]);
      u.z = pack2bf(hs[ci + 2][t], hs[ci + 2][t + 1]);
      u.w = pack2bf(hs[ci + 3][t], hs[ci + 3][t + 1]);
      *reinterpret_cast<uint4*>(ob + ((size_t)(tbase + t) * 1024 + cj * 8) * 2) = u;
    }
  }
}

// ---------------- f32 -> bf16 cast (weights) ----------------
__global__ __launch_bounds__(256) void cast_bf16(const float* __restrict__ in,
    __hip_bfloat16* __restrict__ out, int n) {
  int i = (blockIdx.x * 256 + TID) * 4;
  if (i >= n) return;
  float4 v = *reinterpret_cast<const float4*>(in + i);
  *reinterpret_cast<unsigned int*>(out + i)     = pack2bf(v.x, v.y);
  *reinterpret_cast<unsigned int*>(out + i + 2) = pack2bf(v.z, v.w);
}

// ---------------- wproj [o][ci][4] f32 -> A2[j][o][ci] bf16 ----------------
__global__ __launch_bounds__(256) void cast_wproj(const float* __restrict__ wp,
    __hip_bfloat16* __restrict__ A2) {
  int o = blockIdx.x;
  int ci = TID * 2;
  float4 v0 = *reinterpret_cast<const float4*>(wp + ((size_t)o * 512 + ci) * 4);
  float4 v1 = *reinterpret_cast<const float4*>(wp + ((size_t)o * 512 + ci + 1) * 4);
  const float* a0 = &v0.x;
  const float* a1 = &v1.x;
  #pragma unroll
  for (int j = 0; j < 4; ++j) {
    unsigned int u = pack2bf(a0[j], a1[j]);
    *reinterpret_cast<unsigned int*>(A2 + ((size_t)j * 512 + o) * 512 + ci) = u;
  }
}

// ---------------- bf16 MFMA GEMM v9: 1024 threads, BM=192 x BN=256 (byte-optimal full-fill) ----
// 16 waves 4Mx4N, per-wave 48x64, acc[3][4]. One block = one GN group (192 rows).
__global__ __launch_bounds__(1024, 4) void gemm_bt9(const __hip_bfloat16* __restrict__ A,
    const __hip_bfloat16* __restrict__ Bt, const float* __restrict__ bias,
    __hip_bfloat16* __restrict__ Cout, float* __restrict__ statraw) {
  constexpr int K = 1024;
  __shared__ __align__(16) char lds[56 * 1024];   // 24 A-chunks + 32 B-chunks of 1KB
  int t0 = blockIdx.x * 256, o0 = blockIdx.y * 192, bz = blockIdx.z;
  int wave = TID >> 6, lane = TID & 63;
  int l4 = lane >> 4, r15 = lane & 15;
  int wm = wave >> 2, wn = wave & 3;
  const __hip_bfloat16* Ab = A + (size_t)o0 * K;
  const __hip_bfloat16* Bb = Bt + ((size_t)bz * 1024 + t0) * K;

  f32x4 acc[3][4];
  f32x4 zz = {0.f, 0.f, 0.f, 0.f};
  #pragma unroll
  for (int m = 0; m < 3; ++m)
    #pragma unroll
    for (int n = 0; n < 4; ++n) acc[m][n] = zz;

  for (int kt = 0; kt < 16; ++kt) {
    #pragma unroll
    for (int c = 0; c < 4; ++c) {
      int ch = c * 16 + wave;
      if (ch < 56) {
        int kof = kt * 64 + (ch & 1) * 32 + l4 * 8;
        const __hip_bfloat16* src;
        if (ch < 24) {
          int row = (ch >> 1) * 16 + r15;
          src = Ab + (size_t)row * K + kof;
        } else {
          int cb = ch - 24;
          int row = (cb >> 1) * 16 + r15;
          kof = kt * 64 + (cb & 1) * 32 + l4 * 8;
          src = Bb + (size_t)row * K + kof;
        }
        async16(src, lds + ch * 1024 + lane * 16);
      }
    }
    __syncthreads();
    #pragma unroll
    for (int kk = 0; kk < 2; ++kk) {
      bf16x8 af[3], bfr[4];
      #pragma unroll
      for (int m = 0; m < 3; ++m)
        af[m] = *reinterpret_cast<const bf16x8*>(lds + ((wm * 3 + m) * 2 + kk) * 1024 + lane * 16);
      #pragma unroll
      for (int n = 0; n < 4; ++n)
        bfr[n] = *reinterpret_cast<const bf16x8*>(lds + (24 + (wn * 4 + n) * 2 + kk) * 1024 + lane * 16);
      #pragma unroll
      for (int m = 0; m < 3; ++m)
        #pragma unroll
        for (int n = 0; n < 4; ++n)
          acc[m][n] = __builtin_amdgcn_mfma_f32_16x16x32_bf16(af[m], bfr[n], acc[m][n], 0, 0, 0);
    }
    __syncthreads();
  }

  // epilogue: bf16 store (+bias); block covers exactly one GN group (192 rows)
  float* sred = reinterpret_cast<float*>(lds);   // 96 floats, buffer dead
  #pragma unroll
  for (int m = 0; m < 3; ++m) {
    float s = 0.f, ss2 = 0.f;
    #pragma unroll
    for (int n = 0; n < 4; ++n) {
      int ocol = t0 + (wn * 4 + n) * 16 + r15;
      #pragma unroll
      for (int r = 0; r < 4; ++r) {
        int orow = o0 + (wm * 3 + m) * 16 + l4 * 4 + r;
        float v = acc[m][n][r] + bias[orow];
        Cout[((size_t)bz * C3 + orow) * 1024 + ocol] = __float2bfloat16(v);
        s += v;
        ss2 += v * v;
      }
    }
    #pragma unroll
    for (int off = 1; off < 64; off <<= 1) {
      s   += __shfl_xor(s, off);
      ss2 += __shfl_xor(ss2, off);
    }
    if (lane == 0) {
      sred[(wave * 3 + m) * 2]     = s;
      sred[(wave * 3 + m) * 2 + 1] = ss2;
    }
  }
  __syncthreads();
  if (TID == 0) {
    float S = 0.f, SS = 0.f;
    #pragma unroll
    for (int slot = 0; slot < 48; ++slot) {
      S  += sred[slot * 2];
      SS += sred[slot * 2 + 1];
    }
    int g = bz * 8 + blockIdx.y;
    atomicAdd(&statraw[2 * g],     S);
    atomicAdd(&statraw[2 * g + 1], SS);
  }
}

// ---------------- shift-conv GEMM (conv K=4, no im2col duplication), R13-proven ----------------
__global__ __launch_bounds__(256) void gemm_c4(const __hip_bfloat16* __restrict__ A2,
    const __hip_bfloat16* __restrict__ aT, const float* __restrict__ bias,
    float* __restrict__ Cout, float* __restrict__ statraw) {
  __shared__ __align__(16) char lds[42 * 1024];
  int t0 = blockIdx.x * 128, o0 = blockIdx.y * 128, bz = blockIdx.z;
  int wave = TID >> 6, lane = TID & 63;
  int l4 = lane >> 4, r15 = lane & 15;
  int wm = wave >> 1, wn = wave & 1;
  const __hip_bfloat16* aTb = aT + (size_t)bz * 1056 * 512;

  f32x4 acc[4][4];
  f32x4 zz = {0.f, 0.f, 0.f, 0.f};
  #pragma unroll
  for (int m = 0; m < 4; ++m)
    #pragma unroll
    for (int n = 0; n < 4; ++n) acc[m][n] = zz;

  for (int kt = 0; kt < 16; ++kt) {
    #pragma unroll
    for (int c = 0; c < 11; ++c) {
      int ch = c * 4 + wave;
      if (ch < 42) {
        const __hip_bfloat16* src;
        if (ch < 32) {
          int j = ch >> 3, rg = ch & 7;
          src = A2 + ((size_t)j * 512 + o0 + rg * 16 + r15) * 512 + kt * 32 + l4 * 8;
        } else {
          int rg = ch - 32;
          src = aTb + (size_t)(t0 + rg * 16 + r15) * 512 + kt * 32 + l4 * 8;
        }
        async16(src, lds + ch * 1024 + lane * 16);
      }
    }
    __syncthreads();
    #pragma unroll
    for (int j = 0; j < 4; ++j) {
      bf16x8 af[4], bfr[4];
      #pragma unroll
      for (int m = 0; m < 4; ++m)
        af[m] = *reinterpret_cast<const bf16x8*>(lds + (j * 8 + wm * 4 + m) * 1024 + lane * 16);
      #pragma unroll
      for (int n = 0; n < 4; ++n) {
        int q = (wn * 4 + n) * 16 + r15 + j + 15;
        bfr[n] = *reinterpret_cast<const bf16x8*>(lds + 32 * 1024 + (q >> 4) * 1024 + l4 * 256 + (q & 15) * 16);
      }
      #pragma unroll
      for (int m = 0; m < 4; ++m)
        #pragma unroll
        for (int n = 0; n < 4; ++n)
          acc[m][n] = __builtin_amdgcn_mfma_f32_16x16x32_bf16(af[m], bfr[n], acc[m][n], 0, 0, 0);
    }
    __syncthreads();
  }

  float* sred = reinterpret_cast<float*>(lds);
  #pragma unroll
  for (int m = 0; m < 4; ++m) {
    float s = 0.f, ss2 = 0.f;
    #pragma unroll
    for (int n = 0; n < 4; ++n) {
      int ocol = t0 + (wn * 4 + n) * 16 + r15;
      #pragma unroll
      for (int r = 0; r < 4; ++r) {
        int orow = o0 + (wm * 4 + m) * 16 + l4 * 4 + r;
        float v = acc[m][n][r] + bias[orow];
        Cout[((size_t)bz * Cc + orow) * 1024 + ocol] = v;
        s += v;
        ss2 += v * v;
      }
    }
    #pragma unroll
    for (int off = 1; off < 64; off <<= 1) {
      s   += __shfl_xor(s, off);
      ss2 += __shfl_xor(ss2, off);
    }
    if (lane == 0) {
      sred[(wave * 4 + m) * 2]     = s;
      sred[(wave * 4 + m) * 2 + 1] = ss2;
    }
  }
  __syncthreads();
  if (TID < 2) {
    int g0 = o0 >> 6;
    float S = 0.f, SS = 0.f;
    int cnt = 0;
    #pragma unroll
    for (int slot = 0; slot < 16; ++slot) {
      int rc = ((slot >> 3) << 2) + (slot & 3);
      int g = (o0 + rc * 16) >> 6;
      if (g == g0 + (int)TID) {
        S  += sred[slot * 2];
        SS += sred[slot * 2 + 1];
        ++cnt;
      }
    }
    if (cnt) {
      atomicAdd(&statraw[2 * (bz * 8 + g0 + TID)],     S);
      atomicAdd(&statraw[2 * (bz * 8 + g0 + TID) + 1], SS);
    }
  }
}

// ---------------- fused GN(8)+Mish + build attn input images (bf16 qkv input, raw stats) ----------------
__global__ __launch_bounds__(256) void gn2_prep(const __hip_bfloat16* __restrict__ qkv,
    const float* __restrict__ straw, const float* __restrict__ w, const float* __restrict__ bv,
    char* __restrict__ qTp, char* __restrict__ kimg, char* __restrict__ vimg) {
  __shared__ unsigned short hbf[192 * 66];
  int tl = blockIdx.x & 15, hb = blockIdx.x >> 4;
  int b = hb >> 3, hd = hb & 7;
  float rs = straw[2 * (b * 8 + hd)], rq = straw[2 * (b * 8 + hd) + 1];
  float mean = rs * (1.f / 196608.f);
  float rstd = rsqrtf(fmaxf(rq * (1.f / 196608.f) - mean * mean, 0.f) + 1e-5f);
  for (int task = TID; task < 768; task += 256) {
    int row = task >> 2, seg = task & 3;
    int ch = hd * 192 + row;
    float sw = w[ch] * rstd;
    float sb = bv[ch] - mean * sw;
    const uint4* src = reinterpret_cast<const uint4*>(
        qkv + ((size_t)(b * C3 + ch)) * 1024 + tl * 64 + seg * 16);
    uint4 u0 = src[0], u1 = src[1];
    unsigned int uu[8] = {u0.x, u0.y, u0.z, u0.w, u1.x, u1.y, u1.z, u1.w};
    unsigned int* dst = reinterpret_cast<unsigned int*>(&hbf[row * 66 + seg * 16]);
    #pragma unroll
    for (int j = 0; j < 8; ++j) {
      float a = mishf(bf2f((unsigned short)(uu[j] & 0xffff)) * sw + sb);
      float c = mishf(bf2f((unsigned short)(uu[j] >> 16)) * sw + sb);
      dst[j] = pack2bf(a, c);
    }
  }
  __syncthreads();
  size_t tileof = ((size_t)hb * 16 + tl) * 8192;
  {
    int t = TID & 63, sel = TID >> 6;
    int img = sel >> 1, half = sel & 1;
    char* obase = (img == 0 ? qTp : kimg) + tileof + (size_t)t * 128;
    #pragma unroll
    for (int cc = 0; cc < 4; ++cc) {
      int chunk = half * 4 + cc;
      uint4 u;
      unsigned int* up = reinterpret_cast<unsigned int*>(&u);
      #pragma unroll
      for (int j = 0; j < 4; ++j) {
        int c = chunk * 8 + j * 2;
        unsigned int lo = hbf[(img * 64 + c) * 66 + t];
        unsigned int hi = hbf[(img * 64 + c + 1) * 66 + t];
        up[j] = lo | (hi << 16);
      }
      int cpos = (img == 0) ? chunk : (chunk ^ (t & 7));
      *reinterpret_cast<uint4*>(obase + cpos * 16) = u;
    }
  }
  {
    int c = TID & 63, qtr = TID >> 6;
    const unsigned int* vrow = reinterpret_cast<const unsigned int*>(&hbf[(128 + c) * 66]);
    char* obase = vimg + tileof + (size_t)c * 128;
    #pragma unroll
    for (int k = 0; k < 2; ++k) {
      int chunk = qtr * 2 + k;
      uint4 u;
      unsigned int* up = reinterpret_cast<unsigned int*>(&u);
      #pragma unroll
      for (int j = 0; j < 4; ++j) up[j] = vrow[chunk * 4 + j];
      *reinterpret_cast<uint4*>(obase + (chunk ^ (c & 7)) * 16) = u;
    }
  }
}

// ---------------- MFMA flash attention v4: 1024 threads, 4 q-tiles/block (KV read 4x) ----------------
__global__ __launch_bounds__(1024) void attn_mfma4(const char* __restrict__ qTp,
    const char* __restrict__ kimg, const char* __restrict__ vimg,
    __hip_bfloat16* __restrict__ aT) {
  __shared__ __align__(16) char smem[65536];
  char* kbuf0 = smem;
  char* kbuf1 = smem + 8192;
  char* vbuf0 = smem + 16384;
  char* vbuf1 = smem + 24576;
  char* pp    = smem + 32768;  // 16 waves x 2KB
  char* ov    = smem;          // 32KB alias (dead K/V buffers)

  int hb = blockIdx.y;
  int b = hb >> 3, hd = hb & 7;
  int lane = TID & 63, wave = TID >> 6;
  int qt = wave >> 2, qw = wave & 3;
  int l4 = lane >> 4, r15 = lane & 15;
  size_t ibase = (size_t)hb * 16 * 8192;
  const char* ksrc = kimg + ibase;
  const char* vsrc = vimg + ibase;

  if (TID < 512) async16(ksrc + (size_t)TID * 16, kbuf0 + (size_t)TID * 16);
  else           async16(vsrc + (size_t)(TID - 512) * 16, vbuf0 + (size_t)(TID - 512) * 16);

  bf16x8 aq[2];
  int tg = qw * 16 + r15;
  const char* qrow = qTp + ibase + (size_t)(blockIdx.x * 4 + qt) * 8192 + (size_t)tg * 128;
  aq[0] = *reinterpret_cast<const bf16x8*>(qrow + l4 * 16);
  aq[1] = *reinterpret_cast<const bf16x8*>(qrow + 64 + l4 * 16);

  f32x4 osum[4];
  f32x4 zz = {0.f, 0.f, 0.f, 0.f};
  #pragma unroll
  for (int cf = 0; cf < 4; ++cf) osum[cf] = zz;
  float mrow[4] = {-1e30f, -1e30f, -1e30f, -1e30f};
  float lrow[4] = {0.f, 0.f, 0.f, 0.f};
  __syncthreads();

  for (int it = 0; it < 16; ++it) {
    char* kcur = (it & 1) ? kbuf1 : kbuf0;
    char* vcur = (it & 1) ? vbuf1 : vbuf0;
    if (it < 15) {
      char* knxt = (it & 1) ? kbuf0 : kbuf1;
      char* vnxt = (it & 1) ? vbuf0 : vbuf1;
      const char* kn = ksrc + (size_t)(it + 1) * 8192;
      const char* vn = vsrc + (size_t)(it + 1) * 8192;
      if (TID < 512) async16(kn + (size_t)TID * 16, knxt + (size_t)TID * 16);
      else           async16(vn + (size_t)(TID - 512) * 16, vnxt + (size_t)(TID - 512) * 16);
    }
    f32x4 sc[4];
    #pragma unroll
    for (int sf = 0; sf < 4; ++sf) sc[sf] = zz;
    #pragma unroll
    for (int sf = 0; sf < 4; ++sf) {
      int sr = sf * 16 + r15;
      #pragma unroll
      for (int kk = 0; kk < 2; ++kk) {
        bf16x8 bk = *reinterpret_cast<const bf16x8*>(kcur + sr * 128 + (((kk * 4 + l4) ^ (sr & 7)) << 4));
        sc[sf] = __builtin_amdgcn_mfma_f32_16x16x32_bf16(aq[kk], bk, sc[sf], 0, 0, 0);
      }
    }
    float tmax[4];
    #pragma unroll
    for (int r = 0; r < 4; ++r)
      tmax[r] = fmaxf(fmaxf(sc[0][r], sc[1][r]), fmaxf(sc[2][r], sc[3][r]));
    #pragma unroll
    for (int off = 1; off < 16; off <<= 1)
      #pragma unroll
      for (int r = 0; r < 4; ++r) tmax[r] = fmaxf(tmax[r], __shfl_xor(tmax[r], off));
    float alpha[4];
    #pragma unroll
    for (int r = 0; r < 4; ++r) {
      float mnew = fmaxf(mrow[r], tmax[r]);
      alpha[r] = __expf((mrow[r] - mnew) * 0.125f);
      mrow[r] = mnew;
      lrow[r] *= alpha[r];
    }
    #pragma unroll
    for (int cf = 0; cf < 4; ++cf)
      #pragma unroll
      for (int r = 0; r < 4; ++r) osum[cf][r] *= alpha[r];
    char* pw = pp + wave * 2048;
    float psum[4] = {0.f, 0.f, 0.f, 0.f};
    #pragma unroll
    for (int sf = 0; sf < 4; ++sf) {
      int s = sf * 16 + r15;
      #pragma unroll
      for (int r = 0; r < 4; ++r) {
        float p = __expf((sc[sf][r] - mrow[r]) * 0.125f);
        psum[r] += p;
        int tlc = l4 * 4 + r;
        *reinterpret_cast<__hip_bfloat16*>(pw + tlc * 128 + ((((s >> 3) ^ (tlc & 7)) << 4) | ((s & 7) * 2)))
            = __float2bfloat16(p);
      }
    }
    #pragma unroll
    for (int r = 0; r < 4; ++r) lrow[r] += psum[r];
    asm volatile("s_waitcnt lgkmcnt(0)" ::: "memory");
    __builtin_amdgcn_sched_barrier(0);

    bf16x8 pa[2];
    #pragma unroll
    for (int kk = 0; kk < 2; ++kk)
      pa[kk] = *reinterpret_cast<const bf16x8*>(pw + r15 * 128 + (((kk * 4 + l4) ^ (r15 & 7)) << 4));
    #pragma unroll
    for (int cf = 0; cf < 4; ++cf) {
      int cr = cf * 16 + r15;
      #pragma unroll
      for (int kk = 0; kk < 2; ++kk) {
        bf16x8 bv = *reinterpret_cast<const bf16x8*>(vcur + cr * 128 + (((kk * 4 + l4) ^ (cr & 7)) << 4));
        osum[cf] = __builtin_amdgcn_mfma_f32_16x16x32_bf16(pa[kk], bv, osum[cf], 0, 0, 0);
      }
    }
    __syncthreads();
  }

  #pragma unroll
  for (int off = 1; off < 16; off <<= 1)
    #pragma unroll
    for (int r = 0; r < 4; ++r) lrow[r] += __shfl_xor(lrow[r], off);
  float linv[4];
  #pragma unroll
  for (int r = 0; r < 4; ++r) linv[r] = 1.f / lrow[r];

  // ov[t][c] bf16, t in [0,256), swizzled 128B rows
  #pragma unroll
  for (int cf = 0; cf < 4; ++cf) {
    int c = cf * 16 + r15;
    #pragma unroll
    for (int r = 0; r < 4; ++r) {
      int t = qt * 64 + qw * 16 + l4 * 4 + r;
      *reinterpret_cast<__hip_bfloat16*>(ov + t * 128 + ((((c >> 3) ^ (t & 7)) << 4) | ((c & 7) * 2)))
          = __float2bfloat16(osum[cf][r] * linv[r]);
    }
  }
  __syncthreads();
  __hip_bfloat16* ap = aT + ((size_t)b * 1056 + 16 + blockIdx.x * 256) * 512 + hd * 64;
  for (int u = TID; u < 2048; u += 1024) {
    int t = u >> 3, cj = u & 7;
    uint4 o4 = *reinterpret_cast<const uint4*>(ov + t * 128 + ((cj ^ (t & 7)) << 4));
    *reinterpret_cast<uint4*>(ap + (size_t)t * 512 + cj * 8) = o4;
  }
}

// ---------------- final: out = x + mish(gn(y2)) in-place on d_out (raw stats) ----------------
__global__ __launch_bounds__(256) void final_kernel(const float* __restrict__ x,
    float* __restrict__ y, const float* __restrict__ straw,
    const float* __restrict__ w, const float* __restrict__ bv) {
  size_t i = ((size_t)blockIdx.x * 256 + TID) * 4;
  int ch = (int)((i >> 10) & (Cc - 1));
  int b = (int)(i >> 19);
  int g = b * 8 + (ch >> 6);
  float rs = straw[2 * g], rq = straw[2 * g + 1];
  float mean = rs * (1.f / 65536.f);
  float rstd = rsqrtf(fmaxf(rq * (1.f / 65536.f) - mean * mean, 0.f) + 1e-5f);
  float sw = w[ch] * rstd;
  float sb = bv[ch] - mean * sw;
  float4 v  = *reinterpret_cast<const float4*>(y + i);
  float4 xv = *reinterpret_cast<const float4*>(x + i);
  v.x = xv.x + mishf(v.x * sw + sb);
  v.y = xv.y + mishf(v.y * sw + sb);
  v.z = xv.z + mishf(v.z * sw + sb);
  v.w = xv.w + mishf(v.w * sw + sb);
  *reinterpret_cast<float4*>(y + i) = v;
}

extern "C" void kernel_launch(void* const* d_in, const int* in_sizes, int n_in,
                              void* d_out, int out_size, void* d_ws, size_t ws_size,
                              hipStream_t stream) {
  const float* x     = (const float*)d_in[0];
  const float* gn_w  = (const float*)d_in[1];
  const float* gn_b  = (const float*)d_in[2];
  const float* wqkv  = (const float*)d_in[3];
  const float* bqkv  = (const float*)d_in[4];
  const float* gnq_w = (const float*)d_in[5];
  const float* gnq_b = (const float*)d_in[6];
  const float* wproj = (const float*)d_in[7];
  const float* bproj = (const float*)d_in[8];
  const float* gnp_w = (const float*)d_in[9];
  const float* gnp_b = (const float*)d_in[10];
  float* out = (float*)d_out;

  char* ws = (char*)d_ws;
  const size_t MB = 1024 * 1024;
  __hip_bfloat16* qkvb = (__hip_bfloat16*)ws;            // [0,24MB)   step5 -> step6
  __hip_bfloat16* aT   = (__hip_bfloat16*)(ws + 24 * MB);// [24,33MB)  step2/7 -> step9
  __hip_bfloat16* A1   = (__hip_bfloat16*)(ws + 56 * MB);// [56,59MB)  step3 -> step5
  char* vimg = ws + 56 * MB;                             // [56,64MB)  step6 -> step7 (A1 dead)
  __hip_bfloat16* A2   = (__hip_bfloat16*)(ws + 56 * MB);// [56,58MB)  step8 -> step9 (vimg dead)
  float* st2raw = (float*)(ws + 64 * MB);
  float* st3raw = st2raw + 128;
  __hip_bfloat16* B1t = (__hip_bfloat16*)d_out;          // d_out as B1t  step4 -> step5
  char* qTp  = (char*)d_out;                             // d_out[0,8MB)  step6 -> step7
  char* kimg = (char*)d_out + 8 * MB;                    // d_out[8,16MB) step6 -> step7

  dim3 blk(256);
  zero_stats<<<1, blk, 0, stream>>>(st2raw);                                       // 1
  zero_pads<<<64, blk, 0, stream>>>(aT);                                           // 2
  cast_bf16<<<1536, blk, 0, stream>>>(wqkv, A1, C3 * 1024);                        // 3
  gn1_im2col<<<256, blk, 0, stream>>>(x, gn_w, gn_b, B1t);                         // 4
  gemm_bt9<<<dim3(4, 8, 8), dim3(1024), 0, stream>>>(A1, B1t, bqkv, qkvb, st2raw); // 5
  gn2_prep<<<1024, blk, 0, stream>>>(qkvb, st2raw, gnq_w, gnq_b, qTp, kimg, vimg); // 6
  attn_mfma4<<<dim3(4, 64), dim3(1024), 0, stream>>>(qTp, kimg, vimg, aT);         // 7
  cast_wproj<<<512, blk, 0, stream>>>(wproj, A2);                                  // 8
  gemm_c4<<<dim3(8, 4, 8), blk, 0, stream>>>(A2, aT, bproj, out, st3raw);          // 9
  final_kernel<<<4096, blk, 0, stream>>>(x, out, st3raw, gnp_w, gnp_b);            // 10
}

// Round 15
// 168.446 us; speedup vs baseline: 2.0700x; 1.1071x over previous
//
#include <hip/hip_runtime.h>
#include <hip/hip_bf16.h>
#include <math.h>

#define TID threadIdx.x

constexpr int Cc = 512, Tt = 1024, C3 = 1536;

typedef __attribute__((ext_vector_type(8))) __bf16 bf16x8;
typedef __attribute__((ext_vector_type(4))) float f32x4;

__device__ __forceinline__ void async16(const void* g, void* l) {
  __builtin_amdgcn_global_load_lds(
      (const __attribute__((address_space(1))) unsigned int*)g,
      (__attribute__((address_space(3))) unsigned int*)l, 16, 0, 0);
}

__device__ __forceinline__ unsigned int pack2bf(float a, float b) {
  __hip_bfloat162 h;
  h.x = __float2bfloat16(a);
  h.y = __float2bfloat16(b);
  return *reinterpret_cast<unsigned int*>(&h);
}

__device__ __forceinline__ float bf2f(unsigned short u) {
  unsigned int t = ((unsigned int)u) << 16;
  union { unsigned int i; float f; } c;
  c.i = t;
  return c.f;
}

// mish(x) = x * n/(n+2), n = u*(u+2), u = e^x  (one hw exp + one rcp)
__device__ __forceinline__ float mishf(float x) {
  float u = __expf(x);
  float n = u * (u + 2.f);
  float r = x * n * __builtin_amdgcn_rcpf(n + 2.f);
  return (x > 20.f) ? x : r;
}

__device__ __forceinline__ void blockReduce2(float& s, float& ss) {
  #pragma unroll
  for (int off = 32; off > 0; off >>= 1) {
    s  += __shfl_xor(s,  off);
    ss += __shfl_xor(ss, off);
  }
  __shared__ float ls[4], lss[4];
  int w = TID >> 6;
  if ((TID & 63) == 0) { ls[w] = s; lss[w] = ss; }
  __syncthreads();
  s  = ls[0] + ls[1] + ls[2] + ls[3];
  ss = lss[0] + lss[1] + lss[2] + lss[3];
}

// ---------------- zero the raw-stat accumulators (256 floats) ----------------
__global__ void zero_stats(float* p) { p[TID] = 0.f; }

// ---------------- zero the 16-row halo pads of aT[8][1056][512] ----------------
__global__ __launch_bounds__(256) void zero_pads(__hip_bfloat16* __restrict__ aT) {
  int idx = blockIdx.x * 256 + TID;
  int bb = idx >> 11;
  int task = idx & 2047;
  int prow = task >> 6;
  int col = (task & 63) * 8;
  int P = (prow < 16) ? prow : (1024 + prow);
  uint4 z = {0u, 0u, 0u, 0u};
  *reinterpret_cast<uint4*>(aT + ((size_t)bb * 1056 + P) * 512 + col) = z;
}

// ---------------- fused GN(32) + im2col(K=2, pad_lo=0) -> bf16 B1t[b][t][k=2ci+j] ----------------
__global__ __launch_bounds__(256) void gn1_im2col(const float* __restrict__ x,
    const float* __restrict__ w, const float* __restrict__ bv,
    __hip_bfloat16* __restrict__ B1t) {
  __shared__ float hs[16][262];
  int blk = blockIdx.x, bb = blk >> 5, g = blk & 31;
  size_t base = ((size_t)bb * Cc + g * 16) * Tt;
  const float* xp = x + base;
  float s = 0.f, ss = 0.f;
  for (int i = TID * 4; i < 16 * Tt; i += 1024) {
    float4 v = *reinterpret_cast<const float4*>(xp + i);
    s  += v.x + v.y + v.z + v.w;
    ss += v.x * v.x + v.y * v.y + v.z * v.z + v.w * v.w;
  }
  blockReduce2(s, ss);
  float mean = s * (1.f / 16384.f);
  float rstd = rsqrtf(ss * (1.f / 16384.f) - mean * mean + 1e-5f);

  char* ob = reinterpret_cast<char*>(B1t + (size_t)bb * Tt * 1024 + g * 32);
  for (int tc = 0; tc < 4; ++tc) {
    int tbase = tc * 256;
    __syncthreads();
    for (int task = TID; task < 1024; task += 256) {
      int row = task >> 6, c4 = task & 63;
      int ch = g * 16 + row;
      float sw = w[ch] * rstd;
      float sb = bv[ch] - mean * sw;
      float4 v = *reinterpret_cast<const float4*>(xp + (size_t)row * Tt + tbase + c4 * 4);
      hs[row][c4 * 4 + 0] = v.x * sw + sb;
      hs[row][c4 * 4 + 1] = v.y * sw + sb;
      hs[row][c4 * 4 + 2] = v.z * sw + sb;
      hs[row][c4 * 4 + 3] = v.w * sw + sb;
    }
    if (TID < 16) {
      int row = TID, t = tbase + 256;
      float val = 0.f;
      if (t < Tt) {
        int ch = g * 16 + row;
        float sw = w[ch] * rstd;
        float sb = bv[ch] - mean * sw;
        val = xp[(size_t)row * Tt + t] * sw + sb;
      }
      hs[row][256] = val;
    }
    __syncthreads();
    for (int task = TID; task < 1024; task += 256) {
      int t = task >> 2, cj = task & 3;
      int ci = cj * 4;
      uint4 u;
      u.x = pack2bf(hs[ci + 0][t], hs[ci + 0][t + 1]);
      u.y = pack2bf(hs[ci + 1][t], hs[ci + 1][t + 1]);
      u.z = pack2bf(hs[ci + 2][t], hs[ci + 2][t + 1]);
      u.w = pack2bf(hs[ci + 3][t], hs[ci + 3][t + 1]);
      *reinterpret_cast<uint4*>(ob + ((size_t)(tbase + t) * 1024 + cj * 8) * 2) = u;
    }
  }
}

// ---------------- f32 -> bf16 cast (weights) ----------------
__global__ __launch_bounds__(256) void cast_bf16(const float* __restrict__ in,
    __hip_bfloat16* __restrict__ out, int n) {
  int i = (blockIdx.x * 256 + TID) * 4;
  if (i >= n) return;
  float4 v = *reinterpret_cast<const float4*>(in + i);
  *reinterpret_cast<unsigned int*>(out + i)     = pack2bf(v.x, v.y);
  *reinterpret_cast<unsigned int*>(out + i + 2) = pack2bf(v.z, v.w);
}

// ---------------- wproj [o][ci][4] f32 -> A2[j][o][ci] bf16 ----------------
__global__ __launch_bounds__(256) void cast_wproj(const float* __restrict__ wp,
    __hip_bfloat16* __restrict__ A2) {
  int o = blockIdx.x;
  int ci = TID * 2;
  float4 v0 = *reinterpret_cast<const float4*>(wp + ((size_t)o * 512 + ci) * 4);
  float4 v1 = *reinterpret_cast<const float4*>(wp + ((size_t)o * 512 + ci + 1) * 4);
  const float* a0 = &v0.x;
  const float* a1 = &v1.x;
  #pragma unroll
  for (int j = 0; j < 4; ++j) {
    unsigned int u = pack2bf(a0[j], a1[j]);
    *reinterpret_cast<unsigned int*>(A2 + ((size_t)j * 512 + o) * 512 + ci) = u;
  }
}

// ---------------- bf16 MFMA GEMM v10: BM=192 x BN=256, 1024 thr, ISSUE-AHEAD double buffer ----
// 16 waves 4Mx4N, per-wave 48x64, acc[3][4]. One block = one GN group (192 rows).
__global__ __launch_bounds__(1024, 4) void gemm_bt10(const __hip_bfloat16* __restrict__ A,
    const __hip_bfloat16* __restrict__ Bt, const float* __restrict__ bias,
    __hip_bfloat16* __restrict__ Cout, float* __restrict__ statraw) {
  constexpr int K = 1024;
  constexpr int BUF = 56 * 1024;
  __shared__ __align__(16) char lds[2 * BUF];     // 112 KB (1 block/CU regardless)
  int t0 = blockIdx.x * 256, o0 = blockIdx.y * 192, bz = blockIdx.z;
  int wave = TID >> 6, lane = TID & 63;
  int l4 = lane >> 4, r15 = lane & 15;
  int wm = wave >> 2, wn = wave & 3;
  const __hip_bfloat16* Ab = A + (size_t)o0 * K;
  const __hip_bfloat16* Bb = Bt + ((size_t)bz * 1024 + t0) * K;

  f32x4 acc[3][4];
  f32x4 zz = {0.f, 0.f, 0.f, 0.f};
  #pragma unroll
  for (int m = 0; m < 3; ++m)
    #pragma unroll
    for (int n = 0; n < 4; ++n) acc[m][n] = zz;

  auto stage = [&](int kt, int buf) {
    char* dst = lds + buf * BUF;
    #pragma unroll
    for (int c = 0; c < 4; ++c) {
      int ch = c * 16 + wave;
      if (ch < 56) {
        int kof;
        const __hip_bfloat16* src;
        if (ch < 24) {
          int row = (ch >> 1) * 16 + r15;
          kof = kt * 64 + (ch & 1) * 32 + l4 * 8;
          src = Ab + (size_t)row * K + kof;
        } else {
          int cb = ch - 24;
          int row = (cb >> 1) * 16 + r15;
          kof = kt * 64 + (cb & 1) * 32 + l4 * 8;
          src = Bb + (size_t)row * K + kof;
        }
        async16(src, dst + ch * 1024 + lane * 16);
      }
    }
  };

  stage(0, 0);
  __syncthreads();                         // stage 0 landed (compiler vmcnt(0))
  for (int kt = 0; kt < 16; ++kt) {
    if (kt + 1 < 16) stage(kt + 1, (kt + 1) & 1);   // issue BEFORE compute
    char* cur = lds + (kt & 1) * BUF;
    #pragma unroll
    for (int kk = 0; kk < 2; ++kk) {
      bf16x8 af[3], bfr[4];
      #pragma unroll
      for (int m = 0; m < 3; ++m)
        af[m] = *reinterpret_cast<const bf16x8*>(cur + ((wm * 3 + m) * 2 + kk) * 1024 + lane * 16);
      #pragma unroll
      for (int n = 0; n < 4; ++n)
        bfr[n] = *reinterpret_cast<const bf16x8*>(cur + (24 + (wn * 4 + n) * 2 + kk) * 1024 + lane * 16);
      #pragma unroll
      for (int m = 0; m < 3; ++m)
        #pragma unroll
        for (int n = 0; n < 4; ++n)
          acc[m][n] = __builtin_amdgcn_mfma_f32_16x16x32_bf16(af[m], bfr[n], acc[m][n], 0, 0, 0);
    }
    __syncthreads();                       // drains stage(kt+1) after compute overlap
  }

  // epilogue: bf16 store (+bias); block covers exactly one GN group (192 rows)
  float* sred = reinterpret_cast<float*>(lds);   // 96 floats, buffer dead
  #pragma unroll
  for (int m = 0; m < 3; ++m) {
    float s = 0.f, ss2 = 0.f;
    #pragma unroll
    for (int n = 0; n < 4; ++n) {
      int ocol = t0 + (wn * 4 + n) * 16 + r15;
      #pragma unroll
      for (int r = 0; r < 4; ++r) {
        int orow = o0 + (wm * 3 + m) * 16 + l4 * 4 + r;
        float v = acc[m][n][r] + bias[orow];
        Cout[((size_t)bz * C3 + orow) * 1024 + ocol] = __float2bfloat16(v);
        s += v;
        ss2 += v * v;
      }
    }
    #pragma unroll
    for (int off = 1; off < 64; off <<= 1) {
      s   += __shfl_xor(s, off);
      ss2 += __shfl_xor(ss2, off);
    }
    if (lane == 0) {
      sred[(wave * 3 + m) * 2]     = s;
      sred[(wave * 3 + m) * 2 + 1] = ss2;
    }
  }
  __syncthreads();
  if (TID == 0) {
    float S = 0.f, SS = 0.f;
    #pragma unroll
    for (int slot = 0; slot < 48; ++slot) {
      S  += sred[slot * 2];
      SS += sred[slot * 2 + 1];
    }
    int g = bz * 8 + blockIdx.y;
    atomicAdd(&statraw[2 * g],     S);
    atomicAdd(&statraw[2 * g + 1], SS);
  }
}

// ---------------- shift-conv GEMM (conv K=4), ISSUE-AHEAD double buffer ----------------
__global__ __launch_bounds__(256) void gemm_c4(const __hip_bfloat16* __restrict__ A2,
    const __hip_bfloat16* __restrict__ aT, const float* __restrict__ bias,
    float* __restrict__ Cout, float* __restrict__ statraw) {
  constexpr int BUF = 42 * 1024;
  __shared__ __align__(16) char lds[2 * BUF];     // 84 KB (1 block/CU)
  int t0 = blockIdx.x * 128, o0 = blockIdx.y * 128, bz = blockIdx.z;
  int wave = TID >> 6, lane = TID & 63;
  int l4 = lane >> 4, r15 = lane & 15;
  int wm = wave >> 1, wn = wave & 1;
  const __hip_bfloat16* aTb = aT + (size_t)bz * 1056 * 512;

  f32x4 acc[4][4];
  f32x4 zz = {0.f, 0.f, 0.f, 0.f};
  #pragma unroll
  for (int m = 0; m < 4; ++m)
    #pragma unroll
    for (int n = 0; n < 4; ++n) acc[m][n] = zz;

  auto stage = [&](int kt, int buf) {
    char* dst = lds + buf * BUF;
    #pragma unroll
    for (int c = 0; c < 11; ++c) {
      int ch = c * 4 + wave;
      if (ch < 42) {
        const __hip_bfloat16* src;
        if (ch < 32) {
          int j = ch >> 3, rg = ch & 7;
          src = A2 + ((size_t)j * 512 + o0 + rg * 16 + r15) * 512 + kt * 32 + l4 * 8;
        } else {
          int rg = ch - 32;
          src = aTb + (size_t)(t0 + rg * 16 + r15) * 512 + kt * 32 + l4 * 8;
        }
        async16(src, dst + ch * 1024 + lane * 16);
      }
    }
  };

  stage(0, 0);
  __syncthreads();
  for (int kt = 0; kt < 16; ++kt) {
    if (kt + 1 < 16) stage(kt + 1, (kt + 1) & 1);
    char* cur = lds + (kt & 1) * BUF;
    #pragma unroll
    for (int j = 0; j < 4; ++j) {
      bf16x8 af[4], bfr[4];
      #pragma unroll
      for (int m = 0; m < 4; ++m)
        af[m] = *reinterpret_cast<const bf16x8*>(cur + (j * 8 + wm * 4 + m) * 1024 + lane * 16);
      #pragma unroll
      for (int n = 0; n < 4; ++n) {
        int q = (wn * 4 + n) * 16 + r15 + j + 15;
        bfr[n] = *reinterpret_cast<const bf16x8*>(cur + 32 * 1024 + (q >> 4) * 1024 + l4 * 256 + (q & 15) * 16);
      }
      #pragma unroll
      for (int m = 0; m < 4; ++m)
        #pragma unroll
        for (int n = 0; n < 4; ++n)
          acc[m][n] = __builtin_amdgcn_mfma_f32_16x16x32_bf16(af[m], bfr[n], acc[m][n], 0, 0, 0);
    }
    __syncthreads();
  }

  float* sred = reinterpret_cast<float*>(lds);
  #pragma unroll
  for (int m = 0; m < 4; ++m) {
    float s = 0.f, ss2 = 0.f;
    #pragma unroll
    for (int n = 0; n < 4; ++n) {
      int ocol = t0 + (wn * 4 + n) * 16 + r15;
      #pragma unroll
      for (int r = 0; r < 4; ++r) {
        int orow = o0 + (wm * 4 + m) * 16 + l4 * 4 + r;
        float v = acc[m][n][r] + bias[orow];
        Cout[((size_t)bz * Cc + orow) * 1024 + ocol] = v;
        s += v;
        ss2 += v * v;
      }
    }
    #pragma unroll
    for (int off = 1; off < 64; off <<= 1) {
      s   += __shfl_xor(s, off);
      ss2 += __shfl_xor(ss2, off);
    }
    if (lane == 0) {
      sred[(wave * 4 + m) * 2]     = s;
      sred[(wave * 4 + m) * 2 + 1] = ss2;
    }
  }
  __syncthreads();
  if (TID < 2) {
    int g0 = o0 >> 6;
    float S = 0.f, SS = 0.f;
    int cnt = 0;
    #pragma unroll
    for (int slot = 0; slot < 16; ++slot) {
      int rc = ((slot >> 3) << 2) + (slot & 3);
      int g = (o0 + rc * 16) >> 6;
      if (g == g0 + (int)TID) {
        S  += sred[slot * 2];
        SS += sred[slot * 2 + 1];
        ++cnt;
      }
    }
    if (cnt) {
      atomicAdd(&statraw[2 * (bz * 8 + g0 + TID)],     S);
      atomicAdd(&statraw[2 * (bz * 8 + g0 + TID) + 1], SS);
    }
  }
}

// ---------------- fused GN(8)+Mish + build attn input images (bf16 qkv input, raw stats) ----------------
__global__ __launch_bounds__(256) void gn2_prep(const __hip_bfloat16* __restrict__ qkv,
    const float* __restrict__ straw, const float* __restrict__ w, const float* __restrict__ bv,
    char* __restrict__ qTp, char* __restrict__ kimg, char* __restrict__ vimg) {
  __shared__ unsigned short hbf[192 * 66];
  int tl = blockIdx.x & 15, hb = blockIdx.x >> 4;
  int b = hb >> 3, hd = hb & 7;
  float rs = straw[2 * (b * 8 + hd)], rq = straw[2 * (b * 8 + hd) + 1];
  float mean = rs * (1.f / 196608.f);
  float rstd = rsqrtf(fmaxf(rq * (1.f / 196608.f) - mean * mean, 0.f) + 1e-5f);
  for (int task = TID; task < 768; task += 256) {
    int row = task >> 2, seg = task & 3;
    int ch = hd * 192 + row;
    float sw = w[ch] * rstd;
    float sb = bv[ch] - mean * sw;
    const uint4* src = reinterpret_cast<const uint4*>(
        qkv + ((size_t)(b * C3 + ch)) * 1024 + tl * 64 + seg * 16);
    uint4 u0 = src[0], u1 = src[1];
    unsigned int uu[8] = {u0.x, u0.y, u0.z, u0.w, u1.x, u1.y, u1.z, u1.w};
    unsigned int* dst = reinterpret_cast<unsigned int*>(&hbf[row * 66 + seg * 16]);
    #pragma unroll
    for (int j = 0; j < 8; ++j) {
      float a = mishf(bf2f((unsigned short)(uu[j] & 0xffff)) * sw + sb);
      float c = mishf(bf2f((unsigned short)(uu[j] >> 16)) * sw + sb);
      dst[j] = pack2bf(a, c);
    }
  }
  __syncthreads();
  size_t tileof = ((size_t)hb * 16 + tl) * 8192;
  {
    int t = TID & 63, sel = TID >> 6;
    int img = sel >> 1, half = sel & 1;
    char* obase = (img == 0 ? qTp : kimg) + tileof + (size_t)t * 128;
    #pragma unroll
    for (int cc = 0; cc < 4; ++cc) {
      int chunk = half * 4 + cc;
      uint4 u;
      unsigned int* up = reinterpret_cast<unsigned int*>(&u);
      #pragma unroll
      for (int j = 0; j < 4; ++j) {
        int c = chunk * 8 + j * 2;
        unsigned int lo = hbf[(img * 64 + c) * 66 + t];
        unsigned int hi = hbf[(img * 64 + c + 1) * 66 + t];
        up[j] = lo | (hi << 16);
      }
      int cpos = (img == 0) ? chunk : (chunk ^ (t & 7));
      *reinterpret_cast<uint4*>(obase + cpos * 16) = u;
    }
  }
  {
    int c = TID & 63, qtr = TID >> 6;
    const unsigned int* vrow = reinterpret_cast<const unsigned int*>(&hbf[(128 + c) * 66]);
    char* obase = vimg + tileof + (size_t)c * 128;
    #pragma unroll
    for (int k = 0; k < 2; ++k) {
      int chunk = qtr * 2 + k;
      uint4 u;
      unsigned int* up = reinterpret_cast<unsigned int*>(&u);
      #pragma unroll
      for (int j = 0; j < 4; ++j) up[j] = vrow[chunk * 4 + j];
      *reinterpret_cast<uint4*>(obase + (chunk ^ (c & 7)) * 16) = u;
    }
  }
}

// ---------------- MFMA flash attention v4: 1024 threads, 4 q-tiles/block (KV read 4x) ----------------
__global__ __launch_bounds__(1024) void attn_mfma4(const char* __restrict__ qTp,
    const char* __restrict__ kimg, const char* __restrict__ vimg,
    __hip_bfloat16* __restrict__ aT) {
  __shared__ __align__(16) char smem[65536];
  char* kbuf0 = smem;
  char* kbuf1 = smem + 8192;
  char* vbuf0 = smem + 16384;
  char* vbuf1 = smem + 24576;
  char* pp    = smem + 32768;  // 16 waves x 2KB
  char* ov    = smem;          // 32KB alias (dead K/V buffers)

  int hb = blockIdx.y;
  int b = hb >> 3, hd = hb & 7;
  int lane = TID & 63, wave = TID >> 6;
  int qt = wave >> 2, qw = wave & 3;
  int l4 = lane >> 4, r15 = lane & 15;
  size_t ibase = (size_t)hb * 16 * 8192;
  const char* ksrc = kimg + ibase;
  const char* vsrc = vimg + ibase;

  if (TID < 512) async16(ksrc + (size_t)TID * 16, kbuf0 + (size_t)TID * 16);
  else           async16(vsrc + (size_t)(TID - 512) * 16, vbuf0 + (size_t)(TID - 512) * 16);

  bf16x8 aq[2];
  int tg = qw * 16 + r15;
  const char* qrow = qTp + ibase + (size_t)(blockIdx.x * 4 + qt) * 8192 + (size_t)tg * 128;
  aq[0] = *reinterpret_cast<const bf16x8*>(qrow + l4 * 16);
  aq[1] = *reinterpret_cast<const bf16x8*>(qrow + 64 + l4 * 16);

  f32x4 osum[4];
  f32x4 zz = {0.f, 0.f, 0.f, 0.f};
  #pragma unroll
  for (int cf = 0; cf < 4; ++cf) osum[cf] = zz;
  float mrow[4] = {-1e30f, -1e30f, -1e30f, -1e30f};
  float lrow[4] = {0.f, 0.f, 0.f, 0.f};
  __syncthreads();

  for (int it = 0; it < 16; ++it) {
    char* kcur = (it & 1) ? kbuf1 : kbuf0;
    char* vcur = (it & 1) ? vbuf1 : vbuf0;
    if (it < 15) {
      char* knxt = (it & 1) ? kbuf0 : kbuf1;
      char* vnxt = (it & 1) ? vbuf0 : vbuf1;
      const char* kn = ksrc + (size_t)(it + 1) * 8192;
      const char* vn = vsrc + (size_t)(it + 1) * 8192;
      if (TID < 512) async16(kn + (size_t)TID * 16, knxt + (size_t)TID * 16);
      else           async16(vn + (size_t)(TID - 512) * 16, vnxt + (size_t)(TID - 512) * 16);
    }
    f32x4 sc[4];
    #pragma unroll
    for (int sf = 0; sf < 4; ++sf) sc[sf] = zz;
    #pragma unroll
    for (int sf = 0; sf < 4; ++sf) {
      int sr = sf * 16 + r15;
      #pragma unroll
      for (int kk = 0; kk < 2; ++kk) {
        bf16x8 bk = *reinterpret_cast<const bf16x8*>(kcur + sr * 128 + (((kk * 4 + l4) ^ (sr & 7)) << 4));
        sc[sf] = __builtin_amdgcn_mfma_f32_16x16x32_bf16(aq[kk], bk, sc[sf], 0, 0, 0);
      }
    }
    float tmax[4];
    #pragma unroll
    for (int r = 0; r < 4; ++r)
      tmax[r] = fmaxf(fmaxf(sc[0][r], sc[1][r]), fmaxf(sc[2][r], sc[3][r]));
    #pragma unroll
    for (int off = 1; off < 16; off <<= 1)
      #pragma unroll
      for (int r = 0; r < 4; ++r) tmax[r] = fmaxf(tmax[r], __shfl_xor(tmax[r], off));
    float alpha[4];
    #pragma unroll
    for (int r = 0; r < 4; ++r) {
      float mnew = fmaxf(mrow[r], tmax[r]);
      alpha[r] = __expf((mrow[r] - mnew) * 0.125f);
      mrow[r] = mnew;
      lrow[r] *= alpha[r];
    }
    #pragma unroll
    for (int cf = 0; cf < 4; ++cf)
      #pragma unroll
      for (int r = 0; r < 4; ++r) osum[cf][r] *= alpha[r];
    char* pw = pp + wave * 2048;
    float psum[4] = {0.f, 0.f, 0.f, 0.f};
    #pragma unroll
    for (int sf = 0; sf < 4; ++sf) {
      int s = sf * 16 + r15;
      #pragma unroll
      for (int r = 0; r < 4; ++r) {
        float p = __expf((sc[sf][r] - mrow[r]) * 0.125f);
        psum[r] += p;
        int tlc = l4 * 4 + r;
        *reinterpret_cast<__hip_bfloat16*>(pw + tlc * 128 + ((((s >> 3) ^ (tlc & 7)) << 4) | ((s & 7) * 2)))
            = __float2bfloat16(p);
      }
    }
    #pragma unroll
    for (int r = 0; r < 4; ++r) lrow[r] += psum[r];
    asm volatile("s_waitcnt lgkmcnt(0)" ::: "memory");
    __builtin_amdgcn_sched_barrier(0);

    bf16x8 pa[2];
    #pragma unroll
    for (int kk = 0; kk < 2; ++kk)
      pa[kk] = *reinterpret_cast<const bf16x8*>(pw + r15 * 128 + (((kk * 4 + l4) ^ (r15 & 7)) << 4));
    #pragma unroll
    for (int cf = 0; cf < 4; ++cf) {
      int cr = cf * 16 + r15;
      #pragma unroll
      for (int kk = 0; kk < 2; ++kk) {
        bf16x8 bv = *reinterpret_cast<const bf16x8*>(vcur + cr * 128 + (((kk * 4 + l4) ^ (cr & 7)) << 4));
        osum[cf] = __builtin_amdgcn_mfma_f32_16x16x32_bf16(pa[kk], bv, osum[cf], 0, 0, 0);
      }
    }
    __syncthreads();
  }

  #pragma unroll
  for (int off = 1; off < 16; off <<= 1)
    #pragma unroll
    for (int r = 0; r < 4; ++r) lrow[r] += __shfl_xor(lrow[r], off);
  float linv[4];
  #pragma unroll
  for (int r = 0; r < 4; ++r) linv[r] = 1.f / lrow[r];

  // ov[t][c] bf16, t in [0,256), swizzled 128B rows
  #pragma unroll
  for (int cf = 0; cf < 4; ++cf) {
    int c = cf * 16 + r15;
    #pragma unroll
    for (int r = 0; r < 4; ++r) {
      int t = qt * 64 + qw * 16 + l4 * 4 + r;
      *reinterpret_cast<__hip_bfloat16*>(ov + t * 128 + ((((c >> 3) ^ (t & 7)) << 4) | ((c & 7) * 2)))
          = __float2bfloat16(osum[cf][r] * linv[r]);
    }
  }
  __syncthreads();
  __hip_bfloat16* ap = aT + ((size_t)b * 1056 + 16 + blockIdx.x * 256) * 512 + hd * 64;
  for (int u = TID; u < 2048; u += 1024) {
    int t = u >> 3, cj = u & 7;
    uint4 o4 = *reinterpret_cast<const uint4*>(ov + t * 128 + ((cj ^ (t & 7)) << 4));
    *reinterpret_cast<uint4*>(ap + (size_t)t * 512 + cj * 8) = o4;
  }
}

// ---------------- final: out = x + mish(gn(y2)) in-place on d_out (raw stats) ----------------
__global__ __launch_bounds__(256) void final_kernel(const float* __restrict__ x,
    float* __restrict__ y, const float* __restrict__ straw,
    const float* __restrict__ w, const float* __restrict__ bv) {
  size_t i = ((size_t)blockIdx.x * 256 + TID) * 4;
  int ch = (int)((i >> 10) & (Cc - 1));
  int b = (int)(i >> 19);
  int g = b * 8 + (ch >> 6);
  float rs = straw[2 * g], rq = straw[2 * g + 1];
  float mean = rs * (1.f / 65536.f);
  float rstd = rsqrtf(fmaxf(rq * (1.f / 65536.f) - mean * mean, 0.f) + 1e-5f);
  float sw = w[ch] * rstd;
  float sb = bv[ch] - mean * sw;
  float4 v  = *reinterpret_cast<const float4*>(y + i);
  float4 xv = *reinterpret_cast<const float4*>(x + i);
  v.x = xv.x + mishf(v.x * sw + sb);
  v.y = xv.y + mishf(v.y * sw + sb);
  v.z = xv.z + mishf(v.z * sw + sb);
  v.w = xv.w + mishf(v.w * sw + sb);
  *reinterpret_cast<float4*>(y + i) = v;
}

extern "C" void kernel_launch(void* const* d_in, const int* in_sizes, int n_in,
                              void* d_out, int out_size, void* d_ws, size_t ws_size,
                              hipStream_t stream) {
  const float* x     = (const float*)d_in[0];
  const float* gn_w  = (const float*)d_in[1];
  const float* gn_b  = (const float*)d_in[2];
  const float* wqkv  = (const float*)d_in[3];
  const float* bqkv  = (const float*)d_in[4];
  const float* gnq_w = (const float*)d_in[5];
  const float* gnq_b = (const float*)d_in[6];
  const float* wproj = (const float*)d_in[7];
  const float* bproj = (const float*)d_in[8];
  const float* gnp_w = (const float*)d_in[9];
  const float* gnp_b = (const float*)d_in[10];
  float* out = (float*)d_out;

  char* ws = (char*)d_ws;
  const size_t MB = 1024 * 1024;
  __hip_bfloat16* qkvb = (__hip_bfloat16*)ws;            // [0,24MB)   step5 -> step6
  __hip_bfloat16* aT   = (__hip_bfloat16*)(ws + 24 * MB);// [24,33MB)  step2/7 -> step9
  __hip_bfloat16* A1   = (__hip_bfloat16*)(ws + 56 * MB);// [56,59MB)  step3 -> step5
  char* vimg = ws + 56 * MB;                             // [56,64MB)  step6 -> step7 (A1 dead)
  __hip_bfloat16* A2   = (__hip_bfloat16*)(ws + 56 * MB);// [56,58MB)  step8 -> step9 (vimg dead)
  float* st2raw = (float*)(ws + 64 * MB);
  float* st3raw = st2raw + 128;
  __hip_bfloat16* B1t = (__hip_bfloat16*)d_out;          // d_out as B1t  step4 -> step5
  char* qTp  = (char*)d_out;                             // d_out[0,8MB)  step6 -> step7
  char* kimg = (char*)d_out + 8 * MB;                    // d_out[8,16MB) step6 -> step7

  dim3 blk(256);
  zero_stats<<<1, blk, 0, stream>>>(st2raw);                                        // 1
  zero_pads<<<64, blk, 0, stream>>>(aT);                                            // 2
  cast_bf16<<<1536, blk, 0, stream>>>(wqkv, A1, C3 * 1024);                         // 3
  gn1_im2col<<<256, blk, 0, stream>>>(x, gn_w, gn_b, B1t);                          // 4
  gemm_bt10<<<dim3(4, 8, 8), dim3(1024), 0, stream>>>(A1, B1t, bqkv, qkvb, st2raw); // 5
  gn2_prep<<<1024, blk, 0, stream>>>(qkvb, st2raw, gnq_w, gnq_b, qTp, kimg, vimg);  // 6
  attn_mfma4<<<dim3(4, 64), dim3(1024), 0, stream>>>(qTp, kimg, vimg, aT);          // 7
  cast_wproj<<<512, blk, 0, stream>>>(wproj, A2);                                   // 8
  gemm_c4<<<dim3(8, 4, 8), blk, 0, stream>>>(A2, aT, bproj, out, st3raw);           // 9
  final_kernel<<<4096, blk, 0, stream>>>(x, out, st3raw, gnp_w, gnp_b);             // 10
}

// Round 16
// 167.471 us; speedup vs baseline: 2.0821x; 1.0058x over previous
//
#include <hip/hip_runtime.h>
#include <hip/hip_bf16.h>
#include <math.h>

#define TID threadIdx.x

constexpr int Cc = 512, Tt = 1024, C3 = 1536;

typedef __attribute__((ext_vector_type(8))) __bf16 bf16x8;
typedef __attribute__((ext_vector_type(4))) float f32x4;

__device__ __forceinline__ void async16(const void* g, void* l) {
  __builtin_amdgcn_global_load_lds(
      (const __attribute__((address_space(1))) unsigned int*)g,
      (__attribute__((address_space(3))) unsigned int*)l, 16, 0, 0);
}

__device__ __forceinline__ unsigned int pack2bf(float a, float b) {
  __hip_bfloat162 h;
  h.x = __float2bfloat16(a);
  h.y = __float2bfloat16(b);
  return *reinterpret_cast<unsigned int*>(&h);
}

__device__ __forceinline__ float bf2f(unsigned short u) {
  unsigned int t = ((unsigned int)u) << 16;
  union { unsigned int i; float f; } c;
  c.i = t;
  return c.f;
}

// hardware 2^x (v_exp_f32: D = 2^S0)
__device__ __forceinline__ float exp2_hw(float x) {
  float r;
  asm("v_exp_f32 %0, %1" : "=v"(r) : "v"(x));
  return r;
}

// mish(x) = x * n/(n+2), n = u*(u+2), u = e^x  (one hw exp + one rcp)
__device__ __forceinline__ float mishf(float x) {
  float u = __expf(x);
  float n = u * (u + 2.f);
  float r = x * n * __builtin_amdgcn_rcpf(n + 2.f);
  return (x > 20.f) ? x : r;
}

__device__ __forceinline__ void blockReduce2(float& s, float& ss) {
  #pragma unroll
  for (int off = 32; off > 0; off >>= 1) {
    s  += __shfl_xor(s,  off);
    ss += __shfl_xor(ss, off);
  }
  __shared__ float ls[4], lss[4];
  int w = TID >> 6;
  if ((TID & 63) == 0) { ls[w] = s; lss[w] = ss; }
  __syncthreads();
  s  = ls[0] + ls[1] + ls[2] + ls[3];
  ss = lss[0] + lss[1] + lss[2] + lss[3];
}

// ---------------- zero the raw-stat accumulators (256 floats) ----------------
__global__ void zero_stats(float* p) { p[TID] = 0.f; }

// ---------------- zero the 16-row halo pads of aT[8][1056][512] ----------------
__global__ __launch_bounds__(256) void zero_pads(__hip_bfloat16* __restrict__ aT) {
  int idx = blockIdx.x * 256 + TID;
  int bb = idx >> 11;
  int task = idx & 2047;
  int prow = task >> 6;
  int col = (task & 63) * 8;
  int P = (prow < 16) ? prow : (1024 + prow);
  uint4 z = {0u, 0u, 0u, 0u};
  *reinterpret_cast<uint4*>(aT + ((size_t)bb * 1056 + P) * 512 + col) = z;
}

// ---------------- fused GN(32) + im2col(K=2, pad_lo=0) -> bf16 B1t[b][t][k=2ci+j] ----------------
__global__ __launch_bounds__(256) void gn1_im2col(const float* __restrict__ x,
    const float* __restrict__ w, const float* __restrict__ bv,
    __hip_bfloat16* __restrict__ B1t) {
  __shared__ float hs[16][262];
  int blk = blockIdx.x, bb = blk >> 5, g = blk & 31;
  size_t base = ((size_t)bb * Cc + g * 16) * Tt;
  const float* xp = x + base;
  float s = 0.f, ss = 0.f;
  for (int i = TID * 4; i < 16 * Tt; i += 1024) {
    float4 v = *reinterpret_cast<const float4*>(xp + i);
    s  += v.x + v.y + v.z + v.w;
    ss += v.x * v.x + v.y * v.y + v.z * v.z + v.w * v.w;
  }
  blockReduce2(s, ss);
  float mean = s * (1.f / 16384.f);
  float rstd = rsqrtf(ss * (1.f / 16384.f) - mean * mean + 1e-5f);

  char* ob = reinterpret_cast<char*>(B1t + (size_t)bb * Tt * 1024 + g * 32);
  for (int tc = 0; tc < 4; ++tc) {
    int tbase = tc * 256;
    __syncthreads();
    for (int task = TID; task < 1024; task += 256) {
      int row = task >> 6, c4 = task & 63;
      int ch = g * 16 + row;
      float sw = w[ch] * rstd;
      float sb = bv[ch] - mean * sw;
      float4 v = *reinterpret_cast<const float4*>(xp + (size_t)row * Tt + tbase + c4 * 4);
      hs[row][c4 * 4 + 0] = v.x * sw + sb;
      hs[row][c4 * 4 + 1] = v.y * sw + sb;
      hs[row][c4 * 4 + 2] = v.z * sw + sb;
      hs[row][c4 * 4 + 3] = v.w * sw + sb;
    }
    if (TID < 16) {
      int row = TID, t = tbase + 256;
      float val = 0.f;
      if (t < Tt) {
        int ch = g * 16 + row;
        float sw = w[ch] * rstd;
        float sb = bv[ch] - mean * sw;
        val = xp[(size_t)row * Tt + t] * sw + sb;
      }
      hs[row][256] = val;
    }
    __syncthreads();
    for (int task = TID; task < 1024; task += 256) {
      int t = task >> 2, cj = task & 3;
      int ci = cj * 4;
      uint4 u;
      u.x = pack2bf(hs[ci + 0][t], hs[ci + 0][t + 1]);
      u.y = pack2bf(hs[ci + 1][t], hs[ci + 1][t + 1]);
      u.z = pack2bf(hs[ci + 2][t], hs[ci + 2][t + 1]);
      u.w = pack2bf(hs[ci + 3][t], hs[ci + 3][t + 1]);
      *reinterpret_cast<uint4*>(ob + ((size_t)(tbase + t) * 1024 + cj * 8) * 2) = u;
    }
  }
}

// ---------------- f32 -> bf16 cast (weights) ----------------
__global__ __launch_bounds__(256) void cast_bf16(const float* __restrict__ in,
    __hip_bfloat16* __restrict__ out, int n) {
  int i = (blockIdx.x * 256 + TID) * 4;
  if (i >= n) return;
  float4 v = *reinterpret_cast<const float4*>(in + i);
  *reinterpret_cast<unsigned int*>(out + i)     = pack2bf(v.x, v.y);
  *reinterpret_cast<unsigned int*>(out + i + 2) = pack2bf(v.z, v.w);
}

// ---------------- wproj [o][ci][4] f32 -> A2[j][o][ci] bf16 ----------------
__global__ __launch_bounds__(256) void cast_wproj(const float* __restrict__ wp,
    __hip_bfloat16* __restrict__ A2) {
  int o = blockIdx.x;
  int ci = TID * 2;
  float4 v0 = *reinterpret_cast<const float4*>(wp + ((size_t)o * 512 + ci) * 4);
  float4 v1 = *reinterpret_cast<const float4*>(wp + ((size_t)o * 512 + ci + 1) * 4);
  const float* a0 = &v0.x;
  const float* a1 = &v1.x;
  #pragma unroll
  for (int j = 0; j < 4; ++j) {
    unsigned int u = pack2bf(a0[j], a1[j]);
    *reinterpret_cast<unsigned int*>(A2 + ((size_t)j * 512 + o) * 512 + ci) = u;
  }
}

// ---------------- bf16 MFMA GEMM v10: BM=192 x BN=256, 1024 thr, ISSUE-AHEAD double buffer ----
__global__ __launch_bounds__(1024, 4) void gemm_bt10(const __hip_bfloat16* __restrict__ A,
    const __hip_bfloat16* __restrict__ Bt, const float* __restrict__ bias,
    __hip_bfloat16* __restrict__ Cout, float* __restrict__ statraw) {
  constexpr int K = 1024;
  constexpr int BUF = 56 * 1024;
  __shared__ __align__(16) char lds[2 * BUF];
  int t0 = blockIdx.x * 256, o0 = blockIdx.y * 192, bz = blockIdx.z;
  int wave = TID >> 6, lane = TID & 63;
  int l4 = lane >> 4, r15 = lane & 15;
  int wm = wave >> 2, wn = wave & 3;
  const __hip_bfloat16* Ab = A + (size_t)o0 * K;
  const __hip_bfloat16* Bb = Bt + ((size_t)bz * 1024 + t0) * K;

  f32x4 acc[3][4];
  f32x4 zz = {0.f, 0.f, 0.f, 0.f};
  #pragma unroll
  for (int m = 0; m < 3; ++m)
    #pragma unroll
    for (int n = 0; n < 4; ++n) acc[m][n] = zz;

  auto stage = [&](int kt, int buf) {
    char* dst = lds + buf * BUF;
    #pragma unroll
    for (int c = 0; c < 4; ++c) {
      int ch = c * 16 + wave;
      if (ch < 56) {
        int kof;
        const __hip_bfloat16* src;
        if (ch < 24) {
          int row = (ch >> 1) * 16 + r15;
          kof = kt * 64 + (ch & 1) * 32 + l4 * 8;
          src = Ab + (size_t)row * K + kof;
        } else {
          int cb = ch - 24;
          int row = (cb >> 1) * 16 + r15;
          kof = kt * 64 + (cb & 1) * 32 + l4 * 8;
          src = Bb + (size_t)row * K + kof;
        }
        async16(src, dst + ch * 1024 + lane * 16);
      }
    }
  };

  stage(0, 0);
  __syncthreads();
  for (int kt = 0; kt < 16; ++kt) {
    if (kt + 1 < 16) stage(kt + 1, (kt + 1) & 1);
    char* cur = lds + (kt & 1) * BUF;
    #pragma unroll
    for (int kk = 0; kk < 2; ++kk) {
      bf16x8 af[3], bfr[4];
      #pragma unroll
      for (int m = 0; m < 3; ++m)
        af[m] = *reinterpret_cast<const bf16x8*>(cur + ((wm * 3 + m) * 2 + kk) * 1024 + lane * 16);
      #pragma unroll
      for (int n = 0; n < 4; ++n)
        bfr[n] = *reinterpret_cast<const bf16x8*>(cur + (24 + (wn * 4 + n) * 2 + kk) * 1024 + lane * 16);
      #pragma unroll
      for (int m = 0; m < 3; ++m)
        #pragma unroll
        for (int n = 0; n < 4; ++n)
          acc[m][n] = __builtin_amdgcn_mfma_f32_16x16x32_bf16(af[m], bfr[n], acc[m][n], 0, 0, 0);
    }
    __syncthreads();
  }

  float* sred = reinterpret_cast<float*>(lds);
  #pragma unroll
  for (int m = 0; m < 3; ++m) {
    float s = 0.f, ss2 = 0.f;
    #pragma unroll
    for (int n = 0; n < 4; ++n) {
      int ocol = t0 + (wn * 4 + n) * 16 + r15;
      #pragma unroll
      for (int r = 0; r < 4; ++r) {
        int orow = o0 + (wm * 3 + m) * 16 + l4 * 4 + r;
        float v = acc[m][n][r] + bias[orow];
        Cout[((size_t)bz * C3 + orow) * 1024 + ocol] = __float2bfloat16(v);
        s += v;
        ss2 += v * v;
      }
    }
    #pragma unroll
    for (int off = 1; off < 64; off <<= 1) {
      s   += __shfl_xor(s, off);
      ss2 += __shfl_xor(ss2, off);
    }
    if (lane == 0) {
      sred[(wave * 3 + m) * 2]     = s;
      sred[(wave * 3 + m) * 2 + 1] = ss2;
    }
  }
  __syncthreads();
  if (TID == 0) {
    float S = 0.f, SS = 0.f;
    #pragma unroll
    for (int slot = 0; slot < 48; ++slot) {
      S  += sred[slot * 2];
      SS += sred[slot * 2 + 1];
    }
    int g = bz * 8 + blockIdx.y;
    atomicAdd(&statraw[2 * g],     S);
    atomicAdd(&statraw[2 * g + 1], SS);
  }
}

// ---------------- shift-conv GEMM (conv K=4), ISSUE-AHEAD double buffer ----------------
__global__ __launch_bounds__(256) void gemm_c4(const __hip_bfloat16* __restrict__ A2,
    const __hip_bfloat16* __restrict__ aT, const float* __restrict__ bias,
    float* __restrict__ Cout, float* __restrict__ statraw) {
  constexpr int BUF = 42 * 1024;
  __shared__ __align__(16) char lds[2 * BUF];
  int t0 = blockIdx.x * 128, o0 = blockIdx.y * 128, bz = blockIdx.z;
  int wave = TID >> 6, lane = TID & 63;
  int l4 = lane >> 4, r15 = lane & 15;
  int wm = wave >> 1, wn = wave & 1;
  const __hip_bfloat16* aTb = aT + (size_t)bz * 1056 * 512;

  f32x4 acc[4][4];
  f32x4 zz = {0.f, 0.f, 0.f, 0.f};
  #pragma unroll
  for (int m = 0; m < 4; ++m)
    #pragma unroll
    for (int n = 0; n < 4; ++n) acc[m][n] = zz;

  auto stage = [&](int kt, int buf) {
    char* dst = lds + buf * BUF;
    #pragma unroll
    for (int c = 0; c < 11; ++c) {
      int ch = c * 4 + wave;
      if (ch < 42) {
        const __hip_bfloat16* src;
        if (ch < 32) {
          int j = ch >> 3, rg = ch & 7;
          src = A2 + ((size_t)j * 512 + o0 + rg * 16 + r15) * 512 + kt * 32 + l4 * 8;
        } else {
          int rg = ch - 32;
          src = aTb + (size_t)(t0 + rg * 16 + r15) * 512 + kt * 32 + l4 * 8;
        }
        async16(src, dst + ch * 1024 + lane * 16);
      }
    }
  };

  stage(0, 0);
  __syncthreads();
  for (int kt = 0; kt < 16; ++kt) {
    if (kt + 1 < 16) stage(kt + 1, (kt + 1) & 1);
    char* cur = lds + (kt & 1) * BUF;
    #pragma unroll
    for (int j = 0; j < 4; ++j) {
      bf16x8 af[4], bfr[4];
      #pragma unroll
      for (int m = 0; m < 4; ++m)
        af[m] = *reinterpret_cast<const bf16x8*>(cur + (j * 8 + wm * 4 + m) * 1024 + lane * 16);
      #pragma unroll
      for (int n = 0; n < 4; ++n) {
        int q = (wn * 4 + n) * 16 + r15 + j + 15;
        bfr[n] = *reinterpret_cast<const bf16x8*>(cur + 32 * 1024 + (q >> 4) * 1024 + l4 * 256 + (q & 15) * 16);
      }
      #pragma unroll
      for (int m = 0; m < 4; ++m)
        #pragma unroll
        for (int n = 0; n < 4; ++n)
          acc[m][n] = __builtin_amdgcn_mfma_f32_16x16x32_bf16(af[m], bfr[n], acc[m][n], 0, 0, 0);
    }
    __syncthreads();
  }

  float* sred = reinterpret_cast<float*>(lds);
  #pragma unroll
  for (int m = 0; m < 4; ++m) {
    float s = 0.f, ss2 = 0.f;
    #pragma unroll
    for (int n = 0; n < 4; ++n) {
      int ocol = t0 + (wn * 4 + n) * 16 + r15;
      #pragma unroll
      for (int r = 0; r < 4; ++r) {
        int orow = o0 + (wm * 4 + m) * 16 + l4 * 4 + r;
        float v = acc[m][n][r] + bias[orow];
        Cout[((size_t)bz * Cc + orow) * 1024 + ocol] = v;
        s += v;
        ss2 += v * v;
      }
    }
    #pragma unroll
    for (int off = 1; off < 64; off <<= 1) {
      s   += __shfl_xor(s, off);
      ss2 += __shfl_xor(ss2, off);
    }
    if (lane == 0) {
      sred[(wave * 4 + m) * 2]     = s;
      sred[(wave * 4 + m) * 2 + 1] = ss2;
    }
  }
  __syncthreads();
  if (TID < 2) {
    int g0 = o0 >> 6;
    float S = 0.f, SS = 0.f;
    int cnt = 0;
    #pragma unroll
    for (int slot = 0; slot < 16; ++slot) {
      int rc = ((slot >> 3) << 2) + (slot & 3);
      int g = (o0 + rc * 16) >> 6;
      if (g == g0 + (int)TID) {
        S  += sred[slot * 2];
        SS += sred[slot * 2 + 1];
        ++cnt;
      }
    }
    if (cnt) {
      atomicAdd(&statraw[2 * (bz * 8 + g0 + TID)],     S);
      atomicAdd(&statraw[2 * (bz * 8 + g0 + TID) + 1], SS);
    }
  }
}

// ---------------- fused GN(8)+Mish + build attn input images (bf16 qkv input, raw stats) ----------------
__global__ __launch_bounds__(256) void gn2_prep(const __hip_bfloat16* __restrict__ qkv,
    const float* __restrict__ straw, const float* __restrict__ w, const float* __restrict__ bv,
    char* __restrict__ qTp, char* __restrict__ kimg, char* __restrict__ vimg) {
  __shared__ unsigned short hbf[192 * 66];
  int tl = blockIdx.x & 15, hb = blockIdx.x >> 4;
  int b = hb >> 3, hd = hb & 7;
  float rs = straw[2 * (b * 8 + hd)], rq = straw[2 * (b * 8 + hd) + 1];
  float mean = rs * (1.f / 196608.f);
  float rstd = rsqrtf(fmaxf(rq * (1.f / 196608.f) - mean * mean, 0.f) + 1e-5f);
  for (int task = TID; task < 768; task += 256) {
    int row = task >> 2, seg = task & 3;
    int ch = hd * 192 + row;
    float sw = w[ch] * rstd;
    float sb = bv[ch] - mean * sw;
    const uint4* src = reinterpret_cast<const uint4*>(
        qkv + ((size_t)(b * C3 + ch)) * 1024 + tl * 64 + seg * 16);
    uint4 u0 = src[0], u1 = src[1];
    unsigned int uu[8] = {u0.x, u0.y, u0.z, u0.w, u1.x, u1.y, u1.z, u1.w};
    unsigned int* dst = reinterpret_cast<unsigned int*>(&hbf[row * 66 + seg * 16]);
    #pragma unroll
    for (int j = 0; j < 8; ++j) {
      float a = mishf(bf2f((unsigned short)(uu[j] & 0xffff)) * sw + sb);
      float c = mishf(bf2f((unsigned short)(uu[j] >> 16)) * sw + sb);
      dst[j] = pack2bf(a, c);
    }
  }
  __syncthreads();
  size_t tileof = ((size_t)hb * 16 + tl) * 8192;
  {
    int t = TID & 63, sel = TID >> 6;
    int img = sel >> 1, half = sel & 1;
    char* obase = (img == 0 ? qTp : kimg) + tileof + (size_t)t * 128;
    #pragma unroll
    for (int cc = 0; cc < 4; ++cc) {
      int chunk = half * 4 + cc;
      uint4 u;
      unsigned int* up = reinterpret_cast<unsigned int*>(&u);
      #pragma unroll
      for (int j = 0; j < 4; ++j) {
        int c = chunk * 8 + j * 2;
        unsigned int lo = hbf[(img * 64 + c) * 66 + t];
        unsigned int hi = hbf[(img * 64 + c + 1) * 66 + t];
        up[j] = lo | (hi << 16);
      }
      int cpos = (img == 0) ? chunk : (chunk ^ (t & 7));
      *reinterpret_cast<uint4*>(obase + cpos * 16) = u;
    }
  }
  {
    int c = TID & 63, qtr = TID >> 6;
    const unsigned int* vrow = reinterpret_cast<const unsigned int*>(&hbf[(128 + c) * 66]);
    char* obase = vimg + tileof + (size_t)c * 128;
    #pragma unroll
    for (int k = 0; k < 2; ++k) {
      int chunk = qtr * 2 + k;
      uint4 u;
      unsigned int* up = reinterpret_cast<unsigned int*>(&u);
      #pragma unroll
      for (int j = 0; j < 4; ++j) up[j] = vrow[chunk * 4 + j];
      *reinterpret_cast<uint4*>(obase + (chunk ^ (c & 7)) * 16) = u;
    }
  }
}

// ---------------- MFMA flash attention v5: exp2-direct + defer-max ----------------
// Q fragments pre-scaled by 0.125*log2(e): scores are already in the exp2 domain.
__global__ __launch_bounds__(1024) void attn_mfma5(const char* __restrict__ qTp,
    const char* __restrict__ kimg, const char* __restrict__ vimg,
    __hip_bfloat16* __restrict__ aT) {
  __shared__ __align__(16) char smem[65536];
  char* kbuf0 = smem;
  char* kbuf1 = smem + 8192;
  char* vbuf0 = smem + 16384;
  char* vbuf1 = smem + 24576;
  char* pp    = smem + 32768;  // 16 waves x 2KB
  char* ov    = smem;          // 32KB alias (dead K/V buffers)

  int hb = blockIdx.y;
  int b = hb >> 3, hd = hb & 7;
  int lane = TID & 63, wave = TID >> 6;
  int qt = wave >> 2, qw = wave & 3;
  int l4 = lane >> 4, r15 = lane & 15;
  size_t ibase = (size_t)hb * 16 * 8192;
  const char* ksrc = kimg + ibase;
  const char* vsrc = vimg + ibase;

  if (TID < 512) async16(ksrc + (size_t)TID * 16, kbuf0 + (size_t)TID * 16);
  else           async16(vsrc + (size_t)(TID - 512) * 16, vbuf0 + (size_t)(TID - 512) * 16);

  bf16x8 aq[2];
  int tg = qw * 16 + r15;
  const char* qrow = qTp + ibase + (size_t)(blockIdx.x * 4 + qt) * 8192 + (size_t)tg * 128;
  aq[0] = *reinterpret_cast<const bf16x8*>(qrow + l4 * 16);
  aq[1] = *reinterpret_cast<const bf16x8*>(qrow + 64 + l4 * 16);
  // pre-scale Q by 0.125*log2(e) so scores live in the exp2 domain (once per block)
  {
    const float SC = 0.125f * 1.44269504f;
    #pragma unroll
    for (int kk = 0; kk < 2; ++kk) {
      unsigned int* u = reinterpret_cast<unsigned int*>(&aq[kk]);
      #pragma unroll
      for (int j = 0; j < 4; ++j) {
        float lo = bf2f((unsigned short)(u[j] & 0xffff)) * SC;
        float hi = bf2f((unsigned short)(u[j] >> 16)) * SC;
        u[j] = pack2bf(lo, hi);
      }
    }
  }

  f32x4 osum[4];
  f32x4 zz = {0.f, 0.f, 0.f, 0.f};
  #pragma unroll
  for (int cf = 0; cf < 4; ++cf) osum[cf] = zz;
  float mrow[4] = {-1e30f, -1e30f, -1e30f, -1e30f};
  float lrow[4] = {0.f, 0.f, 0.f, 0.f};
  __syncthreads();

  for (int it = 0; it < 16; ++it) {
    char* kcur = (it & 1) ? kbuf1 : kbuf0;
    char* vcur = (it & 1) ? vbuf1 : vbuf0;
    if (it < 15) {
      char* knxt = (it & 1) ? kbuf0 : kbuf1;
      char* vnxt = (it & 1) ? vbuf0 : vbuf1;
      const char* kn = ksrc + (size_t)(it + 1) * 8192;
      const char* vn = vsrc + (size_t)(it + 1) * 8192;
      if (TID < 512) async16(kn + (size_t)TID * 16, knxt + (size_t)TID * 16);
      else           async16(vn + (size_t)(TID - 512) * 16, vnxt + (size_t)(TID - 512) * 16);
    }
    f32x4 sc[4];
    #pragma unroll
    for (int sf = 0; sf < 4; ++sf) sc[sf] = zz;
    #pragma unroll
    for (int sf = 0; sf < 4; ++sf) {
      int sr = sf * 16 + r15;
      #pragma unroll
      for (int kk = 0; kk < 2; ++kk) {
        bf16x8 bk = *reinterpret_cast<const bf16x8*>(kcur + sr * 128 + (((kk * 4 + l4) ^ (sr & 7)) << 4));
        sc[sf] = __builtin_amdgcn_mfma_f32_16x16x32_bf16(aq[kk], bk, sc[sf], 0, 0, 0);
      }
    }
    float tmax[4];
    #pragma unroll
    for (int r = 0; r < 4; ++r)
      tmax[r] = fmaxf(fmaxf(sc[0][r], sc[1][r]), fmaxf(sc[2][r], sc[3][r]));
    #pragma unroll
    for (int off = 1; off < 16; off <<= 1)
      #pragma unroll
      for (int r = 0; r < 4; ++r) tmax[r] = fmaxf(tmax[r], __shfl_xor(tmax[r], off));
    // defer-max: only rescale when the running max actually grows
    bool grow = (tmax[0] > mrow[0]) | (tmax[1] > mrow[1]) |
                (tmax[2] > mrow[2]) | (tmax[3] > mrow[3]);
    if (grow) {
      float alpha[4];
      #pragma unroll
      for (int r = 0; r < 4; ++r) {
        float mnew = fmaxf(mrow[r], tmax[r]);
        alpha[r] = exp2_hw(mrow[r] - mnew);
        mrow[r] = mnew;
        lrow[r] *= alpha[r];
      }
      #pragma unroll
      for (int cf = 0; cf < 4; ++cf)
        #pragma unroll
        for (int r = 0; r < 4; ++r) osum[cf][r] *= alpha[r];
    }
    char* pw = pp + wave * 2048;
    float psum[4] = {0.f, 0.f, 0.f, 0.f};
    #pragma unroll
    for (int sf = 0; sf < 4; ++sf) {
      int s = sf * 16 + r15;
      #pragma unroll
      for (int r = 0; r < 4; ++r) {
        float p = exp2_hw(sc[sf][r] - mrow[r]);
        psum[r] += p;
        int tlc = l4 * 4 + r;
        *reinterpret_cast<__hip_bfloat16*>(pw + tlc * 128 + ((((s >> 3) ^ (tlc & 7)) << 4) | ((s & 7) * 2)))
            = __float2bfloat16(p);
      }
    }
    #pragma unroll
    for (int r = 0; r < 4; ++r) lrow[r] += psum[r];
    asm volatile("s_waitcnt lgkmcnt(0)" ::: "memory");
    __builtin_amdgcn_sched_barrier(0);

    bf16x8 pa[2];
    #pragma unroll
    for (int kk = 0; kk < 2; ++kk)
      pa[kk] = *reinterpret_cast<const bf16x8*>(pw + r15 * 128 + (((kk * 4 + l4) ^ (r15 & 7)) << 4));
    #pragma unroll
    for (int cf = 0; cf < 4; ++cf) {
      int cr = cf * 16 + r15;
      #pragma unroll
      for (int kk = 0; kk < 2; ++kk) {
        bf16x8 bv = *reinterpret_cast<const bf16x8*>(vcur + cr * 128 + (((kk * 4 + l4) ^ (cr & 7)) << 4));
        osum[cf] = __builtin_amdgcn_mfma_f32_16x16x32_bf16(pa[kk], bv, osum[cf], 0, 0, 0);
      }
    }
    __syncthreads();
  }

  #pragma unroll
  for (int off = 1; off < 16; off <<= 1)
    #pragma unroll
    for (int r = 0; r < 4; ++r) lrow[r] += __shfl_xor(lrow[r], off);
  float linv[4];
  #pragma unroll
  for (int r = 0; r < 4; ++r) linv[r] = 1.f / lrow[r];

  // ov[t][c] bf16, t in [0,256), swizzled 128B rows
  #pragma unroll
  for (int cf = 0; cf < 4; ++cf) {
    int c = cf * 16 + r15;
    #pragma unroll
    for (int r = 0; r < 4; ++r) {
      int t = qt * 64 + qw * 16 + l4 * 4 + r;
      *reinterpret_cast<__hip_bfloat16*>(ov + t * 128 + ((((c >> 3) ^ (t & 7)) << 4) | ((c & 7) * 2)))
          = __float2bfloat16(osum[cf][r] * linv[r]);
    }
  }
  __syncthreads();
  __hip_bfloat16* ap = aT + ((size_t)b * 1056 + 16 + blockIdx.x * 256) * 512 + hd * 64;
  for (int u = TID; u < 2048; u += 1024) {
    int t = u >> 3, cj = u & 7;
    uint4 o4 = *reinterpret_cast<const uint4*>(ov + t * 128 + ((cj ^ (t & 7)) << 4));
    *reinterpret_cast<uint4*>(ap + (size_t)t * 512 + cj * 8) = o4;
  }
}

// ---------------- final: out = x + mish(gn(y2)) in-place on d_out (raw stats) ----------------
__global__ __launch_bounds__(256) void final_kernel(const float* __restrict__ x,
    float* __restrict__ y, const float* __restrict__ straw,
    const float* __restrict__ w, const float* __restrict__ bv) {
  size_t i = ((size_t)blockIdx.x * 256 + TID) * 4;
  int ch = (int)((i >> 10) & (Cc - 1));
  int b = (int)(i >> 19);
  int g = b * 8 + (ch >> 6);
  float rs = straw[2 * g], rq = straw[2 * g + 1];
  float mean = rs * (1.f / 65536.f);
  float rstd = rsqrtf(fmaxf(rq * (1.f / 65536.f) - mean * mean, 0.f) + 1e-5f);
  float sw = w[ch] * rstd;
  float sb = bv[ch] - mean * sw;
  float4 v  = *reinterpret_cast<const float4*>(y + i);
  float4 xv = *reinterpret_cast<const float4*>(x + i);
  v.x = xv.x + mishf(v.x * sw + sb);
  v.y = xv.y + mishf(v.y * sw + sb);
  v.z = xv.z + mishf(v.z * sw + sb);
  v.w = xv.w + mishf(v.w * sw + sb);
  *reinterpret_cast<float4*>(y + i) = v;
}

extern "C" void kernel_launch(void* const* d_in, const int* in_sizes, int n_in,
                              void* d_out, int out_size, void* d_ws, size_t ws_size,
                              hipStream_t stream) {
  const float* x     = (const float*)d_in[0];
  const float* gn_w  = (const float*)d_in[1];
  const float* gn_b  = (const float*)d_in[2];
  const float* wqkv  = (const float*)d_in[3];
  const float* bqkv  = (const float*)d_in[4];
  const float* gnq_w = (const float*)d_in[5];
  const float* gnq_b = (const float*)d_in[6];
  const float* wproj = (const float*)d_in[7];
  const float* bproj = (const float*)d_in[8];
  const float* gnp_w = (const float*)d_in[9];
  const float* gnp_b = (const float*)d_in[10];
  float* out = (float*)d_out;

  char* ws = (char*)d_ws;
  const size_t MB = 1024 * 1024;
  __hip_bfloat16* qkvb = (__hip_bfloat16*)ws;            // [0,24MB)   step5 -> step6
  __hip_bfloat16* aT   = (__hip_bfloat16*)(ws + 24 * MB);// [24,33MB)  step2/7 -> step9
  __hip_bfloat16* A1   = (__hip_bfloat16*)(ws + 56 * MB);// [56,59MB)  step3 -> step5
  char* vimg = ws + 56 * MB;                             // [56,64MB)  step6 -> step7 (A1 dead)
  __hip_bfloat16* A2   = (__hip_bfloat16*)(ws + 56 * MB);// [56,58MB)  step8 -> step9 (vimg dead)
  float* st2raw = (float*)(ws + 64 * MB);
  float* st3raw = st2raw + 128;
  __hip_bfloat16* B1t = (__hip_bfloat16*)d_out;          // d_out as B1t  step4 -> step5
  char* qTp  = (char*)d_out;                             // d_out[0,8MB)  step6 -> step7
  char* kimg = (char*)d_out + 8 * MB;                    // d_out[8,16MB) step6 -> step7

  dim3 blk(256);
  zero_stats<<<1, blk, 0, stream>>>(st2raw);                                        // 1
  zero_pads<<<64, blk, 0, stream>>>(aT);                                            // 2
  cast_bf16<<<1536, blk, 0, stream>>>(wqkv, A1, C3 * 1024);                         // 3
  gn1_im2col<<<256, blk, 0, stream>>>(x, gn_w, gn_b, B1t);                          // 4
  gemm_bt10<<<dim3(4, 8, 8), dim3(1024), 0, stream>>>(A1, B1t, bqkv, qkvb, st2raw); // 5
  gn2_prep<<<1024, blk, 0, stream>>>(qkvb, st2raw, gnq_w, gnq_b, qTp, kimg, vimg);  // 6
  attn_mfma5<<<dim3(4, 64), dim3(1024), 0, stream>>>(qTp, kimg, vimg, aT);          // 7
  cast_wproj<<<512, blk, 0, stream>>>(wproj, A2);                                   // 8
  gemm_c4<<<dim3(8, 4, 8), blk, 0, stream>>>(A2, aT, bproj, out, st3raw);           // 9
  final_kernel<<<4096, blk, 0, stream>>>(x, out, st3raw, gnp_w, gnp_b);             // 10
}

// Round 17
// 161.565 us; speedup vs baseline: 2.1582x; 1.0366x over previous
//
#include <hip/hip_runtime.h>
#include <hip/hip_bf16.h>
#include <math.h>

#define TID threadIdx.x

constexpr int Cc = 512, Tt = 1024, C3 = 1536;

typedef __attribute__((ext_vector_type(8))) __bf16 bf16x8;
typedef __attribute__((ext_vector_type(4))) float f32x4;

__device__ __forceinline__ void async16(const void* g, void* l) {
  __builtin_amdgcn_global_load_lds(
      (const __attribute__((address_space(1))) unsigned int*)g,
      (__attribute__((address_space(3))) unsigned int*)l, 16, 0, 0);
}

__device__ __forceinline__ unsigned int pack2bf(float a, float b) {
  __hip_bfloat162 h;
  h.x = __float2bfloat16(a);
  h.y = __float2bfloat16(b);
  return *reinterpret_cast<unsigned int*>(&h);
}

__device__ __forceinline__ float bf2f(unsigned short u) {
  unsigned int t = ((unsigned int)u) << 16;
  union { unsigned int i; float f; } c;
  c.i = t;
  return c.f;
}

// hardware 2^x (v_exp_f32: D = 2^S0)
__device__ __forceinline__ float exp2_hw(float x) {
  float r;
  asm("v_exp_f32 %0, %1" : "=v"(r) : "v"(x));
  return r;
}

// mish(x) = x * n/(n+2), n = u*(u+2), u = e^x  (one hw exp + one rcp)
__device__ __forceinline__ float mishf(float x) {
  float u = __expf(x);
  float n = u * (u + 2.f);
  float r = x * n * __builtin_amdgcn_rcpf(n + 2.f);
  return (x > 20.f) ? x : r;
}

__device__ __forceinline__ void blockReduce2(float& s, float& ss) {
  #pragma unroll
  for (int off = 32; off > 0; off >>= 1) {
    s  += __shfl_xor(s,  off);
    ss += __shfl_xor(ss, off);
  }
  __shared__ float ls[4], lss[4];
  int w = TID >> 6;
  if ((TID & 63) == 0) { ls[w] = s; lss[w] = ss; }
  __syncthreads();
  s  = ls[0] + ls[1] + ls[2] + ls[3];
  ss = lss[0] + lss[1] + lss[2] + lss[3];
}

// ---------------- zero the raw-stat accumulators (256 floats) ----------------
__global__ void zero_stats(float* p) { p[TID] = 0.f; }

// ---------------- zero the 16-row halo pads of aT[8][1056][512] ----------------
__global__ __launch_bounds__(256) void zero_pads(__hip_bfloat16* __restrict__ aT) {
  int idx = blockIdx.x * 256 + TID;
  int bb = idx >> 11;
  int task = idx & 2047;
  int prow = task >> 6;
  int col = (task & 63) * 8;
  int P = (prow < 16) ? prow : (1024 + prow);
  uint4 z = {0u, 0u, 0u, 0u};
  *reinterpret_cast<uint4*>(aT + ((size_t)bb * 1056 + P) * 512 + col) = z;
}

// ---------------- fused GN(32) + im2col(K=2, pad_lo=0) -> bf16 B1t[b][t][k=2ci+j] ----------------
__global__ __launch_bounds__(256) void gn1_im2col(const float* __restrict__ x,
    const float* __restrict__ w, const float* __restrict__ bv,
    __hip_bfloat16* __restrict__ B1t) {
  __shared__ float hs[16][262];
  int blk = blockIdx.x, bb = blk >> 5, g = blk & 31;
  size_t base = ((size_t)bb * Cc + g * 16) * Tt;
  const float* xp = x + base;
  float s = 0.f, ss = 0.f;
  for (int i = TID * 4; i < 16 * Tt; i += 1024) {
    float4 v = *reinterpret_cast<const float4*>(xp + i);
    s  += v.x + v.y + v.z + v.w;
    ss += v.x * v.x + v.y * v.y + v.z * v.z + v.w * v.w;
  }
  blockReduce2(s, ss);
  float mean = s * (1.f / 16384.f);
  float rstd = rsqrtf(ss * (1.f / 16384.f) - mean * mean + 1e-5f);

  char* ob = reinterpret_cast<char*>(B1t + (size_t)bb * Tt * 1024 + g * 32);
  for (int tc = 0; tc < 4; ++tc) {
    int tbase = tc * 256;
    __syncthreads();
    for (int task = TID; task < 1024; task += 256) {
      int row = task >> 6, c4 = task & 63;
      int ch = g * 16 + row;
      float sw = w[ch] * rstd;
      float sb = bv[ch] - mean * sw;
      float4 v = *reinterpret_cast<const float4*>(xp + (size_t)row * Tt + tbase + c4 * 4);
      hs[row][c4 * 4 + 0] = v.x * sw + sb;
      hs[row][c4 * 4 + 1] = v.y * sw + sb;
      hs[row][c4 * 4 + 2] = v.z * sw + sb;
      hs[row][c4 * 4 + 3] = v.w * sw + sb;
    }
    if (TID < 16) {
      int row = TID, t = tbase + 256;
      float val = 0.f;
      if (t < Tt) {
        int ch = g * 16 + row;
        float sw = w[ch] * rstd;
        float sb = bv[ch] - mean * sw;
        val = xp[(size_t)row * Tt + t] * sw + sb;
      }
      hs[row][256] = val;
    }
    __syncthreads();
    for (int task = TID; task < 1024; task += 256) {
      int t = task >> 2, cj = task & 3;
      int ci = cj * 4;
      uint4 u;
      u.x = pack2bf(hs[ci + 0][t], hs[ci + 0][t + 1]);
      u.y = pack2bf(hs[ci + 1][t], hs[ci + 1][t + 1]);
      u.z = pack2bf(hs[ci + 2][t], hs[ci + 2][t + 1]);
      u.w = pack2bf(hs[ci + 3][t], hs[ci + 3][t + 1]);
      *reinterpret_cast<uint4*>(ob + ((size_t)(tbase + t) * 1024 + cj * 8) * 2) = u;
    }
  }
}

// ---------------- f32 -> bf16 cast (weights) ----------------
__global__ __launch_bounds__(256) void cast_bf16(const float* __restrict__ in,
    __hip_bfloat16* __restrict__ out, int n) {
  int i = (blockIdx.x * 256 + TID) * 4;
  if (i >= n) return;
  float4 v = *reinterpret_cast<const float4*>(in + i);
  *reinterpret_cast<unsigned int*>(out + i)     = pack2bf(v.x, v.y);
  *reinterpret_cast<unsigned int*>(out + i + 2) = pack2bf(v.z, v.w);
}

// ---------------- wproj [o][ci][4] f32 -> A2[j][o][ci] bf16 ----------------
__global__ __launch_bounds__(256) void cast_wproj(const float* __restrict__ wp,
    __hip_bfloat16* __restrict__ A2) {
  int o = blockIdx.x;
  int ci = TID * 2;
  float4 v0 = *reinterpret_cast<const float4*>(wp + ((size_t)o * 512 + ci) * 4);
  float4 v1 = *reinterpret_cast<const float4*>(wp + ((size_t)o * 512 + ci + 1) * 4);
  const float* a0 = &v0.x;
  const float* a1 = &v1.x;
  #pragma unroll
  for (int j = 0; j < 4; ++j) {
    unsigned int u = pack2bf(a0[j], a1[j]);
    *reinterpret_cast<unsigned int*>(A2 + ((size_t)j * 512 + o) * 512 + ci) = u;
  }
}

// ---------------- bf16 MFMA GEMM v10: BM=192 x BN=256, 1024 thr, ISSUE-AHEAD double buffer ----
__global__ __launch_bounds__(1024, 4) void gemm_bt10(const __hip_bfloat16* __restrict__ A,
    const __hip_bfloat16* __restrict__ Bt, const float* __restrict__ bias,
    __hip_bfloat16* __restrict__ Cout, float* __restrict__ statraw) {
  constexpr int K = 1024;
  constexpr int BUF = 56 * 1024;
  __shared__ __align__(16) char lds[2 * BUF];
  int t0 = blockIdx.x * 256, o0 = blockIdx.y * 192, bz = blockIdx.z;
  int wave = TID >> 6, lane = TID & 63;
  int l4 = lane >> 4, r15 = lane & 15;
  int wm = wave >> 2, wn = wave & 3;
  const __hip_bfloat16* Ab = A + (size_t)o0 * K;
  const __hip_bfloat16* Bb = Bt + ((size_t)bz * 1024 + t0) * K;

  f32x4 acc[3][4];
  f32x4 zz = {0.f, 0.f, 0.f, 0.f};
  #pragma unroll
  for (int m = 0; m < 3; ++m)
    #pragma unroll
    for (int n = 0; n < 4; ++n) acc[m][n] = zz;

  auto stage = [&](int kt, int buf) {
    char* dst = lds + buf * BUF;
    #pragma unroll
    for (int c = 0; c < 4; ++c) {
      int ch = c * 16 + wave;
      if (ch < 56) {
        int kof;
        const __hip_bfloat16* src;
        if (ch < 24) {
          int row = (ch >> 1) * 16 + r15;
          kof = kt * 64 + (ch & 1) * 32 + l4 * 8;
          src = Ab + (size_t)row * K + kof;
        } else {
          int cb = ch - 24;
          int row = (cb >> 1) * 16 + r15;
          kof = kt * 64 + (cb & 1) * 32 + l4 * 8;
          src = Bb + (size_t)row * K + kof;
        }
        async16(src, dst + ch * 1024 + lane * 16);
      }
    }
  };

  stage(0, 0);
  __syncthreads();
  for (int kt = 0; kt < 16; ++kt) {
    if (kt + 1 < 16) stage(kt + 1, (kt + 1) & 1);
    char* cur = lds + (kt & 1) * BUF;
    #pragma unroll
    for (int kk = 0; kk < 2; ++kk) {
      bf16x8 af[3], bfr[4];
      #pragma unroll
      for (int m = 0; m < 3; ++m)
        af[m] = *reinterpret_cast<const bf16x8*>(cur + ((wm * 3 + m) * 2 + kk) * 1024 + lane * 16);
      #pragma unroll
      for (int n = 0; n < 4; ++n)
        bfr[n] = *reinterpret_cast<const bf16x8*>(cur + (24 + (wn * 4 + n) * 2 + kk) * 1024 + lane * 16);
      #pragma unroll
      for (int m = 0; m < 3; ++m)
        #pragma unroll
        for (int n = 0; n < 4; ++n)
          acc[m][n] = __builtin_amdgcn_mfma_f32_16x16x32_bf16(af[m], bfr[n], acc[m][n], 0, 0, 0);
    }
    __syncthreads();
  }

  float* sred = reinterpret_cast<float*>(lds);
  #pragma unroll
  for (int m = 0; m < 3; ++m) {
    float s = 0.f, ss2 = 0.f;
    #pragma unroll
    for (int n = 0; n < 4; ++n) {
      int ocol = t0 + (wn * 4 + n) * 16 + r15;
      #pragma unroll
      for (int r = 0; r < 4; ++r) {
        int orow = o0 + (wm * 3 + m) * 16 + l4 * 4 + r;
        float v = acc[m][n][r] + bias[orow];
        Cout[((size_t)bz * C3 + orow) * 1024 + ocol] = __float2bfloat16(v);
        s += v;
        ss2 += v * v;
      }
    }
    #pragma unroll
    for (int off = 1; off < 64; off <<= 1) {
      s   += __shfl_xor(s, off);
      ss2 += __shfl_xor(ss2, off);
    }
    if (lane == 0) {
      sred[(wave * 3 + m) * 2]     = s;
      sred[(wave * 3 + m) * 2 + 1] = ss2;
    }
  }
  __syncthreads();
  if (TID == 0) {
    float S = 0.f, SS = 0.f;
    #pragma unroll
    for (int slot = 0; slot < 48; ++slot) {
      S  += sred[slot * 2];
      SS += sred[slot * 2 + 1];
    }
    int g = bz * 8 + blockIdx.y;
    atomicAdd(&statraw[2 * g],     S);
    atomicAdd(&statraw[2 * g + 1], SS);
  }
}

// ---------------- shift-conv GEMM (conv K=4), ISSUE-AHEAD double buffer ----------------
__global__ __launch_bounds__(256) void gemm_c4(const __hip_bfloat16* __restrict__ A2,
    const __hip_bfloat16* __restrict__ aT, const float* __restrict__ bias,
    float* __restrict__ Cout, float* __restrict__ statraw) {
  constexpr int BUF = 42 * 1024;
  __shared__ __align__(16) char lds[2 * BUF];
  int t0 = blockIdx.x * 128, o0 = blockIdx.y * 128, bz = blockIdx.z;
  int wave = TID >> 6, lane = TID & 63;
  int l4 = lane >> 4, r15 = lane & 15;
  int wm = wave >> 1, wn = wave & 1;
  const __hip_bfloat16* aTb = aT + (size_t)bz * 1056 * 512;

  f32x4 acc[4][4];
  f32x4 zz = {0.f, 0.f, 0.f, 0.f};
  #pragma unroll
  for (int m = 0; m < 4; ++m)
    #pragma unroll
    for (int n = 0; n < 4; ++n) acc[m][n] = zz;

  auto stage = [&](int kt, int buf) {
    char* dst = lds + buf * BUF;
    #pragma unroll
    for (int c = 0; c < 11; ++c) {
      int ch = c * 4 + wave;
      if (ch < 42) {
        const __hip_bfloat16* src;
        if (ch < 32) {
          int j = ch >> 3, rg = ch & 7;
          src = A2 + ((size_t)j * 512 + o0 + rg * 16 + r15) * 512 + kt * 32 + l4 * 8;
        } else {
          int rg = ch - 32;
          src = aTb + (size_t)(t0 + rg * 16 + r15) * 512 + kt * 32 + l4 * 8;
        }
        async16(src, dst + ch * 1024 + lane * 16);
      }
    }
  };

  stage(0, 0);
  __syncthreads();
  for (int kt = 0; kt < 16; ++kt) {
    if (kt + 1 < 16) stage(kt + 1, (kt + 1) & 1);
    char* cur = lds + (kt & 1) * BUF;
    #pragma unroll
    for (int j = 0; j < 4; ++j) {
      bf16x8 af[4], bfr[4];
      #pragma unroll
      for (int m = 0; m < 4; ++m)
        af[m] = *reinterpret_cast<const bf16x8*>(cur + (j * 8 + wm * 4 + m) * 1024 + lane * 16);
      #pragma unroll
      for (int n = 0; n < 4; ++n) {
        int q = (wn * 4 + n) * 16 + r15 + j + 15;
        bfr[n] = *reinterpret_cast<const bf16x8*>(cur + 32 * 1024 + (q >> 4) * 1024 + l4 * 256 + (q & 15) * 16);
      }
      #pragma unroll
      for (int m = 0; m < 4; ++m)
        #pragma unroll
        for (int n = 0; n < 4; ++n)
          acc[m][n] = __builtin_amdgcn_mfma_f32_16x16x32_bf16(af[m], bfr[n], acc[m][n], 0, 0, 0);
    }
    __syncthreads();
  }

  float* sred = reinterpret_cast<float*>(lds);
  #pragma unroll
  for (int m = 0; m < 4; ++m) {
    float s = 0.f, ss2 = 0.f;
    #pragma unroll
    for (int n = 0; n < 4; ++n) {
      int ocol = t0 + (wn * 4 + n) * 16 + r15;
      #pragma unroll
      for (int r = 0; r < 4; ++r) {
        int orow = o0 + (wm * 4 + m) * 16 + l4 * 4 + r;
        float v = acc[m][n][r] + bias[orow];
        Cout[((size_t)bz * Cc + orow) * 1024 + ocol] = v;
        s += v;
        ss2 += v * v;
      }
    }
    #pragma unroll
    for (int off = 1; off < 64; off <<= 1) {
      s   += __shfl_xor(s, off);
      ss2 += __shfl_xor(ss2, off);
    }
    if (lane == 0) {
      sred[(wave * 4 + m) * 2]     = s;
      sred[(wave * 4 + m) * 2 + 1] = ss2;
    }
  }
  __syncthreads();
  if (TID < 2) {
    int g0 = o0 >> 6;
    float S = 0.f, SS = 0.f;
    int cnt = 0;
    #pragma unroll
    for (int slot = 0; slot < 16; ++slot) {
      int rc = ((slot >> 3) << 2) + (slot & 3);
      int g = (o0 + rc * 16) >> 6;
      if (g == g0 + (int)TID) {
        S  += sred[slot * 2];
        SS += sred[slot * 2 + 1];
        ++cnt;
      }
    }
    if (cnt) {
      atomicAdd(&statraw[2 * (bz * 8 + g0 + TID)],     S);
      atomicAdd(&statraw[2 * (bz * 8 + g0 + TID) + 1], SS);
    }
  }
}

// ---------------- fused GN(8)+Mish + build attn input images (bf16 qkv input, raw stats) ----------------
__global__ __launch_bounds__(256) void gn2_prep(const __hip_bfloat16* __restrict__ qkv,
    const float* __restrict__ straw, const float* __restrict__ w, const float* __restrict__ bv,
    char* __restrict__ qTp, char* __restrict__ kimg, char* __restrict__ vimg) {
  __shared__ unsigned short hbf[192 * 66];
  int tl = blockIdx.x & 15, hb = blockIdx.x >> 4;
  int b = hb >> 3, hd = hb & 7;
  float rs = straw[2 * (b * 8 + hd)], rq = straw[2 * (b * 8 + hd) + 1];
  float mean = rs * (1.f / 196608.f);
  float rstd = rsqrtf(fmaxf(rq * (1.f / 196608.f) - mean * mean, 0.f) + 1e-5f);
  for (int task = TID; task < 768; task += 256) {
    int row = task >> 2, seg = task & 3;
    int ch = hd * 192 + row;
    float sw = w[ch] * rstd;
    float sb = bv[ch] - mean * sw;
    const uint4* src = reinterpret_cast<const uint4*>(
        qkv + ((size_t)(b * C3 + ch)) * 1024 + tl * 64 + seg * 16);
    uint4 u0 = src[0], u1 = src[1];
    unsigned int uu[8] = {u0.x, u0.y, u0.z, u0.w, u1.x, u1.y, u1.z, u1.w};
    unsigned int* dst = reinterpret_cast<unsigned int*>(&hbf[row * 66 + seg * 16]);
    #pragma unroll
    for (int j = 0; j < 8; ++j) {
      float a = mishf(bf2f((unsigned short)(uu[j] & 0xffff)) * sw + sb);
      float c = mishf(bf2f((unsigned short)(uu[j] >> 16)) * sw + sb);
      dst[j] = pack2bf(a, c);
    }
  }
  __syncthreads();
  size_t tileof = ((size_t)hb * 16 + tl) * 8192;
  {
    int t = TID & 63, sel = TID >> 6;
    int img = sel >> 1, half = sel & 1;
    char* obase = (img == 0 ? qTp : kimg) + tileof + (size_t)t * 128;
    #pragma unroll
    for (int cc = 0; cc < 4; ++cc) {
      int chunk = half * 4 + cc;
      uint4 u;
      unsigned int* up = reinterpret_cast<unsigned int*>(&u);
      #pragma unroll
      for (int j = 0; j < 4; ++j) {
        int c = chunk * 8 + j * 2;
        unsigned int lo = hbf[(img * 64 + c) * 66 + t];
        unsigned int hi = hbf[(img * 64 + c + 1) * 66 + t];
        up[j] = lo | (hi << 16);
      }
      int cpos = (img == 0) ? chunk : (chunk ^ (t & 7));
      *reinterpret_cast<uint4*>(obase + cpos * 16) = u;
    }
  }
  {
    int c = TID & 63, qtr = TID >> 6;
    const unsigned int* vrow = reinterpret_cast<const unsigned int*>(&hbf[(128 + c) * 66]);
    char* obase = vimg + tileof + (size_t)c * 128;
    #pragma unroll
    for (int k = 0; k < 2; ++k) {
      int chunk = qtr * 2 + k;
      uint4 u;
      unsigned int* up = reinterpret_cast<unsigned int*>(&u);
      #pragma unroll
      for (int j = 0; j < 4; ++j) up[j] = vrow[chunk * 4 + j];
      *reinterpret_cast<uint4*>(obase + (chunk ^ (c & 7)) * 16) = u;
    }
  }
}

// ---------------- MFMA flash attention v6: KVBLK=128 (half the tiles, half the barrier tax) ----
// 1024 thr, 4 q-tiles/block. LDS 128KB: K dbuf 2x16K | V dbuf 2x16K | P 16x4K (ov aliases).
__global__ __launch_bounds__(1024) void attn_mfma6(const char* __restrict__ qTp,
    const char* __restrict__ kimg, const char* __restrict__ vimg,
    __hip_bfloat16* __restrict__ aT) {
  __shared__ __align__(16) char smem[131072];
  char* kbuf0 = smem;
  char* kbuf1 = smem + 16384;
  char* vbuf0 = smem + 32768;
  char* vbuf1 = smem + 49152;
  char* pp    = smem + 65536;  // 16 waves x 4KB
  char* ov    = smem;          // 32KB alias (dead K/V buffers)

  int hb = blockIdx.y;
  int b = hb >> 3, hd = hb & 7;
  int lane = TID & 63, wave = TID >> 6;
  int qt = wave >> 2, qw = wave & 3;
  int l4 = lane >> 4, r15 = lane & 15;
  size_t ibase = (size_t)hb * 16 * 8192;
  const char* ksrc = kimg + ibase;
  const char* vsrc = vimg + ibase;

  async16(ksrc + (size_t)TID * 16, kbuf0 + (size_t)TID * 16);
  async16(vsrc + (size_t)TID * 16, vbuf0 + (size_t)TID * 16);

  bf16x8 aq[2];
  int tg = qw * 16 + r15;
  const char* qrow = qTp + ibase + (size_t)(blockIdx.x * 4 + qt) * 8192 + (size_t)tg * 128;
  aq[0] = *reinterpret_cast<const bf16x8*>(qrow + l4 * 16);
  aq[1] = *reinterpret_cast<const bf16x8*>(qrow + 64 + l4 * 16);
  // pre-scale Q by 0.125*log2(e): scores live in the exp2 domain
  {
    const float SC = 0.125f * 1.44269504f;
    #pragma unroll
    for (int kk = 0; kk < 2; ++kk) {
      unsigned int* u = reinterpret_cast<unsigned int*>(&aq[kk]);
      #pragma unroll
      for (int j = 0; j < 4; ++j) {
        float lo = bf2f((unsigned short)(u[j] & 0xffff)) * SC;
        float hi = bf2f((unsigned short)(u[j] >> 16)) * SC;
        u[j] = pack2bf(lo, hi);
      }
    }
  }

  f32x4 osum[4];
  f32x4 zz = {0.f, 0.f, 0.f, 0.f};
  #pragma unroll
  for (int cf = 0; cf < 4; ++cf) osum[cf] = zz;
  float mrow[4] = {-1e30f, -1e30f, -1e30f, -1e30f};
  float lrow[4] = {0.f, 0.f, 0.f, 0.f};
  __syncthreads();

  for (int it = 0; it < 8; ++it) {
    char* kcur = (it & 1) ? kbuf1 : kbuf0;
    char* vcur = (it & 1) ? vbuf1 : vbuf0;
    if (it < 7) {
      char* knxt = (it & 1) ? kbuf0 : kbuf1;
      char* vnxt = (it & 1) ? vbuf0 : vbuf1;
      const char* kn = ksrc + (size_t)(it + 1) * 16384;
      const char* vn = vsrc + (size_t)(it + 1) * 16384;
      async16(kn + (size_t)TID * 16, knxt + (size_t)TID * 16);
      async16(vn + (size_t)TID * 16, vnxt + (size_t)TID * 16);
    }
    // QK^T over 128 s-cols (8 fragments)
    f32x4 sc[8];
    #pragma unroll
    for (int sf = 0; sf < 8; ++sf) sc[sf] = zz;
    #pragma unroll
    for (int sf = 0; sf < 8; ++sf) {
      int sr = sf * 16 + r15;
      #pragma unroll
      for (int kk = 0; kk < 2; ++kk) {
        bf16x8 bk = *reinterpret_cast<const bf16x8*>(kcur + sr * 128 + (((kk * 4 + l4) ^ (sr & 7)) << 4));
        sc[sf] = __builtin_amdgcn_mfma_f32_16x16x32_bf16(aq[kk], bk, sc[sf], 0, 0, 0);
      }
    }
    // row max over 128 cols
    float tmax[4];
    #pragma unroll
    for (int r = 0; r < 4; ++r) {
      float m0 = fmaxf(fmaxf(sc[0][r], sc[1][r]), fmaxf(sc[2][r], sc[3][r]));
      float m1 = fmaxf(fmaxf(sc[4][r], sc[5][r]), fmaxf(sc[6][r], sc[7][r]));
      tmax[r] = fmaxf(m0, m1);
    }
    #pragma unroll
    for (int off = 1; off < 16; off <<= 1)
      #pragma unroll
      for (int r = 0; r < 4; ++r) tmax[r] = fmaxf(tmax[r], __shfl_xor(tmax[r], off));
    // defer-max: rescale only when the running max grows
    bool grow = (tmax[0] > mrow[0]) | (tmax[1] > mrow[1]) |
                (tmax[2] > mrow[2]) | (tmax[3] > mrow[3]);
    if (grow) {
      float alpha[4];
      #pragma unroll
      for (int r = 0; r < 4; ++r) {
        float mnew = fmaxf(mrow[r], tmax[r]);
        alpha[r] = exp2_hw(mrow[r] - mnew);
        mrow[r] = mnew;
        lrow[r] *= alpha[r];
      }
      #pragma unroll
      for (int cf = 0; cf < 4; ++cf)
        #pragma unroll
        for (int r = 0; r < 4; ++r) osum[cf][r] *= alpha[r];
    }
    // P = 2^(sc-m) -> wave-local LDS tile [16t][128s], chunk swizzle ^ (t&15)
    char* pw = pp + wave * 4096;
    float psum[4] = {0.f, 0.f, 0.f, 0.f};
    #pragma unroll
    for (int sf = 0; sf < 8; ++sf) {
      int s = sf * 16 + r15;
      int chunk = s >> 3;
      #pragma unroll
      for (int r = 0; r < 4; ++r) {
        float p = exp2_hw(sc[sf][r] - mrow[r]);
        psum[r] += p;
        int tlc = l4 * 4 + r;
        *reinterpret_cast<__hip_bfloat16*>(pw + tlc * 256 + (((chunk ^ (tlc & 15)) << 4) | ((s & 7) * 2)))
            = __float2bfloat16(p);
      }
    }
    #pragma unroll
    for (int r = 0; r < 4; ++r) lrow[r] += psum[r];
    asm volatile("s_waitcnt lgkmcnt(0)" ::: "memory");
    __builtin_amdgcn_sched_barrier(0);

    // PV: pa[4] over 4 k-slots of 32 s each
    bf16x8 pa[4];
    #pragma unroll
    for (int kk2 = 0; kk2 < 4; ++kk2)
      pa[kk2] = *reinterpret_cast<const bf16x8*>(pw + r15 * 256 + (((kk2 * 4 + l4) ^ (r15 & 15)) << 4));
    #pragma unroll
    for (int cf = 0; cf < 4; ++cf) {
      int cr = cf * 16 + r15;
      #pragma unroll
      for (int kk2 = 0; kk2 < 4; ++kk2) {
        bf16x8 bv = *reinterpret_cast<const bf16x8*>(vcur + (kk2 >> 1) * 8192 + cr * 128 +
                                                     ((((kk2 & 1) * 4 + l4) ^ (cr & 7)) << 4));
        osum[cf] = __builtin_amdgcn_mfma_f32_16x16x32_bf16(pa[kk2], bv, osum[cf], 0, 0, 0);
      }
    }
    __syncthreads();
  }

  #pragma unroll
  for (int off = 1; off < 16; off <<= 1)
    #pragma unroll
    for (int r = 0; r < 4; ++r) lrow[r] += __shfl_xor(lrow[r], off);
  float linv[4];
  #pragma unroll
  for (int r = 0; r < 4; ++r) linv[r] = 1.f / lrow[r];

  // ov[t][c] bf16, t in [0,256), swizzled 128B rows
  #pragma unroll
  for (int cf = 0; cf < 4; ++cf) {
    int c = cf * 16 + r15;
    #pragma unroll
    for (int r = 0; r < 4; ++r) {
      int t = qt * 64 + qw * 16 + l4 * 4 + r;
      *reinterpret_cast<__hip_bfloat16*>(ov + t * 128 + ((((c >> 3) ^ (t & 7)) << 4) | ((c & 7) * 2)))
          = __float2bfloat16(osum[cf][r] * linv[r]);
    }
  }
  __syncthreads();
  __hip_bfloat16* ap = aT + ((size_t)b * 1056 + 16 + blockIdx.x * 256) * 512 + hd * 64;
  for (int u = TID; u < 2048; u += 1024) {
    int t = u >> 3, cj = u & 7;
    uint4 o4 = *reinterpret_cast<const uint4*>(ov + t * 128 + ((cj ^ (t & 7)) << 4));
    *reinterpret_cast<uint4*>(ap + (size_t)t * 512 + cj * 8) = o4;
  }
}

// ---------------- final: out = x + mish(gn(y2)) in-place on d_out (raw stats) ----------------
__global__ __launch_bounds__(256) void final_kernel(const float* __restrict__ x,
    float* __restrict__ y, const float* __restrict__ straw,
    const float* __restrict__ w, const float* __restrict__ bv) {
  size_t i = ((size_t)blockIdx.x * 256 + TID) * 4;
  int ch = (int)((i >> 10) & (Cc - 1));
  int b = (int)(i >> 19);
  int g = b * 8 + (ch >> 6);
  float rs = straw[2 * g], rq = straw[2 * g + 1];
  float mean = rs * (1.f / 65536.f);
  float rstd = rsqrtf(fmaxf(rq * (1.f / 65536.f) - mean * mean, 0.f) + 1e-5f);
  float sw = w[ch] * rstd;
  float sb = bv[ch] - mean * sw;
  float4 v  = *reinterpret_cast<const float4*>(y + i);
  float4 xv = *reinterpret_cast<const float4*>(x + i);
  v.x = xv.x + mishf(v.x * sw + sb);
  v.y = xv.y + mishf(v.y * sw + sb);
  v.z = xv.z + mishf(v.z * sw + sb);
  v.w = xv.w + mishf(v.w * sw + sb);
  *reinterpret_cast<float4*>(y + i) = v;
}

extern "C" void kernel_launch(void* const* d_in, const int* in_sizes, int n_in,
                              void* d_out, int out_size, void* d_ws, size_t ws_size,
                              hipStream_t stream) {
  const float* x     = (const float*)d_in[0];
  const float* gn_w  = (const float*)d_in[1];
  const float* gn_b  = (const float*)d_in[2];
  const float* wqkv  = (const float*)d_in[3];
  const float* bqkv  = (const float*)d_in[4];
  const float* gnq_w = (const float*)d_in[5];
  const float* gnq_b = (const float*)d_in[6];
  const float* wproj = (const float*)d_in[7];
  const float* bproj = (const float*)d_in[8];
  const float* gnp_w = (const float*)d_in[9];
  const float* gnp_b = (const float*)d_in[10];
  float* out = (float*)d_out;

  char* ws = (char*)d_ws;
  const size_t MB = 1024 * 1024;
  __hip_bfloat16* qkvb = (__hip_bfloat16*)ws;            // [0,24MB)   step5 -> step6
  __hip_bfloat16* aT   = (__hip_bfloat16*)(ws + 24 * MB);// [24,33MB)  step2/7 -> step9
  __hip_bfloat16* A1   = (__hip_bfloat16*)(ws + 56 * MB);// [56,59MB)  step3 -> step5
  char* vimg = ws + 56 * MB;                             // [56,64MB)  step6 -> step7 (A1 dead)
  __hip_bfloat16* A2   = (__hip_bfloat16*)(ws + 56 * MB);// [56,58MB)  step8 -> step9 (vimg dead)
  float* st2raw = (float*)(ws + 64 * MB);
  float* st3raw = st2raw + 128;
  __hip_bfloat16* B1t = (__hip_bfloat16*)d_out;          // d_out as B1t  step4 -> step5
  char* qTp  = (char*)d_out;                             // d_out[0,8MB)  step6 -> step7
  char* kimg = (char*)d_out + 8 * MB;                    // d_out[8,16MB) step6 -> step7

  dim3 blk(256);
  zero_stats<<<1, blk, 0, stream>>>(st2raw);                                        // 1
  zero_pads<<<64, blk, 0, stream>>>(aT);                                            // 2
  cast_bf16<<<1536, blk, 0, stream>>>(wqkv, A1, C3 * 1024);                         // 3
  gn1_im2col<<<256, blk, 0, stream>>>(x, gn_w, gn_b, B1t);                          // 4
  gemm_bt10<<<dim3(4, 8, 8), dim3(1024), 0, stream>>>(A1, B1t, bqkv, qkvb, st2raw); // 5
  gn2_prep<<<1024, blk, 0, stream>>>(qkvb, st2raw, gnq_w, gnq_b, qTp, kimg, vimg);  // 6
  attn_mfma6<<<dim3(4, 64), dim3(1024), 0, stream>>>(qTp, kimg, vimg, aT);          // 7
  cast_wproj<<<512, blk, 0, stream>>>(wproj, A2);                                   // 8
  gemm_c4<<<dim3(8, 4, 8), blk, 0, stream>>>(A2, aT, bproj, out, st3raw);           // 9
  final_kernel<<<4096, blk, 0, stream>>>(x, out, st3raw, gnp_w, gnp_b);             // 10
}